// Round 10
// baseline (341.327 us; speedup 1.0000x reference)
//
#include <hip/hip_runtime.h>
#include <hip/hip_bf16.h>

typedef unsigned short u16;
typedef __bf16 bf16x8 __attribute__((ext_vector_type(8)));
typedef float  f32x4  __attribute__((ext_vector_type(4)));

constexpr int TT = 4096;   // seq
constexpr int BBATCH = 2;  // batch
constexpr int EE = 1024;   // embed
constexpr int HH = 16;     // heads
constexpr int DD = 64;     // head dim
constexpr int WQ = 256;    // one-sided window
constexpr int GG = 64;     // global tokens
constexpr int NSPLIT = 16; // key splits for global attention (R10: 8->16, halves serial chain)
constexpr float LOG2E = 1.4426950408889634f;

// ---------- bf16 / math helpers ----------
__device__ __forceinline__ float fast_exp2(float x) {
    return __builtin_amdgcn_exp2f(x);   // native v_exp_f32 (2^x)
}
__device__ __forceinline__ u16 f2bf(float f) {
    union { float f; unsigned int i; } c; c.f = f;
    unsigned int x = c.i;
    return (u16)((x + 0x7fffu + ((x >> 16) & 1u)) >> 16);  // RNE
}
__device__ __forceinline__ unsigned cvt_pk_bf16(float a, float b) {
    unsigned r;
    asm("v_cvt_pk_bf16_f32 %0, %1, %2" : "=v"(r) : "v"(a), "v"(b));
    return r;  // low16 = bf16(a), high16 = bf16(b), RNE
}
__device__ __forceinline__ uint4 pack8(float4 a, float4 b) {
    uint4 r;
    r.x = (unsigned)f2bf(a.x) | ((unsigned)f2bf(a.y) << 16);
    r.y = (unsigned)f2bf(a.z) | ((unsigned)f2bf(a.w) << 16);
    r.z = (unsigned)f2bf(b.x) | ((unsigned)f2bf(b.y) << 16);
    r.w = (unsigned)f2bf(b.z) | ((unsigned)f2bf(b.w) << 16);
    return r;
}

// async global->LDS, 16B per lane; LDS dest = wave-uniform base + lane*16
__device__ __forceinline__ void g2l16(const u16* g, u16* l) {
    __builtin_amdgcn_global_load_lds(
        (const __attribute__((address_space(1))) void*)g,
        (__attribute__((address_space(3))) void*)l, 16, 0, 0);
}

// XCD swizzle: blocks sharing an M-tile (y) get linear ids == c (mod 8) -> one XCD's L2
__device__ __forceinline__ void xcd_swizzle(int& bx, int& by) {
    bx = blockIdx.x; by = blockIdx.y;
    if ((gridDim.y & 7) == 0) {
        const int g   = blockIdx.x + blockIdx.y * gridDim.x;
        const int idx = g >> 3;
        bx = idx % gridDim.x;
        by = (g & 7) + ((idx / gridDim.x) << 3);
    }
}

// ---------- fp32 -> bf16 conversion ----------
struct WPtrs { const float* p[7]; };
__global__ __launch_bounds__(256) void conv_kernel(
    WPtrs wp, const float* __restrict__ query, u16* __restrict__ wb, u16* __restrict__ xb)
{
    const size_t i8 = ((size_t)blockIdx.x * 256 + threadIdx.x) << 3;
    const size_t WTOT = (size_t)7 << 20;   // 7 x 1024*1024
    const float* src;
    u16* dst;
    if (i8 < WTOT) {
        const int which = (int)(i8 >> 20);
        src = wp.p[which] + (i8 & (((size_t)1 << 20) - 1));
        dst = wb + i8;
    } else {
        const size_t j = i8 - WTOT;            // dst index in [B,T,E]
        const size_t e = j & (EE - 1);
        const size_t t = (j >> 10) & (TT - 1);
        const size_t b = j >> 22;
        src = query + (t * BBATCH + b) * EE + e;
        dst = xb + j;
    }
    const float4 f0 = *(const float4*)src;
    const float4 f1 = *(const float4*)(src + 4);
    *(uint4*)dst = pack8(f0, f1);
}

struct FusedArgs { u16* out[3]; const float* bias[3]; float scale[3]; int vseg; };

// ---------- pipelined 128x128 GEMM (verified best: 0 bank conflicts, 2 blocks/CU) ----------
// PERMA: logical row m reads source row (m>>6)*4096 + (m&63)  (x[:, :G] gather for qg)
template<int NSEG, int CF32, int PERMC, int PERMA>
__global__ __launch_bounds__(256, 2) void gemm_pipe_kernel(
    const u16* __restrict__ A, const u16* __restrict__ W, FusedArgs fa)
{
    const int tid = threadIdx.x, lane = tid & 63, w = tid >> 6;
    const int wm = w >> 1, wn = w & 1;
    int bx, by;
    xcd_swizzle(bx, by);
    const int m0 = by << 7, n0 = bx << 7;

    __shared__ __align__(16) u16 As[2][8192];   // [buf][128][64], swizzled
    __shared__ __align__(16) u16 Bs[2][8192];

    const int srow = lane >> 3;                        // 0..7 (== dest row & 7)
    const int scol = ((lane & 7) ^ srow) << 3;         // pre-swizzled source col (elems)
    auto arow = [](int m) -> size_t {
        return PERMA ? (size_t)(((m >> 6) << 12) | (m & 63)) : (size_t)m;
    };
    const u16* gB = W + (size_t)(n0 + (w << 5) + srow) * EE + scol;
    u16* lA = &As[0][0] + (w << 11);
    u16* lB = &Bs[0][0] + (w << 11);

    f32x4 acc[4][4];
#pragma unroll
    for (int i = 0; i < 4; i++)
#pragma unroll
        for (int j = 0; j < 4; j++)
            acc[i][j] = (f32x4){0.f, 0.f, 0.f, 0.f};

    const int fr = lane & 15;
    const int qb = (lane >> 4) << 4;                   // frag 16B-chunk byte col
    const int xr = (fr & 7) << 4;                      // read-side swizzle XOR

    auto stageA = [&](int k0, int buf) {
#pragma unroll
        for (int l = 0; l < 4; l++) {
            const int row = m0 + (w << 5) + srow + (l << 3);
            g2l16(A + arow(row) * EE + scol + k0, lA + buf * 8192 + (l << 9));
        }
    };
    auto stageB = [&](int k0, int buf) {
#pragma unroll
        for (int l = 0; l < 4; l++)
            g2l16(gB + (size_t)(l << 3) * EE + k0, lB + buf * 8192 + (l << 9));
    };

    stageA(0, 0);
    stageB(0, 0);
    __syncthreads();

    constexpr int NT = EE / 64;                        // 16 K-tiles
#pragma unroll 2
    for (int t = 0; t < NT; t++) {
        const int buf = t & 1;
        const bool pf = (t + 1 < NT);
        const int kn = (t + 1) << 6;
        bf16x8 af[4], bfv[4];

        // ---- phase 0 : k-half 0 ----
#pragma unroll
        for (int mi = 0; mi < 4; mi++)
            af[mi] = *(const bf16x8*)((const char*)&As[buf][0] +
                      ((((wm << 6) + (mi << 4) + fr)) << 7) + (qb ^ xr));
#pragma unroll
        for (int nj = 0; nj < 4; nj++)
            bfv[nj] = *(const bf16x8*)((const char*)&Bs[buf][0] +
                      ((((wn << 6) + (nj << 4) + fr)) << 7) + (qb ^ xr));
        if (pf) stageA(kn, buf ^ 1);
        __builtin_amdgcn_s_barrier();
        __builtin_amdgcn_s_setprio(1);
#pragma unroll
        for (int mi = 0; mi < 4; mi++)
#pragma unroll
            for (int nj = 0; nj < 4; nj++)
                acc[mi][nj] = __builtin_amdgcn_mfma_f32_16x16x32_bf16(af[mi], bfv[nj], acc[mi][nj], 0, 0, 0);
        __builtin_amdgcn_s_setprio(0);
        __builtin_amdgcn_s_barrier();

        // ---- phase 1 : k-half 1 ----
#pragma unroll
        for (int mi = 0; mi < 4; mi++)
            af[mi] = *(const bf16x8*)((const char*)&As[buf][0] +
                      ((((wm << 6) + (mi << 4) + fr)) << 7) + ((64 | qb) ^ xr));
#pragma unroll
        for (int nj = 0; nj < 4; nj++)
            bfv[nj] = *(const bf16x8*)((const char*)&Bs[buf][0] +
                      ((((wn << 6) + (nj << 4) + fr)) << 7) + ((64 | qb) ^ xr));
        if (pf) stageB(kn, buf ^ 1);
        __builtin_amdgcn_s_barrier();
        __builtin_amdgcn_s_setprio(1);
#pragma unroll
        for (int mi = 0; mi < 4; mi++)
#pragma unroll
            for (int nj = 0; nj < 4; nj++)
                acc[mi][nj] = __builtin_amdgcn_mfma_f32_16x16x32_bf16(af[mi], bfv[nj], acc[mi][nj], 0, 0, 0);
        __builtin_amdgcn_s_setprio(0);
        __syncthreads();
    }

    const int seg = (NSEG > 1) ? (n0 >> 10) : 0;
    u16* outp = fa.out[seg];
    const float* bp = fa.bias[seg];
    const float scl = fa.scale[seg];
    const bool vtr = (NSEG > 1) && (seg == fa.vseg);

    const int colbase = n0 + (wn << 6);
    const int rowbase = m0 + (wm << 6) + ((lane >> 4) << 2);
#pragma unroll
    for (int j = 0; j < 4; j++) {
        const int col = colbase + (j << 4) + fr;
        const int cl  = col & (EE - 1);
        const float bv = bp[cl];
#pragma unroll
        for (int i = 0; i < 4; i++) {
            if (vtr) {
                const int row0 = rowbase + (i << 4);
                const int bb = row0 >> 12, t = row0 & (TT - 1);
                const int hh = cl >> 6, d = cl & 63;
                ushort4 pk;
                pk.x = f2bf((acc[i][j][0] + bv) * scl);
                pk.y = f2bf((acc[i][j][1] + bv) * scl);
                pk.z = f2bf((acc[i][j][2] + bv) * scl);
                pk.w = f2bf((acc[i][j][3] + bv) * scl);
                *(ushort4*)(outp + (((size_t)(bb * HH + hh) * DD + d) * TT + t)) = pk;
            } else {
#pragma unroll
                for (int r = 0; r < 4; r++) {
                    const int row = rowbase + (i << 4) + r;
                    const float val = (acc[i][j][r] + bv) * scl;
                    const size_t drow = PERMC ? (size_t)(((row & (TT - 1)) << 1) | (row >> 12))
                                              : (size_t)row;
                    if (CF32) ((float*)outp)[drow * EE + cl] = val;
                    else      outp[drow * EE + cl] = f2bf(val);
                }
            }
        }
    }
}

// ---------- band attention: S^T softmax + async staging + defer-max + exp2 ----------
__global__ __launch_bounds__(256) void band_attn_kernel(
    const u16* __restrict__ q, const u16* __restrict__ k, const u16* __restrict__ vt,
    u16* __restrict__ attnb)
{
    const int tid  = threadIdx.x;
    const int lane = tid & 63;
    const int w    = tid >> 6;
    const int col  = lane & 15;
    const int quad = lane >> 4;

    const int qt = blockIdx.x >> 5;
    const int bh = blockIdx.x & 31;
    const int h  = bh & (HH - 1);
    const int b  = bh >> 4;
    const int t0 = qt << 6;

    __shared__ __align__(16) u16 Ks[2][64][72];   // [buf][key][dim]
    __shared__ __align__(16) u16 Vs[2][64][72];   // [buf][dim][key]
    __shared__ __align__(16) u16 Ps[4][16][72];   // [wave][q][k]

    const size_t base   = (size_t)b * TT * EE + (size_t)h * DD;
    const size_t vtbase = (size_t)bh * DD * TT;

    const u16* qp = q + base + (size_t)(t0 + (w << 4) + col) * EE + (quad << 3);
    const bf16x8 qf0 = *(const bf16x8*)qp;
    const bf16x8 qf1 = *(const bf16x8*)(qp + 32);

    float m_i = -1e30f, l_i = 0.f;
    f32x4 acc_o[4];
#pragma unroll
    for (int nt = 0; nt < 4; nt++) acc_o[nt] = (f32x4){0.f, 0.f, 0.f, 0.f};

    const int c_lo = 1 + ((t0 < WQ) ? ((WQ - t0) >> 6) : 0);
    const int c_hi = min(9, 1 + ((TT + WQ - 64 - t0) >> 6));
    const int NTL  = 2 + c_hi - c_lo;              // tiles: 1 global + window tiles

    const int srow  = tid >> 2;
    const int spart = (tid & 3) << 4;

    uint4 kr0, kr1, vr0, vr1;                      // staging regs (in flight)
    auto issue_loads = [&](int i) {
        const int kpos0 = (i == 0) ? 0 : (t0 - WQ + ((c_lo + i - 2) << 6));
        const u16* ks = k + base + (size_t)(kpos0 + srow) * EE + spart;
        const u16* vs = vt + vtbase + (size_t)srow * TT + kpos0 + spart;
        kr0 = *(const uint4*)ks;
        kr1 = *(const uint4*)(ks + 8);
        vr0 = *(const uint4*)vs;
        vr1 = *(const uint4*)(vs + 8);
    };
    auto write_stage = [&](int buf) {
        *(uint4*)&Ks[buf][srow][spart]     = kr0;
        *(uint4*)&Ks[buf][srow][spart + 8] = kr1;
        *(uint4*)&Vs[buf][srow][spart]     = vr0;
        *(uint4*)&Vs[buf][srow][spart + 8] = vr1;
    };

    issue_loads(0);
    write_stage(0);
    int buf = 0;

    const int qrow = (w << 4) + col;               // this lane's query row (rel t0)
    const int alsrc0 = (lane & 48) | ((lane >> 2) & 12);  // lane holding alpha/l for row quad*4+r

#pragma unroll 1
    for (int i = 0; i < NTL; i++) {
        __syncthreads();                           // LDS[buf] ready for all waves
        const int c     = c_lo + i - 1;            // window chunk id (i>=1)
        const int jbase = (i > 0 && (c == 1 || c == 9)) ? ((c - 1) << 6) : -1;
        const bool pf   = (i + 1 < NTL);
        if (pf) issue_loads(i + 1);                // latency hides under compute

        // QK^T transposed: sT[nt] row=key(quad*4+r), col=q
        f32x4 sT[4];
#pragma unroll
        for (int nt = 0; nt < 4; nt++) {
            const bf16x8 kf0 = *(const bf16x8*)&Ks[buf][(nt << 4) + col][quad << 3];
            const bf16x8 kf1 = *(const bf16x8*)&Ks[buf][(nt << 4) + col][32 + (quad << 3)];
            f32x4 s = (f32x4){0.f, 0.f, 0.f, 0.f};
            s = __builtin_amdgcn_mfma_f32_16x16x32_bf16(kf0, qf0, s, 0, 0, 0);
            s = __builtin_amdgcn_mfma_f32_16x16x32_bf16(kf1, qf1, s, 0, 0, 0);
            sT[nt] = s;
        }

        if (jbase >= 0) {
#pragma unroll
            for (int nt = 0; nt < 4; nt++) {
#pragma unroll
                for (int r = 0; r < 4; r++) {
                    const int jp = jbase + (nt << 4) + (quad << 2) + r;
                    const bool ok = (jp >= qrow) && (jp <= qrow + 2 * WQ);
                    if (!ok) sT[nt][r] = -1e30f;
                }
            }
        }

        // per-lane online softmax over this lane's 16 keys + cross-quad reduce
        float mx = sT[0][0];
#pragma unroll
        for (int nt = 0; nt < 4; nt++)
#pragma unroll
            for (int r = 0; r < 4; r++) mx = fmaxf(mx, sT[nt][r]);
        mx = fmaxf(mx, __shfl_xor(mx, 16));
        mx = fmaxf(mx, __shfl_xor(mx, 32));

        // T13 defer-max (log2 units): skip rescale when growth <= 11 (P <= 2^11)
        if (!__all(mx - m_i <= 11.0f)) {
            const float m_new = fmaxf(m_i, mx);
            const float alpha = fast_exp2(m_i - m_new);
            m_i = m_new;
            l_i *= alpha;
            float al[4];
#pragma unroll
            for (int r = 0; r < 4; r++) al[r] = __shfl(alpha, alsrc0 | r);
#pragma unroll
            for (int nt = 0; nt < 4; nt++)
#pragma unroll
                for (int r = 0; r < 4; r++) acc_o[nt][r] *= al[r];
        }

        float ps = 0.f;
#pragma unroll
        for (int nt = 0; nt < 4; nt++)
#pragma unroll
            for (int r = 0; r < 4; r++) {
                const float e = fast_exp2(sT[nt][r] - m_i);
                sT[nt][r] = e;
                ps += e;
            }
        ps += __shfl_xor(ps, 16);
        ps += __shfl_xor(ps, 32);
        l_i += ps;

        // P pack + write: row q=col, k = nt*16 + quad*4 + {0..3}
#pragma unroll
        for (int nt = 0; nt < 4; nt++) {
            uint2 pk2;
            pk2.x = cvt_pk_bf16(sT[nt][0], sT[nt][1]);
            pk2.y = cvt_pk_bf16(sT[nt][2], sT[nt][3]);
            *(uint2*)&Ps[w][col][(nt << 4) + (quad << 2)] = pk2;
        }

        const bf16x8 pf0 = *(const bf16x8*)&Ps[w][col][quad << 3];
        const bf16x8 pf1 = *(const bf16x8*)&Ps[w][col][32 + (quad << 3)];

#pragma unroll
        for (int nt = 0; nt < 4; nt++) {
            const bf16x8 vf0 = *(const bf16x8*)&Vs[buf][(nt << 4) + col][quad << 3];
            const bf16x8 vf1 = *(const bf16x8*)&Vs[buf][(nt << 4) + col][32 + (quad << 3)];
            acc_o[nt] = __builtin_amdgcn_mfma_f32_16x16x32_bf16(pf0, vf0, acc_o[nt], 0, 0, 0);
            acc_o[nt] = __builtin_amdgcn_mfma_f32_16x16x32_bf16(pf1, vf1, acc_o[nt], 0, 0, 0);
        }

        if (pf) write_stage(buf ^ 1);              // regs -> other buffer (no barrier needed)
        buf ^= 1;
    }

    float inv[4];
#pragma unroll
    for (int r = 0; r < 4; r++) inv[r] = 1.f / __shfl(l_i, alsrc0 | r);
#pragma unroll
    for (int nt = 0; nt < 4; nt++) {
#pragma unroll
        for (int r = 0; r < 4; r++) {
            const int t = t0 + (w << 4) + (quad << 2) + r;
            attnb[base + (size_t)t * EE + (nt << 4) + col] = f2bf(acc_o[nt][r] * inv[r]);
        }
    }
}

// ---------- global-token attention: swapped QK^T + transposed V + defer-max + exp2 ----------
__global__ __launch_bounds__(256) void global_attn_flash_kernel(
    const u16* __restrict__ qg, const u16* __restrict__ kg, const u16* __restrict__ vgt,
    float* __restrict__ Op, float* __restrict__ Ml, float* __restrict__ Ll)
{
    const int tid  = threadIdx.x;
    const int lane = tid & 63;
    const int w    = tid >> 6;
    const int col  = lane & 15;
    const int quad = lane >> 4;

    const int s  = blockIdx.x & (NSPLIT - 1);
    const int h  = (blockIdx.x >> 4) & (HH - 1);
    const int b  = blockIdx.x >> 8;
    const int k0pos = s * (TT / NSPLIT);

    __shared__ __align__(16) u16 Ks[2][64][72];   // [buf][key][dim]
    __shared__ __align__(16) u16 Vs[2][64][72];   // [buf][dim][key]
    __shared__ __align__(16) u16 Ps[4][16][72];   // [wave][q][k]

    const size_t base   = (size_t)b * TT * EE + (size_t)h * DD;        // kg row-major
    const size_t vtbase = (size_t)((b << 4) | h) * DD * TT;            // vgt [B,H,D,T]

    const u16* qp = qg + (size_t)(b * GG + (w << 4) + col) * EE + (size_t)h * DD + (quad << 3);
    const bf16x8 qf0 = *(const bf16x8*)qp;
    const bf16x8 qf1 = *(const bf16x8*)(qp + 32);

    float m_i = -1e30f, l_i = 0.f;
    f32x4 acc_o[4];
#pragma unroll
    for (int nt = 0; nt < 4; nt++) acc_o[nt] = (f32x4){0.f, 0.f, 0.f, 0.f};

    constexpr int NTL = TT / NSPLIT / 64;          // 4 key tiles per split
    const int srow  = tid >> 2;
    const int spart = (tid & 3) << 4;

    uint4 kr0, kr1, vr0, vr1;
    auto issue_loads = [&](int i) {
        const int kpos0 = k0pos + (i << 6);
        const u16* ks = kg + base + (size_t)(kpos0 + srow) * EE + spart;
        const u16* vs = vgt + vtbase + (size_t)srow * TT + kpos0 + spart;
        kr0 = *(const uint4*)ks;
        kr1 = *(const uint4*)(ks + 8);
        vr0 = *(const uint4*)vs;
        vr1 = *(const uint4*)(vs + 8);
    };
    auto write_stage = [&](int buf) {
        *(uint4*)&Ks[buf][srow][spart]     = kr0;
        *(uint4*)&Ks[buf][srow][spart + 8] = kr1;
        *(uint4*)&Vs[buf][srow][spart]     = vr0;
        *(uint4*)&Vs[buf][srow][spart + 8] = vr1;
    };

    issue_loads(0);
    write_stage(0);
    int buf = 0;

    const int alsrc0 = (lane & 48) | ((lane >> 2) & 12);

#pragma unroll 1
    for (int i = 0; i < NTL; i++) {
        __syncthreads();
        const bool pf = (i + 1 < NTL);
        if (pf) issue_loads(i + 1);

        f32x4 sT[4];
#pragma unroll
        for (int nt = 0; nt < 4; nt++) {
            const bf16x8 kf0 = *(const bf16x8*)&Ks[buf][(nt << 4) + col][quad << 3];
            const bf16x8 kf1 = *(const bf16x8*)&Ks[buf][(nt << 4) + col][32 + (quad << 3)];
            f32x4 sv = (f32x4){0.f, 0.f, 0.f, 0.f};
            sv = __builtin_amdgcn_mfma_f32_16x16x32_bf16(kf0, qf0, sv, 0, 0, 0);
            sv = __builtin_amdgcn_mfma_f32_16x16x32_bf16(kf1, qf1, sv, 0, 0, 0);
            sT[nt] = sv;
        }

        float mx = sT[0][0];
#pragma unroll
        for (int nt = 0; nt < 4; nt++)
#pragma unroll
            for (int r = 0; r < 4; r++) mx = fmaxf(mx, sT[nt][r]);
        mx = fmaxf(mx, __shfl_xor(mx, 16));
        mx = fmaxf(mx, __shfl_xor(mx, 32));

        if (!__all(mx - m_i <= 11.0f)) {
            const float m_new = fmaxf(m_i, mx);
            const float alpha = fast_exp2(m_i - m_new);
            m_i = m_new;
            l_i *= alpha;
            float al[4];
#pragma unroll
            for (int r = 0; r < 4; r++) al[r] = __shfl(alpha, alsrc0 | r);
#pragma unroll
            for (int nt = 0; nt < 4; nt++)
#pragma unroll
                for (int r = 0; r < 4; r++) acc_o[nt][r] *= al[r];
        }

        float ps = 0.f;
#pragma unroll
        for (int nt = 0; nt < 4; nt++)
#pragma unroll
            for (int r = 0; r < 4; r++) {
                const float e = fast_exp2(sT[nt][r] - m_i);
                sT[nt][r] = e;
                ps += e;
            }
        ps += __shfl_xor(ps, 16);
        ps += __shfl_xor(ps, 32);
        l_i += ps;

#pragma unroll
        for (int nt = 0; nt < 4; nt++) {
            uint2 pk2;
            pk2.x = cvt_pk_bf16(sT[nt][0], sT[nt][1]);
            pk2.y = cvt_pk_bf16(sT[nt][2], sT[nt][3]);
            *(uint2*)&Ps[w][col][(nt << 4) + (quad << 2)] = pk2;
        }

        const bf16x8 pf0 = *(const bf16x8*)&Ps[w][col][quad << 3];
        const bf16x8 pf1 = *(const bf16x8*)&Ps[w][col][32 + (quad << 3)];

#pragma unroll
        for (int nt = 0; nt < 4; nt++) {
            const bf16x8 vf0 = *(const bf16x8*)&Vs[buf][(nt << 4) + col][quad << 3];
            const bf16x8 vf1 = *(const bf16x8*)&Vs[buf][(nt << 4) + col][32 + (quad << 3)];
            acc_o[nt] = __builtin_amdgcn_mfma_f32_16x16x32_bf16(pf0, vf0, acc_o[nt], 0, 0, 0);
            acc_o[nt] = __builtin_amdgcn_mfma_f32_16x16x32_bf16(pf1, vf1, acc_o[nt], 0, 0, 0);
        }

        if (pf) write_stage(buf ^ 1);
        buf ^= 1;
    }

    const size_t obase = (size_t)blockIdx.x * GG * DD;
#pragma unroll
    for (int nt = 0; nt < 4; nt++) {
#pragma unroll
        for (int r = 0; r < 4; r++) {
            const int row = (w << 4) + (quad << 2) + r;
            Op[obase + (size_t)row * DD + (nt << 4) + col] = acc_o[nt][r];
        }
    }
    if (quad == 0) {
        Ml[blockIdx.x * GG + (w << 4) + col] = m_i;
        Ll[blockIdx.x * GG + (w << 4) + col] = l_i;
    }
}

// ---------- combine split-K partials (m/l are in log2 units -> exp2) ----------
__global__ __launch_bounds__(256) void global_combine_kernel(
    const float* __restrict__ Op, const float* __restrict__ Ml, const float* __restrict__ Ll,
    u16* __restrict__ attnb)
{
    const int bh  = blockIdx.x;
    const int b   = bh >> 4;
    const int h   = bh & (HH - 1);
    const int row = threadIdx.x >> 2;
    const int d0  = (threadIdx.x & 3) << 4;

    float mv[NSPLIT];
    float m = -1e30f;
#pragma unroll
    for (int s = 0; s < NSPLIT; s++) {
        mv[s] = Ml[(bh * NSPLIT + s) * GG + row];
        m = fmaxf(m, mv[s]);
    }
    float l = 0.f;
    float sc[NSPLIT];
#pragma unroll
    for (int s = 0; s < NSPLIT; s++) {
        sc[s] = fast_exp2(mv[s] - m);
        l += Ll[(bh * NSPLIT + s) * GG + row] * sc[s];
    }
    float o[16];
#pragma unroll
    for (int j = 0; j < 16; j++) o[j] = 0.f;
#pragma unroll
    for (int s = 0; s < NSPLIT; s++) {
        const float* src = Op + ((size_t)(bh * NSPLIT + s) * GG + row) * DD + d0;
        const float f = sc[s];
#pragma unroll
        for (int j = 0; j < 16; j += 4) {
            const float4 v4 = *(const float4*)(src + j);
            o[j + 0] = fmaf(v4.x, f, o[j + 0]);
            o[j + 1] = fmaf(v4.y, f, o[j + 1]);
            o[j + 2] = fmaf(v4.z, f, o[j + 2]);
            o[j + 3] = fmaf(v4.w, f, o[j + 3]);
        }
    }
    const float inv = 1.f / l;
    u16* dst = attnb + ((size_t)b * TT + row) * EE + (size_t)h * DD + d0;
#pragma unroll
    for (int j = 0; j < 16; j++) dst[j] = f2bf(o[j] * inv);
}

extern "C" void kernel_launch(void* const* d_in, const int* in_sizes, int n_in,
                              void* d_out, int out_size, void* d_ws, size_t ws_size,
                              hipStream_t stream)
{
    (void)in_sizes; (void)n_in; (void)out_size; (void)ws_size;
    const float* query = (const float*)d_in[0];
    const float* Wq  = (const float*)d_in[2];  const float* bq  = (const float*)d_in[3];
    const float* Wk  = (const float*)d_in[4];  const float* bk  = (const float*)d_in[5];
    const float* Wv  = (const float*)d_in[6];  const float* bv  = (const float*)d_in[7];
    const float* Wqg = (const float*)d_in[8];  const float* bqg = (const float*)d_in[9];
    const float* Wkg = (const float*)d_in[10]; const float* bkg = (const float*)d_in[11];
    const float* Wvg = (const float*)d_in[12]; const float* bvg = (const float*)d_in[13];
    const float* Wo  = (const float*)d_in[14]; const float* bo  = (const float*)d_in[15];

    const size_t nfull = (size_t)BBATCH * TT * EE;      // 8.39M elems
    const size_t wsz   = (size_t)1 << 20;               // one weight, elems
    u16* xb    = (u16*)d_ws;                            // bf16 x [B,T,E]; later reused as attnb
    u16* wb    = xb + nfull;                            // 7 converted weights
    u16* slotA = wb + 7 * wsz;                          // kg, then q
    u16* slotB = slotA + nfull;                         // vgt, then k
    u16* slotC = slotB + nfull;                         // vt [B,H,D,T]
    u16* qg    = slotC + nfull;                         // [B*G, E]
    float* Op  = (float*)(qg + (size_t)BBATCH * GG * EE);
    float* Ml  = Op + (size_t)BBATCH * HH * NSPLIT * GG * DD;
    float* Ll  = Ml + (size_t)BBATCH * HH * NSPLIT * GG;
    u16* attnb = xb;                                    // alias: xb dead after last GEMM that reads it
    // peak ws ≈ 90 MB (Op grew with NSPLIT=16)

    WPtrs wp;   // order: fuse3 (Wq,Wk,Wv) | fuse2 (Wkg,Wvg) | Wqg | Wo
    wp.p[0] = Wq; wp.p[1] = Wk; wp.p[2] = Wv;
    wp.p[3] = Wkg; wp.p[4] = Wvg; wp.p[5] = Wqg; wp.p[6] = Wo;

    const dim3 blk(256);
    const dim3 gF2(16, 64);     // 128^2 tiles, N=2048
    const dim3 gF3(24, 64);     // 128^2 tiles, N=3072
    const dim3 gFull(8, 64);    // 128^2 tiles, N=1024 (Wo)
    const dim3 gQg(8, 1);       // 128^2 tiles, N=1024, M=128 (qg, PERMA gather)
    const float sc = 0.125f * LOG2E;   // D^-0.5, pre-scaled for exp2 softmax

    conv_kernel<<<7680, blk, 0, stream>>>(wp, query, wb, xb);

    // qg projection (reads xb) — pipelined kernel with PERMA row gather
    FusedArgs faQ;
    faQ.out[0] = qg;  faQ.out[1] = nullptr; faQ.out[2] = nullptr;
    faQ.bias[0] = bqg; faQ.bias[1] = nullptr; faQ.bias[2] = nullptr;
    faQ.scale[0] = sc; faQ.scale[1] = 1.f;    faQ.scale[2] = 1.f;
    faQ.vseg = -1;
    gemm_pipe_kernel<1, 0, 0, 1><<<gQg, blk, 0, stream>>>(xb, wb + 5 * wsz, faQ);

    // fused kg|vgt projection (vg written transposed per head for the flash)
    FusedArgs fa2;
    fa2.out[0] = slotA; fa2.out[1] = slotB; fa2.out[2] = nullptr;
    fa2.bias[0] = bkg;  fa2.bias[1] = bvg;  fa2.bias[2] = nullptr;
    fa2.scale[0] = 1.f; fa2.scale[1] = 1.f; fa2.scale[2] = 1.f;
    fa2.vseg = 1;
    gemm_pipe_kernel<2, 0, 0, 0><<<gF2, blk, 0, stream>>>(xb, wb + 3 * wsz, fa2);
    global_attn_flash_kernel<<<BBATCH * HH * NSPLIT, blk, 0, stream>>>(qg, slotA, slotB, Op, Ml, Ll);

    // fused q|k|vt projection (q pre-scaled by D^-0.5 * log2e for exp2 softmax)
    FusedArgs fa3;
    fa3.out[0] = slotA; fa3.out[1] = slotB; fa3.out[2] = slotC;
    fa3.bias[0] = bq;   fa3.bias[1] = bk;   fa3.bias[2] = bv;
    fa3.scale[0] = sc;  fa3.scale[1] = 1.f; fa3.scale[2] = 1.f;
    fa3.vseg = 2;
    gemm_pipe_kernel<3, 0, 0, 0><<<gF3, blk, 0, stream>>>(xb, wb, fa3);

    band_attn_kernel<<<BBATCH * HH * (TT / 64), blk, 0, stream>>>(slotA, slotB, slotC, attnb);
    global_combine_kernel<<<BBATCH * HH, blk, 0, stream>>>(Op, Ml, Ll, attnb);

    // output projection (128^2 pipelined, f32 out, [B,T]->[T,B] row perm)
    FusedArgs faO;
    faO.out[0] = (u16*)d_out; faO.out[1] = nullptr; faO.out[2] = nullptr;
    faO.bias[0] = bo;         faO.bias[1] = nullptr; faO.bias[2] = nullptr;
    faO.scale[0] = 1.f;       faO.scale[1] = 1.f;    faO.scale[2] = 1.f;
    faO.vseg = -1;
    gemm_pipe_kernel<1, 1, 1, 0><<<gFull, blk, 0, stream>>>(attnb, wb + 6 * wsz, faO);
}

// Round 11
// 339.471 us; speedup vs baseline: 1.0055x; 1.0055x over previous
//
#include <hip/hip_runtime.h>
#include <hip/hip_bf16.h>

typedef unsigned short u16;
typedef __bf16 bf16x8 __attribute__((ext_vector_type(8)));
typedef float  f32x4  __attribute__((ext_vector_type(4)));

constexpr int TT = 4096;   // seq
constexpr int BBATCH = 2;  // batch
constexpr int EE = 1024;   // embed
constexpr int HH = 16;     // heads
constexpr int DD = 64;     // head dim
constexpr int WQ = 256;    // one-sided window
constexpr int GG = 64;     // global tokens
constexpr int NSPLIT = 8;  // key splits for global attention (16 regressed: 2x Op traffic)
constexpr float LOG2E = 1.4426950408889634f;

// ---------- bf16 / math helpers ----------
__device__ __forceinline__ float fast_exp2(float x) {
    return __builtin_amdgcn_exp2f(x);   // native v_exp_f32 (2^x)
}
__device__ __forceinline__ u16 f2bf(float f) {
    union { float f; unsigned int i; } c; c.f = f;
    unsigned int x = c.i;
    return (u16)((x + 0x7fffu + ((x >> 16) & 1u)) >> 16);  // RNE
}
__device__ __forceinline__ unsigned cvt_pk_bf16(float a, float b) {
    unsigned r;
    asm("v_cvt_pk_bf16_f32 %0, %1, %2" : "=v"(r) : "v"(a), "v"(b));
    return r;  // low16 = bf16(a), high16 = bf16(b), RNE
}
__device__ __forceinline__ uint4 pack8(float4 a, float4 b) {
    uint4 r;
    r.x = (unsigned)f2bf(a.x) | ((unsigned)f2bf(a.y) << 16);
    r.y = (unsigned)f2bf(a.z) | ((unsigned)f2bf(a.w) << 16);
    r.z = (unsigned)f2bf(b.x) | ((unsigned)f2bf(b.y) << 16);
    r.w = (unsigned)f2bf(b.z) | ((unsigned)f2bf(b.w) << 16);
    return r;
}

// async global->LDS, 16B per lane; LDS dest = wave-uniform base + lane*16
__device__ __forceinline__ void g2l16(const u16* g, u16* l) {
    __builtin_amdgcn_global_load_lds(
        (const __attribute__((address_space(1))) void*)g,
        (__attribute__((address_space(3))) void*)l, 16, 0, 0);
}

// XCD swizzle: blocks sharing an M-tile (y) get linear ids == c (mod 8) -> one XCD's L2
__device__ __forceinline__ void xcd_swizzle(int& bx, int& by) {
    bx = blockIdx.x; by = blockIdx.y;
    if ((gridDim.y & 7) == 0) {
        const int g   = blockIdx.x + blockIdx.y * gridDim.x;
        const int idx = g >> 3;
        bx = idx % gridDim.x;
        by = (g & 7) + ((idx / gridDim.x) << 3);
    }
}

// ---------- fp32 -> bf16 conversion ----------
struct WPtrs { const float* p[7]; };
__global__ __launch_bounds__(256) void conv_kernel(
    WPtrs wp, const float* __restrict__ query, u16* __restrict__ wb, u16* __restrict__ xb)
{
    const size_t i8 = ((size_t)blockIdx.x * 256 + threadIdx.x) << 3;
    const size_t WTOT = (size_t)7 << 20;   // 7 x 1024*1024
    const float* src;
    u16* dst;
    if (i8 < WTOT) {
        const int which = (int)(i8 >> 20);
        src = wp.p[which] + (i8 & (((size_t)1 << 20) - 1));
        dst = wb + i8;
    } else {
        const size_t j = i8 - WTOT;            // dst index in [B,T,E]
        const size_t e = j & (EE - 1);
        const size_t t = (j >> 10) & (TT - 1);
        const size_t b = j >> 22;
        src = query + (t * BBATCH + b) * EE + e;
        dst = xb + j;
    }
    const float4 f0 = *(const float4*)src;
    const float4 f1 = *(const float4*)(src + 4);
    *(uint4*)dst = pack8(f0, f1);
}

struct FusedArgs { u16* out[3]; const float* bias[3]; float scale[3]; int vseg; };

// ---------- pipelined 128x128 GEMM (verified best: 0 bank conflicts, 2 blocks/CU) ----------
// PERMA: logical row m reads source row (m>>6)*4096 + (m&63)  (x[:, :G] gather for qg)
template<int NSEG, int CF32, int PERMC, int PERMA>
__global__ __launch_bounds__(256, 2) void gemm_pipe_kernel(
    const u16* __restrict__ A, const u16* __restrict__ W, FusedArgs fa)
{
    const int tid = threadIdx.x, lane = tid & 63, w = tid >> 6;
    const int wm = w >> 1, wn = w & 1;
    int bx, by;
    xcd_swizzle(bx, by);
    const int m0 = by << 7, n0 = bx << 7;

    __shared__ __align__(16) u16 As[2][8192];   // [buf][128][64], swizzled
    __shared__ __align__(16) u16 Bs[2][8192];

    const int srow = lane >> 3;                        // 0..7 (== dest row & 7)
    const int scol = ((lane & 7) ^ srow) << 3;         // pre-swizzled source col (elems)
    auto arow = [](int m) -> size_t {
        return PERMA ? (size_t)(((m >> 6) << 12) | (m & 63)) : (size_t)m;
    };
    const u16* gB = W + (size_t)(n0 + (w << 5) + srow) * EE + scol;
    u16* lA = &As[0][0] + (w << 11);
    u16* lB = &Bs[0][0] + (w << 11);

    f32x4 acc[4][4];
#pragma unroll
    for (int i = 0; i < 4; i++)
#pragma unroll
        for (int j = 0; j < 4; j++)
            acc[i][j] = (f32x4){0.f, 0.f, 0.f, 0.f};

    const int fr = lane & 15;
    const int qb = (lane >> 4) << 4;                   // frag 16B-chunk byte col
    const int xr = (fr & 7) << 4;                      // read-side swizzle XOR

    auto stageA = [&](int k0, int buf) {
#pragma unroll
        for (int l = 0; l < 4; l++) {
            const int row = m0 + (w << 5) + srow + (l << 3);
            g2l16(A + arow(row) * EE + scol + k0, lA + buf * 8192 + (l << 9));
        }
    };
    auto stageB = [&](int k0, int buf) {
#pragma unroll
        for (int l = 0; l < 4; l++)
            g2l16(gB + (size_t)(l << 3) * EE + k0, lB + buf * 8192 + (l << 9));
    };

    stageA(0, 0);
    stageB(0, 0);
    __syncthreads();

    constexpr int NT = EE / 64;                        // 16 K-tiles
#pragma unroll 2
    for (int t = 0; t < NT; t++) {
        const int buf = t & 1;
        const bool pf = (t + 1 < NT);
        const int kn = (t + 1) << 6;
        bf16x8 af[4], bfv[4];

        // ---- phase 0 : k-half 0 ----
#pragma unroll
        for (int mi = 0; mi < 4; mi++)
            af[mi] = *(const bf16x8*)((const char*)&As[buf][0] +
                      ((((wm << 6) + (mi << 4) + fr)) << 7) + (qb ^ xr));
#pragma unroll
        for (int nj = 0; nj < 4; nj++)
            bfv[nj] = *(const bf16x8*)((const char*)&Bs[buf][0] +
                      ((((wn << 6) + (nj << 4) + fr)) << 7) + (qb ^ xr));
        if (pf) stageA(kn, buf ^ 1);
        __builtin_amdgcn_s_barrier();
        __builtin_amdgcn_s_setprio(1);
#pragma unroll
        for (int mi = 0; mi < 4; mi++)
#pragma unroll
            for (int nj = 0; nj < 4; nj++)
                acc[mi][nj] = __builtin_amdgcn_mfma_f32_16x16x32_bf16(af[mi], bfv[nj], acc[mi][nj], 0, 0, 0);
        __builtin_amdgcn_s_setprio(0);
        __builtin_amdgcn_s_barrier();

        // ---- phase 1 : k-half 1 ----
#pragma unroll
        for (int mi = 0; mi < 4; mi++)
            af[mi] = *(const bf16x8*)((const char*)&As[buf][0] +
                      ((((wm << 6) + (mi << 4) + fr)) << 7) + ((64 | qb) ^ xr));
#pragma unroll
        for (int nj = 0; nj < 4; nj++)
            bfv[nj] = *(const bf16x8*)((const char*)&Bs[buf][0] +
                      ((((wn << 6) + (nj << 4) + fr)) << 7) + ((64 | qb) ^ xr));
        if (pf) stageB(kn, buf ^ 1);
        __builtin_amdgcn_s_barrier();
        __builtin_amdgcn_s_setprio(1);
#pragma unroll
        for (int mi = 0; mi < 4; mi++)
#pragma unroll
            for (int nj = 0; nj < 4; nj++)
                acc[mi][nj] = __builtin_amdgcn_mfma_f32_16x16x32_bf16(af[mi], bfv[nj], acc[mi][nj], 0, 0, 0);
        __builtin_amdgcn_s_setprio(0);
        __syncthreads();
    }

    const int seg = (NSEG > 1) ? (n0 >> 10) : 0;
    u16* outp = fa.out[seg];
    const float* bp = fa.bias[seg];
    const float scl = fa.scale[seg];
    const bool vtr = (NSEG > 1) && (seg == fa.vseg);

    const int colbase = n0 + (wn << 6);
    const int rowbase = m0 + (wm << 6) + ((lane >> 4) << 2);
#pragma unroll
    for (int j = 0; j < 4; j++) {
        const int col = colbase + (j << 4) + fr;
        const int cl  = col & (EE - 1);
        const float bv = bp[cl];
#pragma unroll
        for (int i = 0; i < 4; i++) {
            if (vtr) {
                const int row0 = rowbase + (i << 4);
                const int bb = row0 >> 12, t = row0 & (TT - 1);
                const int hh = cl >> 6, d = cl & 63;
                ushort4 pk;
                pk.x = f2bf((acc[i][j][0] + bv) * scl);
                pk.y = f2bf((acc[i][j][1] + bv) * scl);
                pk.z = f2bf((acc[i][j][2] + bv) * scl);
                pk.w = f2bf((acc[i][j][3] + bv) * scl);
                *(ushort4*)(outp + (((size_t)(bb * HH + hh) * DD + d) * TT + t)) = pk;
            } else {
#pragma unroll
                for (int r = 0; r < 4; r++) {
                    const int row = rowbase + (i << 4) + r;
                    const float val = (acc[i][j][r] + bv) * scl;
                    const size_t drow = PERMC ? (size_t)(((row & (TT - 1)) << 1) | (row >> 12))
                                              : (size_t)row;
                    if (CF32) ((float*)outp)[drow * EE + cl] = val;
                    else      outp[drow * EE + cl] = f2bf(val);
                }
            }
        }
    }
}

// ---------- band attention: S^T softmax + async staging + defer-max + exp2 ----------
__global__ __launch_bounds__(256) void band_attn_kernel(
    const u16* __restrict__ q, const u16* __restrict__ k, const u16* __restrict__ vt,
    u16* __restrict__ attnb)
{
    const int tid  = threadIdx.x;
    const int lane = tid & 63;
    const int w    = tid >> 6;
    const int col  = lane & 15;
    const int quad = lane >> 4;

    const int qt = blockIdx.x >> 5;
    const int bh = blockIdx.x & 31;
    const int h  = bh & (HH - 1);
    const int b  = bh >> 4;
    const int t0 = qt << 6;

    __shared__ __align__(16) u16 Ks[2][64][72];   // [buf][key][dim]
    __shared__ __align__(16) u16 Vs[2][64][72];   // [buf][dim][key]
    __shared__ __align__(16) u16 Ps[4][16][72];   // [wave][q][k]

    const size_t base   = (size_t)b * TT * EE + (size_t)h * DD;
    const size_t vtbase = (size_t)bh * DD * TT;

    const u16* qp = q + base + (size_t)(t0 + (w << 4) + col) * EE + (quad << 3);
    const bf16x8 qf0 = *(const bf16x8*)qp;
    const bf16x8 qf1 = *(const bf16x8*)(qp + 32);

    float m_i = -1e30f, l_i = 0.f;
    f32x4 acc_o[4];
#pragma unroll
    for (int nt = 0; nt < 4; nt++) acc_o[nt] = (f32x4){0.f, 0.f, 0.f, 0.f};

    const int c_lo = 1 + ((t0 < WQ) ? ((WQ - t0) >> 6) : 0);
    const int c_hi = min(9, 1 + ((TT + WQ - 64 - t0) >> 6));
    const int NTL  = 2 + c_hi - c_lo;              // tiles: 1 global + window tiles

    const int srow  = tid >> 2;
    const int spart = (tid & 3) << 4;

    uint4 kr0, kr1, vr0, vr1;                      // staging regs (in flight)
    auto issue_loads = [&](int i) {
        const int kpos0 = (i == 0) ? 0 : (t0 - WQ + ((c_lo + i - 2) << 6));
        const u16* ks = k + base + (size_t)(kpos0 + srow) * EE + spart;
        const u16* vs = vt + vtbase + (size_t)srow * TT + kpos0 + spart;
        kr0 = *(const uint4*)ks;
        kr1 = *(const uint4*)(ks + 8);
        vr0 = *(const uint4*)vs;
        vr1 = *(const uint4*)(vs + 8);
    };
    auto write_stage = [&](int buf) {
        *(uint4*)&Ks[buf][srow][spart]     = kr0;
        *(uint4*)&Ks[buf][srow][spart + 8] = kr1;
        *(uint4*)&Vs[buf][srow][spart]     = vr0;
        *(uint4*)&Vs[buf][srow][spart + 8] = vr1;
    };

    issue_loads(0);
    write_stage(0);
    int buf = 0;

    const int qrow = (w << 4) + col;               // this lane's query row (rel t0)
    const int alsrc0 = (lane & 48) | ((lane >> 2) & 12);  // lane holding alpha/l for row quad*4+r

#pragma unroll 1
    for (int i = 0; i < NTL; i++) {
        __syncthreads();                           // LDS[buf] ready for all waves
        const int c     = c_lo + i - 1;            // window chunk id (i>=1)
        const int jbase = (i > 0 && (c == 1 || c == 9)) ? ((c - 1) << 6) : -1;
        const bool pf   = (i + 1 < NTL);
        if (pf) issue_loads(i + 1);                // latency hides under compute

        // QK^T transposed: sT[nt] row=key(quad*4+r), col=q
        f32x4 sT[4];
#pragma unroll
        for (int nt = 0; nt < 4; nt++) {
            const bf16x8 kf0 = *(const bf16x8*)&Ks[buf][(nt << 4) + col][quad << 3];
            const bf16x8 kf1 = *(const bf16x8*)&Ks[buf][(nt << 4) + col][32 + (quad << 3)];
            f32x4 s = (f32x4){0.f, 0.f, 0.f, 0.f};
            s = __builtin_amdgcn_mfma_f32_16x16x32_bf16(kf0, qf0, s, 0, 0, 0);
            s = __builtin_amdgcn_mfma_f32_16x16x32_bf16(kf1, qf1, s, 0, 0, 0);
            sT[nt] = s;
        }

        if (jbase >= 0) {
#pragma unroll
            for (int nt = 0; nt < 4; nt++) {
#pragma unroll
                for (int r = 0; r < 4; r++) {
                    const int jp = jbase + (nt << 4) + (quad << 2) + r;
                    const bool ok = (jp >= qrow) && (jp <= qrow + 2 * WQ);
                    if (!ok) sT[nt][r] = -1e30f;
                }
            }
        }

        // per-lane online softmax over this lane's 16 keys + cross-quad reduce
        float mx = sT[0][0];
#pragma unroll
        for (int nt = 0; nt < 4; nt++)
#pragma unroll
            for (int r = 0; r < 4; r++) mx = fmaxf(mx, sT[nt][r]);
        mx = fmaxf(mx, __shfl_xor(mx, 16));
        mx = fmaxf(mx, __shfl_xor(mx, 32));

        // T13 defer-max (log2 units): skip rescale when growth <= 11 (P <= 2^11)
        if (!__all(mx - m_i <= 11.0f)) {
            const float m_new = fmaxf(m_i, mx);
            const float alpha = fast_exp2(m_i - m_new);
            m_i = m_new;
            l_i *= alpha;
            float al[4];
#pragma unroll
            for (int r = 0; r < 4; r++) al[r] = __shfl(alpha, alsrc0 | r);
#pragma unroll
            for (int nt = 0; nt < 4; nt++)
#pragma unroll
                for (int r = 0; r < 4; r++) acc_o[nt][r] *= al[r];
        }

        float ps = 0.f;
#pragma unroll
        for (int nt = 0; nt < 4; nt++)
#pragma unroll
            for (int r = 0; r < 4; r++) {
                const float e = fast_exp2(sT[nt][r] - m_i);
                sT[nt][r] = e;
                ps += e;
            }
        ps += __shfl_xor(ps, 16);
        ps += __shfl_xor(ps, 32);
        l_i += ps;

        // P pack + write: row q=col, k = nt*16 + quad*4 + {0..3}
#pragma unroll
        for (int nt = 0; nt < 4; nt++) {
            uint2 pk2;
            pk2.x = cvt_pk_bf16(sT[nt][0], sT[nt][1]);
            pk2.y = cvt_pk_bf16(sT[nt][2], sT[nt][3]);
            *(uint2*)&Ps[w][col][(nt << 4) + (quad << 2)] = pk2;
        }

        const bf16x8 pf0 = *(const bf16x8*)&Ps[w][col][quad << 3];
        const bf16x8 pf1 = *(const bf16x8*)&Ps[w][col][32 + (quad << 3)];

#pragma unroll
        for (int nt = 0; nt < 4; nt++) {
            const bf16x8 vf0 = *(const bf16x8*)&Vs[buf][(nt << 4) + col][quad << 3];
            const bf16x8 vf1 = *(const bf16x8*)&Vs[buf][(nt << 4) + col][32 + (quad << 3)];
            acc_o[nt] = __builtin_amdgcn_mfma_f32_16x16x32_bf16(pf0, vf0, acc_o[nt], 0, 0, 0);
            acc_o[nt] = __builtin_amdgcn_mfma_f32_16x16x32_bf16(pf1, vf1, acc_o[nt], 0, 0, 0);
        }

        if (pf) write_stage(buf ^ 1);              // regs -> other buffer (no barrier needed)
        buf ^= 1;
    }

    float inv[4];
#pragma unroll
    for (int r = 0; r < 4; r++) inv[r] = 1.f / __shfl(l_i, alsrc0 | r);
#pragma unroll
    for (int nt = 0; nt < 4; nt++) {
#pragma unroll
        for (int r = 0; r < 4; r++) {
            const int t = t0 + (w << 4) + (quad << 2) + r;
            attnb[base + (size_t)t * EE + (nt << 4) + col] = f2bf(acc_o[nt][r] * inv[r]);
        }
    }
}

// ---------- global-token attention: swapped QK^T + transposed V + defer-max + exp2 ----------
__global__ __launch_bounds__(256) void global_attn_flash_kernel(
    const u16* __restrict__ qg, const u16* __restrict__ kg, const u16* __restrict__ vgt,
    float* __restrict__ Op, float* __restrict__ Ml, float* __restrict__ Ll)
{
    const int tid  = threadIdx.x;
    const int lane = tid & 63;
    const int w    = tid >> 6;
    const int col  = lane & 15;
    const int quad = lane >> 4;

    const int s  = blockIdx.x & (NSPLIT - 1);
    const int h  = (blockIdx.x >> 3) & (HH - 1);
    const int b  = blockIdx.x >> 7;
    const int k0pos = s * (TT / NSPLIT);

    __shared__ __align__(16) u16 Ks[2][64][72];   // [buf][key][dim]
    __shared__ __align__(16) u16 Vs[2][64][72];   // [buf][dim][key]
    __shared__ __align__(16) u16 Ps[4][16][72];   // [wave][q][k]

    const size_t base   = (size_t)b * TT * EE + (size_t)h * DD;        // kg row-major
    const size_t vtbase = (size_t)((b << 4) | h) * DD * TT;            // vgt [B,H,D,T]

    const u16* qp = qg + (size_t)(b * GG + (w << 4) + col) * EE + (size_t)h * DD + (quad << 3);
    const bf16x8 qf0 = *(const bf16x8*)qp;
    const bf16x8 qf1 = *(const bf16x8*)(qp + 32);

    float m_i = -1e30f, l_i = 0.f;
    f32x4 acc_o[4];
#pragma unroll
    for (int nt = 0; nt < 4; nt++) acc_o[nt] = (f32x4){0.f, 0.f, 0.f, 0.f};

    constexpr int NTL = TT / NSPLIT / 64;          // 8 key tiles per split
    const int srow  = tid >> 2;
    const int spart = (tid & 3) << 4;

    uint4 kr0, kr1, vr0, vr1;
    auto issue_loads = [&](int i) {
        const int kpos0 = k0pos + (i << 6);
        const u16* ks = kg + base + (size_t)(kpos0 + srow) * EE + spart;
        const u16* vs = vgt + vtbase + (size_t)srow * TT + kpos0 + spart;
        kr0 = *(const uint4*)ks;
        kr1 = *(const uint4*)(ks + 8);
        vr0 = *(const uint4*)vs;
        vr1 = *(const uint4*)(vs + 8);
    };
    auto write_stage = [&](int buf) {
        *(uint4*)&Ks[buf][srow][spart]     = kr0;
        *(uint4*)&Ks[buf][srow][spart + 8] = kr1;
        *(uint4*)&Vs[buf][srow][spart]     = vr0;
        *(uint4*)&Vs[buf][srow][spart + 8] = vr1;
    };

    issue_loads(0);
    write_stage(0);
    int buf = 0;

    const int alsrc0 = (lane & 48) | ((lane >> 2) & 12);

#pragma unroll 1
    for (int i = 0; i < NTL; i++) {
        __syncthreads();
        const bool pf = (i + 1 < NTL);
        if (pf) issue_loads(i + 1);

        f32x4 sT[4];
#pragma unroll
        for (int nt = 0; nt < 4; nt++) {
            const bf16x8 kf0 = *(const bf16x8*)&Ks[buf][(nt << 4) + col][quad << 3];
            const bf16x8 kf1 = *(const bf16x8*)&Ks[buf][(nt << 4) + col][32 + (quad << 3)];
            f32x4 sv = (f32x4){0.f, 0.f, 0.f, 0.f};
            sv = __builtin_amdgcn_mfma_f32_16x16x32_bf16(kf0, qf0, sv, 0, 0, 0);
            sv = __builtin_amdgcn_mfma_f32_16x16x32_bf16(kf1, qf1, sv, 0, 0, 0);
            sT[nt] = sv;
        }

        float mx = sT[0][0];
#pragma unroll
        for (int nt = 0; nt < 4; nt++)
#pragma unroll
            for (int r = 0; r < 4; r++) mx = fmaxf(mx, sT[nt][r]);
        mx = fmaxf(mx, __shfl_xor(mx, 16));
        mx = fmaxf(mx, __shfl_xor(mx, 32));

        if (!__all(mx - m_i <= 11.0f)) {
            const float m_new = fmaxf(m_i, mx);
            const float alpha = fast_exp2(m_i - m_new);
            m_i = m_new;
            l_i *= alpha;
            float al[4];
#pragma unroll
            for (int r = 0; r < 4; r++) al[r] = __shfl(alpha, alsrc0 | r);
#pragma unroll
            for (int nt = 0; nt < 4; nt++)
#pragma unroll
                for (int r = 0; r < 4; r++) acc_o[nt][r] *= al[r];
        }

        float ps = 0.f;
#pragma unroll
        for (int nt = 0; nt < 4; nt++)
#pragma unroll
            for (int r = 0; r < 4; r++) {
                const float e = fast_exp2(sT[nt][r] - m_i);
                sT[nt][r] = e;
                ps += e;
            }
        ps += __shfl_xor(ps, 16);
        ps += __shfl_xor(ps, 32);
        l_i += ps;

#pragma unroll
        for (int nt = 0; nt < 4; nt++) {
            uint2 pk2;
            pk2.x = cvt_pk_bf16(sT[nt][0], sT[nt][1]);
            pk2.y = cvt_pk_bf16(sT[nt][2], sT[nt][3]);
            *(uint2*)&Ps[w][col][(nt << 4) + (quad << 2)] = pk2;
        }

        const bf16x8 pf0 = *(const bf16x8*)&Ps[w][col][quad << 3];
        const bf16x8 pf1 = *(const bf16x8*)&Ps[w][col][32 + (quad << 3)];

#pragma unroll
        for (int nt = 0; nt < 4; nt++) {
            const bf16x8 vf0 = *(const bf16x8*)&Vs[buf][(nt << 4) + col][quad << 3];
            const bf16x8 vf1 = *(const bf16x8*)&Vs[buf][(nt << 4) + col][32 + (quad << 3)];
            acc_o[nt] = __builtin_amdgcn_mfma_f32_16x16x32_bf16(pf0, vf0, acc_o[nt], 0, 0, 0);
            acc_o[nt] = __builtin_amdgcn_mfma_f32_16x16x32_bf16(pf1, vf1, acc_o[nt], 0, 0, 0);
        }

        if (pf) write_stage(buf ^ 1);
        buf ^= 1;
    }

    const size_t obase = (size_t)blockIdx.x * GG * DD;
#pragma unroll
    for (int nt = 0; nt < 4; nt++) {
#pragma unroll
        for (int r = 0; r < 4; r++) {
            const int row = (w << 4) + (quad << 2) + r;
            Op[obase + (size_t)row * DD + (nt << 4) + col] = acc_o[nt][r];
        }
    }
    if (quad == 0) {
        Ml[blockIdx.x * GG + (w << 4) + col] = m_i;
        Ll[blockIdx.x * GG + (w << 4) + col] = l_i;
    }
}

// ---------- combine split-K partials (m/l are in log2 units -> exp2) ----------
__global__ __launch_bounds__(256) void global_combine_kernel(
    const float* __restrict__ Op, const float* __restrict__ Ml, const float* __restrict__ Ll,
    u16* __restrict__ attnb)
{
    const int bh  = blockIdx.x;
    const int b   = bh >> 4;
    const int h   = bh & (HH - 1);
    const int row = threadIdx.x >> 2;
    const int d0  = (threadIdx.x & 3) << 4;

    float mv[NSPLIT];
    float m = -1e30f;
#pragma unroll
    for (int s = 0; s < NSPLIT; s++) {
        mv[s] = Ml[(bh * NSPLIT + s) * GG + row];
        m = fmaxf(m, mv[s]);
    }
    float l = 0.f;
    float sc[NSPLIT];
#pragma unroll
    for (int s = 0; s < NSPLIT; s++) {
        sc[s] = fast_exp2(mv[s] - m);
        l += Ll[(bh * NSPLIT + s) * GG + row] * sc[s];
    }
    float o[16];
#pragma unroll
    for (int j = 0; j < 16; j++) o[j] = 0.f;
#pragma unroll
    for (int s = 0; s < NSPLIT; s++) {
        const float* src = Op + ((size_t)(bh * NSPLIT + s) * GG + row) * DD + d0;
        const float f = sc[s];
#pragma unroll
        for (int j = 0; j < 16; j += 4) {
            const float4 v4 = *(const float4*)(src + j);
            o[j + 0] = fmaf(v4.x, f, o[j + 0]);
            o[j + 1] = fmaf(v4.y, f, o[j + 1]);
            o[j + 2] = fmaf(v4.z, f, o[j + 2]);
            o[j + 3] = fmaf(v4.w, f, o[j + 3]);
        }
    }
    const float inv = 1.f / l;
    u16* dst = attnb + ((size_t)b * TT + row) * EE + (size_t)h * DD + d0;
#pragma unroll
    for (int j = 0; j < 16; j++) dst[j] = f2bf(o[j] * inv);
}

extern "C" void kernel_launch(void* const* d_in, const int* in_sizes, int n_in,
                              void* d_out, int out_size, void* d_ws, size_t ws_size,
                              hipStream_t stream)
{
    (void)in_sizes; (void)n_in; (void)out_size; (void)ws_size;
    const float* query = (const float*)d_in[0];
    const float* Wq  = (const float*)d_in[2];  const float* bq  = (const float*)d_in[3];
    const float* Wk  = (const float*)d_in[4];  const float* bk  = (const float*)d_in[5];
    const float* Wv  = (const float*)d_in[6];  const float* bv  = (const float*)d_in[7];
    const float* Wqg = (const float*)d_in[8];  const float* bqg = (const float*)d_in[9];
    const float* Wkg = (const float*)d_in[10]; const float* bkg = (const float*)d_in[11];
    const float* Wvg = (const float*)d_in[12]; const float* bvg = (const float*)d_in[13];
    const float* Wo  = (const float*)d_in[14]; const float* bo  = (const float*)d_in[15];

    const size_t nfull = (size_t)BBATCH * TT * EE;      // 8.39M elems
    const size_t wsz   = (size_t)1 << 20;               // one weight, elems
    u16* xb    = (u16*)d_ws;                            // bf16 x [B,T,E]; later reused as attnb
    u16* wb    = xb + nfull;                            // 7 converted weights
    u16* slotA = wb + 7 * wsz;                          // kg, then q
    u16* slotB = slotA + nfull;                         // vgt, then k
    u16* slotC = slotB + nfull;                         // vt [B,H,D,T]
    u16* qg    = slotC + nfull;                         // [B*G, E]
    float* Op  = (float*)(qg + (size_t)BBATCH * GG * EE);
    float* Ml  = Op + (size_t)BBATCH * HH * NSPLIT * GG * DD;
    float* Ll  = Ml + (size_t)BBATCH * HH * NSPLIT * GG;
    u16* attnb = xb;                                    // alias: xb dead after last GEMM that reads it
    // peak ws ≈ 86 MB

    WPtrs wp;   // order: fuse3 (Wq,Wk,Wv) | fuse2 (Wkg,Wvg) | Wqg | Wo
    wp.p[0] = Wq; wp.p[1] = Wk; wp.p[2] = Wv;
    wp.p[3] = Wkg; wp.p[4] = Wvg; wp.p[5] = Wqg; wp.p[6] = Wo;

    const dim3 blk(256);
    const dim3 gF2(16, 64);     // 128^2 tiles, N=2048
    const dim3 gF3(24, 64);     // 128^2 tiles, N=3072
    const dim3 gFull(8, 64);    // 128^2 tiles, N=1024 (Wo)
    const dim3 gQg(8, 1);       // 128^2 tiles, N=1024, M=128 (qg, PERMA gather)
    const float sc = 0.125f * LOG2E;   // D^-0.5, pre-scaled for exp2 softmax

    conv_kernel<<<7680, blk, 0, stream>>>(wp, query, wb, xb);

    // qg projection (reads xb) — pipelined kernel with PERMA row gather
    FusedArgs faQ;
    faQ.out[0] = qg;  faQ.out[1] = nullptr; faQ.out[2] = nullptr;
    faQ.bias[0] = bqg; faQ.bias[1] = nullptr; faQ.bias[2] = nullptr;
    faQ.scale[0] = sc; faQ.scale[1] = 1.f;    faQ.scale[2] = 1.f;
    faQ.vseg = -1;
    gemm_pipe_kernel<1, 0, 0, 1><<<gQg, blk, 0, stream>>>(xb, wb + 5 * wsz, faQ);

    // fused kg|vgt projection (vg written transposed per head for the flash)
    FusedArgs fa2;
    fa2.out[0] = slotA; fa2.out[1] = slotB; fa2.out[2] = nullptr;
    fa2.bias[0] = bkg;  fa2.bias[1] = bvg;  fa2.bias[2] = nullptr;
    fa2.scale[0] = 1.f; fa2.scale[1] = 1.f; fa2.scale[2] = 1.f;
    fa2.vseg = 1;
    gemm_pipe_kernel<2, 0, 0, 0><<<gF2, blk, 0, stream>>>(xb, wb + 3 * wsz, fa2);
    global_attn_flash_kernel<<<BBATCH * HH * NSPLIT, blk, 0, stream>>>(qg, slotA, slotB, Op, Ml, Ll);

    // fused q|k|vt projection (q pre-scaled by D^-0.5 * log2e for exp2 softmax)
    FusedArgs fa3;
    fa3.out[0] = slotA; fa3.out[1] = slotB; fa3.out[2] = slotC;
    fa3.bias[0] = bq;   fa3.bias[1] = bk;   fa3.bias[2] = bv;
    fa3.scale[0] = sc;  fa3.scale[1] = 1.f; fa3.scale[2] = 1.f;
    fa3.vseg = 2;
    gemm_pipe_kernel<3, 0, 0, 0><<<gF3, blk, 0, stream>>>(xb, wb, fa3);

    band_attn_kernel<<<BBATCH * HH * (TT / 64), blk, 0, stream>>>(slotA, slotB, slotC, attnb);
    global_combine_kernel<<<BBATCH * HH, blk, 0, stream>>>(Op, Ml, Ll, attnb);

    // output projection (128^2 pipelined, f32 out, [B,T]->[T,B] row perm)
    FusedArgs faO;
    faO.out[0] = (u16*)d_out; faO.out[1] = nullptr; faO.out[2] = nullptr;
    faO.bias[0] = bo;         faO.bias[1] = nullptr; faO.bias[2] = nullptr;
    faO.scale[0] = 1.f;       faO.scale[1] = 1.f;    faO.scale[2] = 1.f;
    faO.vseg = -1;
    gemm_pipe_kernel<1, 1, 1, 0><<<gFull, blk, 0, stream>>>(attnb, wb + 6 * wsz, faO);
}

// Round 12
// 335.023 us; speedup vs baseline: 1.0188x; 1.0133x over previous
//
#include <hip/hip_runtime.h>
#include <hip/hip_bf16.h>

typedef unsigned short u16;
typedef __bf16 bf16x8 __attribute__((ext_vector_type(8)));
typedef float  f32x4  __attribute__((ext_vector_type(4)));

constexpr int TT = 4096;   // seq
constexpr int BBATCH = 2;  // batch
constexpr int EE = 1024;   // embed
constexpr int HH = 16;     // heads
constexpr int DD = 64;     // head dim
constexpr int WQ = 256;    // one-sided window
constexpr int GG = 64;     // global tokens
constexpr int NSPLIT = 8;  // key splits for global attention
constexpr float LOG2E = 1.4426950408889634f;

// ---------- bf16 / math helpers ----------
__device__ __forceinline__ float fast_exp2(float x) {
    return __builtin_amdgcn_exp2f(x);   // native v_exp_f32 (2^x)
}
__device__ __forceinline__ u16 f2bf(float f) {
    union { float f; unsigned int i; } c; c.f = f;
    unsigned int x = c.i;
    return (u16)((x + 0x7fffu + ((x >> 16) & 1u)) >> 16);  // RNE
}
__device__ __forceinline__ unsigned cvt_pk_bf16(float a, float b) {
    unsigned r;
    asm("v_cvt_pk_bf16_f32 %0, %1, %2" : "=v"(r) : "v"(a), "v"(b));
    return r;  // low16 = bf16(a), high16 = bf16(b), RNE
}
__device__ __forceinline__ uint4 pack8(float4 a, float4 b) {
    uint4 r;
    r.x = (unsigned)f2bf(a.x) | ((unsigned)f2bf(a.y) << 16);
    r.y = (unsigned)f2bf(a.z) | ((unsigned)f2bf(a.w) << 16);
    r.z = (unsigned)f2bf(b.x) | ((unsigned)f2bf(b.y) << 16);
    r.w = (unsigned)f2bf(b.z) | ((unsigned)f2bf(b.w) << 16);
    return r;
}

// async global->LDS, 16B per lane; LDS dest = wave-uniform base + lane*16
__device__ __forceinline__ void g2l16(const u16* g, u16* l) {
    __builtin_amdgcn_global_load_lds(
        (const __attribute__((address_space(1))) void*)g,
        (__attribute__((address_space(3))) void*)l, 16, 0, 0);
}

// XCD swizzle: blocks sharing an M-tile (y) get linear ids == c (mod 8) -> one XCD's L2
__device__ __forceinline__ void xcd_swizzle(int& bx, int& by) {
    bx = blockIdx.x; by = blockIdx.y;
    if ((gridDim.y & 7) == 0) {
        const int g   = blockIdx.x + blockIdx.y * gridDim.x;
        const int idx = g >> 3;
        bx = idx % gridDim.x;
        by = (g & 7) + ((idx / gridDim.x) << 3);
    }
}

// ---------- fp32 -> bf16 conversion ----------
struct WPtrs { const float* p[7]; };
__global__ __launch_bounds__(256) void conv_kernel(
    WPtrs wp, const float* __restrict__ query, u16* __restrict__ wb, u16* __restrict__ xb)
{
    const size_t i8 = ((size_t)blockIdx.x * 256 + threadIdx.x) << 3;
    const size_t WTOT = (size_t)7 << 20;   // 7 x 1024*1024
    const float* src;
    u16* dst;
    if (i8 < WTOT) {
        const int which = (int)(i8 >> 20);
        src = wp.p[which] + (i8 & (((size_t)1 << 20) - 1));
        dst = wb + i8;
    } else {
        const size_t j = i8 - WTOT;            // dst index in [B,T,E]
        const size_t e = j & (EE - 1);
        const size_t t = (j >> 10) & (TT - 1);
        const size_t b = j >> 22;
        src = query + (t * BBATCH + b) * EE + e;
        dst = xb + j;
    }
    const float4 f0 = *(const float4*)src;
    const float4 f1 = *(const float4*)(src + 4);
    *(uint4*)dst = pack8(f0, f1);
}

// ---------- single-output GEMM (qg only: tiny M) ----------
template<int C_F32, int PERMA_QG, int PERMC_TB>
__global__ __launch_bounds__(256) void gemm_kernel(
    const u16* __restrict__ A, const u16* __restrict__ W, const float* __restrict__ bias,
    void* __restrict__ Cv, float scale)
{
    const int tid = threadIdx.x, lane = tid & 63, w = tid >> 6;
    const int wm = w >> 1, wn = w & 1;
    int bx, by;
    xcd_swizzle(bx, by);
    const int m0 = by << 7, n0 = bx << 7;

    __shared__ __align__(16) u16 As[2 * 128 * 32];   // two 32-col panels
    __shared__ __align__(16) u16 Bs[2 * 128 * 32];

    const int lrow = lane >> 2;
    const int lcol = (lane & 3) << 3;
    auto arow = [](int m) -> size_t {
        return PERMA_QG ? (size_t)(((m >> 6) << 12) | (m & 63)) : (size_t)m;
    };
    const u16* gA0 = A + arow(m0 + (w << 4) + lrow) * EE + lcol;
    const u16* gA1 = A + arow(m0 + 64 + (w << 4) + lrow) * EE + lcol;
    const u16* gB0 = W + (size_t)(n0 + (w << 4) + lrow) * EE + lcol;
    const u16* gB1 = gB0 + (size_t)64 * EE;
    u16* lA0 = As + (w << 9);
    u16* lA1 = As + 2048 + (w << 9);
    u16* lB0 = Bs + (w << 9);
    u16* lB1 = Bs + 2048 + (w << 9);

    f32x4 acc[4][4];
#pragma unroll
    for (int i = 0; i < 4; i++)
#pragma unroll
        for (int j = 0; j < 4; j++)
            acc[i][j] = (f32x4){0.f, 0.f, 0.f, 0.f};

    const int fr = lane & 15;
    const int fq = (lane >> 4) << 3;

    for (int k0 = 0; k0 < EE; k0 += 64) {
        g2l16(gA0 + k0, lA0);  g2l16(gA0 + k0 + 32, lA0 + 4096);
        g2l16(gA1 + k0, lA1);  g2l16(gA1 + k0 + 32, lA1 + 4096);
        g2l16(gB0 + k0, lB0);  g2l16(gB0 + k0 + 32, lB0 + 4096);
        g2l16(gB1 + k0, lB1);  g2l16(gB1 + k0 + 32, lB1 + 4096);
        __syncthreads();
#pragma unroll
        for (int p = 0; p < 2; p++) {
            bf16x8 af[4], bfv[4];
#pragma unroll
            for (int i = 0; i < 4; i++)
                af[i] = *(const bf16x8*)&As[p * 4096 + ((wm << 6) + (i << 4) + fr) * 32 + fq];
#pragma unroll
            for (int j = 0; j < 4; j++)
                bfv[j] = *(const bf16x8*)&Bs[p * 4096 + ((wn << 6) + (j << 4) + fr) * 32 + fq];
#pragma unroll
            for (int i = 0; i < 4; i++)
#pragma unroll
                for (int j = 0; j < 4; j++)
                    acc[i][j] = __builtin_amdgcn_mfma_f32_16x16x32_bf16(af[i], bfv[j], acc[i][j], 0, 0, 0);
        }
        __syncthreads();
    }

    const int colbase = n0 + (wn << 6);
    const int rowbase = m0 + (wm << 6) + ((lane >> 4) << 2);
#pragma unroll
    for (int j = 0; j < 4; j++) {
        const int col = colbase + (j << 4) + fr;
        const float bv = bias[col];
#pragma unroll
        for (int i = 0; i < 4; i++) {
#pragma unroll
            for (int r = 0; r < 4; r++) {
                const int row = rowbase + (i << 4) + r;
                const float val = (acc[i][j][r] + bv) * scale;
                const size_t dst = (size_t)(PERMC_TB ? (((row & (TT - 1)) << 1) | (row >> 12)) : row) * EE + col;
                if (C_F32) ((float*)Cv)[dst] = val;
                else       ((u16*)Cv)[dst]   = f2bf(val);
            }
        }
    }
}

struct FusedArgs { u16* out[3]; const float* bias[3]; float scale[3]; int vseg; };

// ---------- pipelined 128x128 GEMM (verified best: 0 bank conflicts, 2 blocks/CU) ----------
template<int NSEG, int CF32, int PERMC>
__global__ __launch_bounds__(256, 2) void gemm_pipe_kernel(
    const u16* __restrict__ A, const u16* __restrict__ W, FusedArgs fa)
{
    const int tid = threadIdx.x, lane = tid & 63, w = tid >> 6;
    const int wm = w >> 1, wn = w & 1;
    int bx, by;
    xcd_swizzle(bx, by);
    const int m0 = by << 7, n0 = bx << 7;

    __shared__ __align__(16) u16 As[2][8192];   // [buf][128][64], swizzled
    __shared__ __align__(16) u16 Bs[2][8192];

    const int srow = lane >> 3;                        // 0..7 (== dest row & 7)
    const int scol = ((lane & 7) ^ srow) << 3;         // pre-swizzled source col (elems)
    const u16* gA = A + (size_t)(m0 + (w << 5) + srow) * EE + scol;
    const u16* gB = W + (size_t)(n0 + (w << 5) + srow) * EE + scol;
    u16* lA = &As[0][0] + (w << 11);
    u16* lB = &Bs[0][0] + (w << 11);

    f32x4 acc[4][4];
#pragma unroll
    for (int i = 0; i < 4; i++)
#pragma unroll
        for (int j = 0; j < 4; j++)
            acc[i][j] = (f32x4){0.f, 0.f, 0.f, 0.f};

    const int fr = lane & 15;
    const int qb = (lane >> 4) << 4;                   // frag 16B-chunk byte col
    const int xr = (fr & 7) << 4;                      // read-side swizzle XOR

    auto stageA = [&](int k0, int buf) {
#pragma unroll
        for (int l = 0; l < 4; l++)
            g2l16(gA + (size_t)(l << 3) * EE + k0, lA + buf * 8192 + (l << 9));
    };
    auto stageB = [&](int k0, int buf) {
#pragma unroll
        for (int l = 0; l < 4; l++)
            g2l16(gB + (size_t)(l << 3) * EE + k0, lB + buf * 8192 + (l << 9));
    };

    stageA(0, 0);
    stageB(0, 0);
    __syncthreads();

    constexpr int NT = EE / 64;                        // 16 K-tiles
#pragma unroll 2
    for (int t = 0; t < NT; t++) {
        const int buf = t & 1;
        const bool pf = (t + 1 < NT);
        const int kn = (t + 1) << 6;
        bf16x8 af[4], bfv[4];

        // ---- phase 0 : k-half 0 ----
#pragma unroll
        for (int mi = 0; mi < 4; mi++)
            af[mi] = *(const bf16x8*)((const char*)&As[buf][0] +
                      ((((wm << 6) + (mi << 4) + fr)) << 7) + (qb ^ xr));
#pragma unroll
        for (int nj = 0; nj < 4; nj++)
            bfv[nj] = *(const bf16x8*)((const char*)&Bs[buf][0] +
                      ((((wn << 6) + (nj << 4) + fr)) << 7) + (qb ^ xr));
        if (pf) stageA(kn, buf ^ 1);
        __builtin_amdgcn_s_barrier();
        __builtin_amdgcn_s_setprio(1);
#pragma unroll
        for (int mi = 0; mi < 4; mi++)
#pragma unroll
            for (int nj = 0; nj < 4; nj++)
                acc[mi][nj] = __builtin_amdgcn_mfma_f32_16x16x32_bf16(af[mi], bfv[nj], acc[mi][nj], 0, 0, 0);
        __builtin_amdgcn_s_setprio(0);
        __builtin_amdgcn_s_barrier();

        // ---- phase 1 : k-half 1 ----
#pragma unroll
        for (int mi = 0; mi < 4; mi++)
            af[mi] = *(const bf16x8*)((const char*)&As[buf][0] +
                      ((((wm << 6) + (mi << 4) + fr)) << 7) + ((64 | qb) ^ xr));
#pragma unroll
        for (int nj = 0; nj < 4; nj++)
            bfv[nj] = *(const bf16x8*)((const char*)&Bs[buf][0] +
                      ((((wn << 6) + (nj << 4) + fr)) << 7) + ((64 | qb) ^ xr));
        if (pf) stageB(kn, buf ^ 1);
        __builtin_amdgcn_s_barrier();
        __builtin_amdgcn_s_setprio(1);
#pragma unroll
        for (int mi = 0; mi < 4; mi++)
#pragma unroll
            for (int nj = 0; nj < 4; nj++)
                acc[mi][nj] = __builtin_amdgcn_mfma_f32_16x16x32_bf16(af[mi], bfv[nj], acc[mi][nj], 0, 0, 0);
        __builtin_amdgcn_s_setprio(0);
        __syncthreads();
    }

    const int seg = (NSEG > 1) ? (n0 >> 10) : 0;
    u16* outp = fa.out[seg];
    const float* bp = fa.bias[seg];
    const float scl = fa.scale[seg];
    const bool vtr = (NSEG > 1) && (seg == fa.vseg);

    const int colbase = n0 + (wn << 6);
    const int rowbase = m0 + (wm << 6) + ((lane >> 4) << 2);
#pragma unroll
    for (int j = 0; j < 4; j++) {
        const int col = colbase + (j << 4) + fr;
        const int cl  = col & (EE - 1);
        const float bv = bp[cl];
#pragma unroll
        for (int i = 0; i < 4; i++) {
            if (vtr) {
                const int row0 = rowbase + (i << 4);
                const int bb = row0 >> 12, t = row0 & (TT - 1);
                const int hh = cl >> 6, d = cl & 63;
                ushort4 pk;
                pk.x = f2bf((acc[i][j][0] + bv) * scl);
                pk.y = f2bf((acc[i][j][1] + bv) * scl);
                pk.z = f2bf((acc[i][j][2] + bv) * scl);
                pk.w = f2bf((acc[i][j][3] + bv) * scl);
                *(ushort4*)(outp + (((size_t)(bb * HH + hh) * DD + d) * TT + t)) = pk;
            } else {
#pragma unroll
                for (int r = 0; r < 4; r++) {
                    const int row = rowbase + (i << 4) + r;
                    const float val = (acc[i][j][r] + bv) * scl;
                    const size_t drow = PERMC ? (size_t)(((row & (TT - 1)) << 1) | (row >> 12))
                                              : (size_t)row;
                    if (CF32) ((float*)outp)[drow * EE + cl] = val;
                    else      outp[drow * EE + cl] = f2bf(val);
                }
            }
        }
    }
}

// ---------- band attention: S^T softmax + async staging + defer-max + exp2 ----------
__global__ __launch_bounds__(256) void band_attn_kernel(
    const u16* __restrict__ q, const u16* __restrict__ k, const u16* __restrict__ vt,
    u16* __restrict__ attnb)
{
    const int tid  = threadIdx.x;
    const int lane = tid & 63;
    const int w    = tid >> 6;
    const int col  = lane & 15;
    const int quad = lane >> 4;

    const int qt = blockIdx.x >> 5;
    const int bh = blockIdx.x & 31;
    const int h  = bh & (HH - 1);
    const int b  = bh >> 4;
    const int t0 = qt << 6;

    __shared__ __align__(16) u16 Ks[2][64][72];   // [buf][key][dim]
    __shared__ __align__(16) u16 Vs[2][64][72];   // [buf][dim][key]
    __shared__ __align__(16) u16 Ps[4][16][72];   // [wave][q][k]

    const size_t base   = (size_t)b * TT * EE + (size_t)h * DD;
    const size_t vtbase = (size_t)bh * DD * TT;

    const u16* qp = q + base + (size_t)(t0 + (w << 4) + col) * EE + (quad << 3);
    const bf16x8 qf0 = *(const bf16x8*)qp;
    const bf16x8 qf1 = *(const bf16x8*)(qp + 32);

    float m_i = -1e30f, l_i = 0.f;
    f32x4 acc_o[4];
#pragma unroll
    for (int nt = 0; nt < 4; nt++) acc_o[nt] = (f32x4){0.f, 0.f, 0.f, 0.f};

    const int c_lo = 1 + ((t0 < WQ) ? ((WQ - t0) >> 6) : 0);
    const int c_hi = min(9, 1 + ((TT + WQ - 64 - t0) >> 6));
    const int NTL  = 2 + c_hi - c_lo;              // tiles: 1 global + window tiles

    const int srow  = tid >> 2;
    const int spart = (tid & 3) << 4;

    uint4 kr0, kr1, vr0, vr1;                      // staging regs (in flight)
    auto issue_loads = [&](int i) {
        const int kpos0 = (i == 0) ? 0 : (t0 - WQ + ((c_lo + i - 2) << 6));
        const u16* ks = k + base + (size_t)(kpos0 + srow) * EE + spart;
        const u16* vs = vt + vtbase + (size_t)srow * TT + kpos0 + spart;
        kr0 = *(const uint4*)ks;
        kr1 = *(const uint4*)(ks + 8);
        vr0 = *(const uint4*)vs;
        vr1 = *(const uint4*)(vs + 8);
    };
    auto write_stage = [&](int buf) {
        *(uint4*)&Ks[buf][srow][spart]     = kr0;
        *(uint4*)&Ks[buf][srow][spart + 8] = kr1;
        *(uint4*)&Vs[buf][srow][spart]     = vr0;
        *(uint4*)&Vs[buf][srow][spart + 8] = vr1;
    };

    issue_loads(0);
    write_stage(0);
    int buf = 0;

    const int qrow = (w << 4) + col;               // this lane's query row (rel t0)
    const int alsrc0 = (lane & 48) | ((lane >> 2) & 12);  // lane holding alpha/l for row quad*4+r

#pragma unroll 1
    for (int i = 0; i < NTL; i++) {
        __syncthreads();                           // LDS[buf] ready for all waves
        const int c     = c_lo + i - 1;            // window chunk id (i>=1)
        const int jbase = (i > 0 && (c == 1 || c == 9)) ? ((c - 1) << 6) : -1;
        const bool pf   = (i + 1 < NTL);
        if (pf) issue_loads(i + 1);                // latency hides under compute

        // QK^T transposed: sT[nt] row=key(quad*4+r), col=q
        f32x4 sT[4];
#pragma unroll
        for (int nt = 0; nt < 4; nt++) {
            const bf16x8 kf0 = *(const bf16x8*)&Ks[buf][(nt << 4) + col][quad << 3];
            const bf16x8 kf1 = *(const bf16x8*)&Ks[buf][(nt << 4) + col][32 + (quad << 3)];
            f32x4 s = (f32x4){0.f, 0.f, 0.f, 0.f};
            s = __builtin_amdgcn_mfma_f32_16x16x32_bf16(kf0, qf0, s, 0, 0, 0);
            s = __builtin_amdgcn_mfma_f32_16x16x32_bf16(kf1, qf1, s, 0, 0, 0);
            sT[nt] = s;
        }

        if (jbase >= 0) {
#pragma unroll
            for (int nt = 0; nt < 4; nt++) {
#pragma unroll
                for (int r = 0; r < 4; r++) {
                    const int jp = jbase + (nt << 4) + (quad << 2) + r;
                    const bool ok = (jp >= qrow) && (jp <= qrow + 2 * WQ);
                    if (!ok) sT[nt][r] = -1e30f;
                }
            }
        }

        // per-lane online softmax over this lane's 16 keys + cross-quad reduce
        float mx = sT[0][0];
#pragma unroll
        for (int nt = 0; nt < 4; nt++)
#pragma unroll
            for (int r = 0; r < 4; r++) mx = fmaxf(mx, sT[nt][r]);
        mx = fmaxf(mx, __shfl_xor(mx, 16));
        mx = fmaxf(mx, __shfl_xor(mx, 32));

        // T13 defer-max (log2 units): skip rescale when growth <= 11 (P <= 2^11)
        if (!__all(mx - m_i <= 11.0f)) {
            const float m_new = fmaxf(m_i, mx);
            const float alpha = fast_exp2(m_i - m_new);
            m_i = m_new;
            l_i *= alpha;
            float al[4];
#pragma unroll
            for (int r = 0; r < 4; r++) al[r] = __shfl(alpha, alsrc0 | r);
#pragma unroll
            for (int nt = 0; nt < 4; nt++)
#pragma unroll
                for (int r = 0; r < 4; r++) acc_o[nt][r] *= al[r];
        }

        float ps = 0.f;
#pragma unroll
        for (int nt = 0; nt < 4; nt++)
#pragma unroll
            for (int r = 0; r < 4; r++) {
                const float e = fast_exp2(sT[nt][r] - m_i);
                sT[nt][r] = e;
                ps += e;
            }
        ps += __shfl_xor(ps, 16);
        ps += __shfl_xor(ps, 32);
        l_i += ps;

        // P pack + write: row q=col, k = nt*16 + quad*4 + {0..3}
#pragma unroll
        for (int nt = 0; nt < 4; nt++) {
            uint2 pk2;
            pk2.x = cvt_pk_bf16(sT[nt][0], sT[nt][1]);
            pk2.y = cvt_pk_bf16(sT[nt][2], sT[nt][3]);
            *(uint2*)&Ps[w][col][(nt << 4) + (quad << 2)] = pk2;
        }

        const bf16x8 pf0 = *(const bf16x8*)&Ps[w][col][quad << 3];
        const bf16x8 pf1 = *(const bf16x8*)&Ps[w][col][32 + (quad << 3)];

#pragma unroll
        for (int nt = 0; nt < 4; nt++) {
            const bf16x8 vf0 = *(const bf16x8*)&Vs[buf][(nt << 4) + col][quad << 3];
            const bf16x8 vf1 = *(const bf16x8*)&Vs[buf][(nt << 4) + col][32 + (quad << 3)];
            acc_o[nt] = __builtin_amdgcn_mfma_f32_16x16x32_bf16(pf0, vf0, acc_o[nt], 0, 0, 0);
            acc_o[nt] = __builtin_amdgcn_mfma_f32_16x16x32_bf16(pf1, vf1, acc_o[nt], 0, 0, 0);
        }

        if (pf) write_stage(buf ^ 1);              // regs -> other buffer (no barrier needed)
        buf ^= 1;
    }

    float inv[4];
#pragma unroll
    for (int r = 0; r < 4; r++) inv[r] = 1.f / __shfl(l_i, alsrc0 | r);
#pragma unroll
    for (int nt = 0; nt < 4; nt++) {
#pragma unroll
        for (int r = 0; r < 4; r++) {
            const int t = t0 + (w << 4) + (quad << 2) + r;
            attnb[base + (size_t)t * EE + (nt << 4) + col] = f2bf(acc_o[nt][r] * inv[r]);
        }
    }
}

// ---------- global-token attention: swapped QK^T + transposed V + defer-max + exp2 ----------
__global__ __launch_bounds__(256) void global_attn_flash_kernel(
    const u16* __restrict__ qg, const u16* __restrict__ kg, const u16* __restrict__ vgt,
    float* __restrict__ Op, float* __restrict__ Ml, float* __restrict__ Ll)
{
    const int tid  = threadIdx.x;
    const int lane = tid & 63;
    const int w    = tid >> 6;
    const int col  = lane & 15;
    const int quad = lane >> 4;

    const int s  = blockIdx.x & (NSPLIT - 1);
    const int h  = (blockIdx.x >> 3) & (HH - 1);
    const int b  = blockIdx.x >> 7;
    const int k0pos = s * (TT / NSPLIT);

    __shared__ __align__(16) u16 Ks[2][64][72];   // [buf][key][dim]
    __shared__ __align__(16) u16 Vs[2][64][72];   // [buf][dim][key]
    __shared__ __align__(16) u16 Ps[4][16][72];   // [wave][q][k]

    const size_t base   = (size_t)b * TT * EE + (size_t)h * DD;        // kg row-major
    const size_t vtbase = (size_t)((b << 4) | h) * DD * TT;            // vgt [B,H,D,T]

    const u16* qp = qg + (size_t)(b * GG + (w << 4) + col) * EE + (size_t)h * DD + (quad << 3);
    const bf16x8 qf0 = *(const bf16x8*)qp;
    const bf16x8 qf1 = *(const bf16x8*)(qp + 32);

    float m_i = -1e30f, l_i = 0.f;
    f32x4 acc_o[4];
#pragma unroll
    for (int nt = 0; nt < 4; nt++) acc_o[nt] = (f32x4){0.f, 0.f, 0.f, 0.f};

    constexpr int NTL = TT / NSPLIT / 64;          // 8 key tiles per split
    const int srow  = tid >> 2;
    const int spart = (tid & 3) << 4;

    uint4 kr0, kr1, vr0, vr1;
    auto issue_loads = [&](int i) {
        const int kpos0 = k0pos + (i << 6);
        const u16* ks = kg + base + (size_t)(kpos0 + srow) * EE + spart;
        const u16* vs = vgt + vtbase + (size_t)srow * TT + kpos0 + spart;
        kr0 = *(const uint4*)ks;
        kr1 = *(const uint4*)(ks + 8);
        vr0 = *(const uint4*)vs;
        vr1 = *(const uint4*)(vs + 8);
    };
    auto write_stage = [&](int buf) {
        *(uint4*)&Ks[buf][srow][spart]     = kr0;
        *(uint4*)&Ks[buf][srow][spart + 8] = kr1;
        *(uint4*)&Vs[buf][srow][spart]     = vr0;
        *(uint4*)&Vs[buf][srow][spart + 8] = vr1;
    };

    issue_loads(0);
    write_stage(0);
    int buf = 0;

    const int alsrc0 = (lane & 48) | ((lane >> 2) & 12);

#pragma unroll 1
    for (int i = 0; i < NTL; i++) {
        __syncthreads();
        const bool pf = (i + 1 < NTL);
        if (pf) issue_loads(i + 1);

        f32x4 sT[4];
#pragma unroll
        for (int nt = 0; nt < 4; nt++) {
            const bf16x8 kf0 = *(const bf16x8*)&Ks[buf][(nt << 4) + col][quad << 3];
            const bf16x8 kf1 = *(const bf16x8*)&Ks[buf][(nt << 4) + col][32 + (quad << 3)];
            f32x4 sv = (f32x4){0.f, 0.f, 0.f, 0.f};
            sv = __builtin_amdgcn_mfma_f32_16x16x32_bf16(kf0, qf0, sv, 0, 0, 0);
            sv = __builtin_amdgcn_mfma_f32_16x16x32_bf16(kf1, qf1, sv, 0, 0, 0);
            sT[nt] = sv;
        }

        float mx = sT[0][0];
#pragma unroll
        for (int nt = 0; nt < 4; nt++)
#pragma unroll
            for (int r = 0; r < 4; r++) mx = fmaxf(mx, sT[nt][r]);
        mx = fmaxf(mx, __shfl_xor(mx, 16));
        mx = fmaxf(mx, __shfl_xor(mx, 32));

        if (!__all(mx - m_i <= 11.0f)) {
            const float m_new = fmaxf(m_i, mx);
            const float alpha = fast_exp2(m_i - m_new);
            m_i = m_new;
            l_i *= alpha;
            float al[4];
#pragma unroll
            for (int r = 0; r < 4; r++) al[r] = __shfl(alpha, alsrc0 | r);
#pragma unroll
            for (int nt = 0; nt < 4; nt++)
#pragma unroll
                for (int r = 0; r < 4; r++) acc_o[nt][r] *= al[r];
        }

        float ps = 0.f;
#pragma unroll
        for (int nt = 0; nt < 4; nt++)
#pragma unroll
            for (int r = 0; r < 4; r++) {
                const float e = fast_exp2(sT[nt][r] - m_i);
                sT[nt][r] = e;
                ps += e;
            }
        ps += __shfl_xor(ps, 16);
        ps += __shfl_xor(ps, 32);
        l_i += ps;

#pragma unroll
        for (int nt = 0; nt < 4; nt++) {
            uint2 pk2;
            pk2.x = cvt_pk_bf16(sT[nt][0], sT[nt][1]);
            pk2.y = cvt_pk_bf16(sT[nt][2], sT[nt][3]);
            *(uint2*)&Ps[w][col][(nt << 4) + (quad << 2)] = pk2;
        }

        const bf16x8 pf0 = *(const bf16x8*)&Ps[w][col][quad << 3];
        const bf16x8 pf1 = *(const bf16x8*)&Ps[w][col][32 + (quad << 3)];

#pragma unroll
        for (int nt = 0; nt < 4; nt++) {
            const bf16x8 vf0 = *(const bf16x8*)&Vs[buf][(nt << 4) + col][quad << 3];
            const bf16x8 vf1 = *(const bf16x8*)&Vs[buf][(nt << 4) + col][32 + (quad << 3)];
            acc_o[nt] = __builtin_amdgcn_mfma_f32_16x16x32_bf16(pf0, vf0, acc_o[nt], 0, 0, 0);
            acc_o[nt] = __builtin_amdgcn_mfma_f32_16x16x32_bf16(pf1, vf1, acc_o[nt], 0, 0, 0);
        }

        if (pf) write_stage(buf ^ 1);
        buf ^= 1;
    }

    const size_t obase = (size_t)blockIdx.x * GG * DD;
#pragma unroll
    for (int nt = 0; nt < 4; nt++) {
#pragma unroll
        for (int r = 0; r < 4; r++) {
            const int row = (w << 4) + (quad << 2) + r;
            Op[obase + (size_t)row * DD + (nt << 4) + col] = acc_o[nt][r];
        }
    }
    if (quad == 0) {
        Ml[blockIdx.x * GG + (w << 4) + col] = m_i;
        Ll[blockIdx.x * GG + (w << 4) + col] = l_i;
    }
}

// ---------- combine split-K partials (m/l are in log2 units -> exp2) ----------
__global__ __launch_bounds__(256) void global_combine_kernel(
    const float* __restrict__ Op, const float* __restrict__ Ml, const float* __restrict__ Ll,
    u16* __restrict__ attnb)
{
    const int bh  = blockIdx.x;
    const int b   = bh >> 4;
    const int h   = bh & (HH - 1);
    const int row = threadIdx.x >> 2;
    const int d0  = (threadIdx.x & 3) << 4;

    float mv[NSPLIT];
    float m = -1e30f;
#pragma unroll
    for (int s = 0; s < NSPLIT; s++) {
        mv[s] = Ml[(bh * NSPLIT + s) * GG + row];
        m = fmaxf(m, mv[s]);
    }
    float l = 0.f;
    float sc[NSPLIT];
#pragma unroll
    for (int s = 0; s < NSPLIT; s++) {
        sc[s] = fast_exp2(mv[s] - m);
        l += Ll[(bh * NSPLIT + s) * GG + row] * sc[s];
    }
    float o[16];
#pragma unroll
    for (int j = 0; j < 16; j++) o[j] = 0.f;
#pragma unroll
    for (int s = 0; s < NSPLIT; s++) {
        const float* src = Op + ((size_t)(bh * NSPLIT + s) * GG + row) * DD + d0;
        const float f = sc[s];
#pragma unroll
        for (int j = 0; j < 16; j += 4) {
            const float4 v4 = *(const float4*)(src + j);
            o[j + 0] = fmaf(v4.x, f, o[j + 0]);
            o[j + 1] = fmaf(v4.y, f, o[j + 1]);
            o[j + 2] = fmaf(v4.z, f, o[j + 2]);
            o[j + 3] = fmaf(v4.w, f, o[j + 3]);
        }
    }
    const float inv = 1.f / l;
    u16* dst = attnb + ((size_t)b * TT + row) * EE + (size_t)h * DD + d0;
#pragma unroll
    for (int j = 0; j < 16; j++) dst[j] = f2bf(o[j] * inv);
}

extern "C" void kernel_launch(void* const* d_in, const int* in_sizes, int n_in,
                              void* d_out, int out_size, void* d_ws, size_t ws_size,
                              hipStream_t stream)
{
    (void)in_sizes; (void)n_in; (void)out_size; (void)ws_size;
    const float* query = (const float*)d_in[0];
    const float* Wq  = (const float*)d_in[2];  const float* bq  = (const float*)d_in[3];
    const float* Wk  = (const float*)d_in[4];  const float* bk  = (const float*)d_in[5];
    const float* Wv  = (const float*)d_in[6];  const float* bv  = (const float*)d_in[7];
    const float* Wqg = (const float*)d_in[8];  const float* bqg = (const float*)d_in[9];
    const float* Wkg = (const float*)d_in[10]; const float* bkg = (const float*)d_in[11];
    const float* Wvg = (const float*)d_in[12]; const float* bvg = (const float*)d_in[13];
    const float* Wo  = (const float*)d_in[14]; const float* bo  = (const float*)d_in[15];

    const size_t nfull = (size_t)BBATCH * TT * EE;      // 8.39M elems
    const size_t wsz   = (size_t)1 << 20;               // one weight, elems
    u16* xb    = (u16*)d_ws;                            // bf16 x [B,T,E]; later reused as attnb
    u16* wb    = xb + nfull;                            // 7 converted weights
    u16* slotA = wb + 7 * wsz;                          // kg, then q
    u16* slotB = slotA + nfull;                         // vgt, then k
    u16* slotC = slotB + nfull;                         // vt [B,H,D,T]
    u16* qg    = slotC + nfull;                         // [B*G, E]
    float* Op  = (float*)(qg + (size_t)BBATCH * GG * EE);
    float* Ml  = Op + (size_t)BBATCH * HH * NSPLIT * GG * DD;
    float* Ll  = Ml + (size_t)BBATCH * HH * NSPLIT * GG;
    u16* attnb = xb;                                    // alias: xb dead after last GEMM that reads it
    // peak ws ≈ 86 MB

    WPtrs wp;   // order: fuse3 (Wq,Wk,Wv) | fuse2 (Wkg,Wvg) | Wqg | Wo
    wp.p[0] = Wq; wp.p[1] = Wk; wp.p[2] = Wv;
    wp.p[3] = Wkg; wp.p[4] = Wvg; wp.p[5] = Wqg; wp.p[6] = Wo;

    const dim3 blk(256);
    const dim3 gF2(16, 64);     // 128^2 tiles, N=2048
    const dim3 gF3(24, 64);     // 128^2 tiles, N=3072
    const dim3 gFull(8, 64);    // 128^2 tiles, N=1024 (Wo)
    const dim3 gQg(8, 1);
    const float sc = 0.125f * LOG2E;   // D^-0.5, pre-scaled for exp2 softmax

    conv_kernel<<<7680, blk, 0, stream>>>(wp, query, wb, xb);

    // qg projection (reads xb) — tiny M, keep simple kernel; log2e folded in
    gemm_kernel<0, 1, 0><<<gQg, blk, 0, stream>>>(xb, wb + 5 * wsz, bqg, qg, sc);

    // fused kg|vgt projection (vg written transposed per head for the flash)
    FusedArgs fa2;
    fa2.out[0] = slotA; fa2.out[1] = slotB; fa2.out[2] = nullptr;
    fa2.bias[0] = bkg;  fa2.bias[1] = bvg;  fa2.bias[2] = nullptr;
    fa2.scale[0] = 1.f; fa2.scale[1] = 1.f; fa2.scale[2] = 1.f;
    fa2.vseg = 1;
    gemm_pipe_kernel<2, 0, 0><<<gF2, blk, 0, stream>>>(xb, wb + 3 * wsz, fa2);
    global_attn_flash_kernel<<<BBATCH * HH * NSPLIT, blk, 0, stream>>>(qg, slotA, slotB, Op, Ml, Ll);

    // fused q|k|vt projection (q pre-scaled by D^-0.5 * log2e for exp2 softmax)
    FusedArgs fa3;
    fa3.out[0] = slotA; fa3.out[1] = slotB; fa3.out[2] = slotC;
    fa3.bias[0] = bq;   fa3.bias[1] = bk;   fa3.bias[2] = bv;
    fa3.scale[0] = sc;  fa3.scale[1] = 1.f; fa3.scale[2] = 1.f;
    fa3.vseg = 2;
    gemm_pipe_kernel<3, 0, 0><<<gF3, blk, 0, stream>>>(xb, wb, fa3);

    band_attn_kernel<<<BBATCH * HH * (TT / 64), blk, 0, stream>>>(slotA, slotB, slotC, attnb);
    global_combine_kernel<<<BBATCH * HH, blk, 0, stream>>>(Op, Ml, Ll, attnb);

    // output projection (128^2 pipelined, f32 out, [B,T]->[T,B] row perm)
    FusedArgs faO;
    faO.out[0] = (u16*)d_out; faO.out[1] = nullptr; faO.out[2] = nullptr;
    faO.bias[0] = bo;         faO.bias[1] = nullptr; faO.bias[2] = nullptr;
    faO.scale[0] = 1.f;       faO.scale[1] = 1.f;    faO.scale[2] = 1.f;
    faO.vseg = -1;
    gemm_pipe_kernel<1, 1, 1><<<gFull, blk, 0, stream>>>(attnb, wb + 6 * wsz, faO);
}

// Round 13
// 329.925 us; speedup vs baseline: 1.0346x; 1.0154x over previous
//
#include <hip/hip_runtime.h>
#include <hip/hip_bf16.h>

typedef unsigned short u16;
typedef __bf16 bf16x8 __attribute__((ext_vector_type(8)));
typedef float  f32x4  __attribute__((ext_vector_type(4)));

constexpr int TT = 4096;   // seq
constexpr int BBATCH = 2;  // batch
constexpr int EE = 1024;   // embed
constexpr int HH = 16;     // heads
constexpr int DD = 64;     // head dim
constexpr int WQ = 256;    // one-sided window
constexpr int GG = 64;     // global tokens
constexpr int NSPLIT = 8;  // key splits for global attention
constexpr float LOG2E = 1.4426950408889634f;

// ---------- bf16 / math helpers ----------
__device__ __forceinline__ float fast_exp2(float x) {
    return __builtin_amdgcn_exp2f(x);   // native v_exp_f32 (2^x)
}
__device__ __forceinline__ u16 f2bf(float f) {
    union { float f; unsigned int i; } c; c.f = f;
    unsigned int x = c.i;
    return (u16)((x + 0x7fffu + ((x >> 16) & 1u)) >> 16);  // RNE
}
__device__ __forceinline__ unsigned cvt_pk_bf16(float a, float b) {
    unsigned r;
    asm("v_cvt_pk_bf16_f32 %0, %1, %2" : "=v"(r) : "v"(a), "v"(b));
    return r;  // low16 = bf16(a), high16 = bf16(b), RNE
}
__device__ __forceinline__ uint4 pack8(float4 a, float4 b) {
    uint4 r;
    r.x = (unsigned)f2bf(a.x) | ((unsigned)f2bf(a.y) << 16);
    r.y = (unsigned)f2bf(a.z) | ((unsigned)f2bf(a.w) << 16);
    r.z = (unsigned)f2bf(b.x) | ((unsigned)f2bf(b.y) << 16);
    r.w = (unsigned)f2bf(b.z) | ((unsigned)f2bf(b.w) << 16);
    return r;
}

// async global->LDS, 16B per lane; LDS dest = wave-uniform base + lane*16
__device__ __forceinline__ void g2l16(const u16* g, u16* l) {
    __builtin_amdgcn_global_load_lds(
        (const __attribute__((address_space(1))) void*)g,
        (__attribute__((address_space(3))) void*)l, 16, 0, 0);
}

// XCD swizzle: blocks sharing an M-tile (y) get linear ids == c (mod 8) -> one XCD's L2
__device__ __forceinline__ void xcd_swizzle(int& bx, int& by) {
    bx = blockIdx.x; by = blockIdx.y;
    if ((gridDim.y & 7) == 0) {
        const int g   = blockIdx.x + blockIdx.y * gridDim.x;
        const int idx = g >> 3;
        bx = idx % gridDim.x;
        by = (g & 7) + ((idx / gridDim.x) << 3);
    }
}

// ---------- fp32 -> bf16 conversion ----------
struct WPtrs { const float* p[7]; };
__global__ __launch_bounds__(256) void conv_kernel(
    WPtrs wp, const float* __restrict__ query, u16* __restrict__ wb, u16* __restrict__ xb)
{
    const size_t i8 = ((size_t)blockIdx.x * 256 + threadIdx.x) << 3;
    const size_t WTOT = (size_t)7 << 20;   // 7 x 1024*1024
    const float* src;
    u16* dst;
    if (i8 < WTOT) {
        const int which = (int)(i8 >> 20);
        src = wp.p[which] + (i8 & (((size_t)1 << 20) - 1));
        dst = wb + i8;
    } else {
        const size_t j = i8 - WTOT;            // dst index in [B,T,E]
        const size_t e = j & (EE - 1);
        const size_t t = (j >> 10) & (TT - 1);
        const size_t b = j >> 22;
        src = query + (t * BBATCH + b) * EE + e;
        dst = xb + j;
    }
    const float4 f0 = *(const float4*)src;
    const float4 f1 = *(const float4*)(src + 4);
    *(uint4*)dst = pack8(f0, f1);
}

// ---------- single-output GEMM (qg only: tiny M) ----------
template<int C_F32, int PERMA_QG, int PERMC_TB>
__global__ __launch_bounds__(256) void gemm_kernel(
    const u16* __restrict__ A, const u16* __restrict__ W, const float* __restrict__ bias,
    void* __restrict__ Cv, float scale)
{
    const int tid = threadIdx.x, lane = tid & 63, w = tid >> 6;
    const int wm = w >> 1, wn = w & 1;
    int bx, by;
    xcd_swizzle(bx, by);
    const int m0 = by << 7, n0 = bx << 7;

    __shared__ __align__(16) u16 As[2 * 128 * 32];   // two 32-col panels
    __shared__ __align__(16) u16 Bs[2 * 128 * 32];

    const int lrow = lane >> 2;
    const int lcol = (lane & 3) << 3;
    auto arow = [](int m) -> size_t {
        return PERMA_QG ? (size_t)(((m >> 6) << 12) | (m & 63)) : (size_t)m;
    };
    const u16* gA0 = A + arow(m0 + (w << 4) + lrow) * EE + lcol;
    const u16* gA1 = A + arow(m0 + 64 + (w << 4) + lrow) * EE + lcol;
    const u16* gB0 = W + (size_t)(n0 + (w << 4) + lrow) * EE + lcol;
    const u16* gB1 = gB0 + (size_t)64 * EE;
    u16* lA0 = As + (w << 9);
    u16* lA1 = As + 2048 + (w << 9);
    u16* lB0 = Bs + (w << 9);
    u16* lB1 = Bs + 2048 + (w << 9);

    f32x4 acc[4][4];
#pragma unroll
    for (int i = 0; i < 4; i++)
#pragma unroll
        for (int j = 0; j < 4; j++)
            acc[i][j] = (f32x4){0.f, 0.f, 0.f, 0.f};

    const int fr = lane & 15;
    const int fq = (lane >> 4) << 3;

    for (int k0 = 0; k0 < EE; k0 += 64) {
        g2l16(gA0 + k0, lA0);  g2l16(gA0 + k0 + 32, lA0 + 4096);
        g2l16(gA1 + k0, lA1);  g2l16(gA1 + k0 + 32, lA1 + 4096);
        g2l16(gB0 + k0, lB0);  g2l16(gB0 + k0 + 32, lB0 + 4096);
        g2l16(gB1 + k0, lB1);  g2l16(gB1 + k0 + 32, lB1 + 4096);
        __syncthreads();
#pragma unroll
        for (int p = 0; p < 2; p++) {
            bf16x8 af[4], bfv[4];
#pragma unroll
            for (int i = 0; i < 4; i++)
                af[i] = *(const bf16x8*)&As[p * 4096 + ((wm << 6) + (i << 4) + fr) * 32 + fq];
#pragma unroll
            for (int j = 0; j < 4; j++)
                bfv[j] = *(const bf16x8*)&Bs[p * 4096 + ((wn << 6) + (j << 4) + fr) * 32 + fq];
#pragma unroll
            for (int i = 0; i < 4; i++)
#pragma unroll
                for (int j = 0; j < 4; j++)
                    acc[i][j] = __builtin_amdgcn_mfma_f32_16x16x32_bf16(af[i], bfv[j], acc[i][j], 0, 0, 0);
        }
        __syncthreads();
    }

    const int colbase = n0 + (wn << 6);
    const int rowbase = m0 + (wm << 6) + ((lane >> 4) << 2);
#pragma unroll
    for (int j = 0; j < 4; j++) {
        const int col = colbase + (j << 4) + fr;
        const float bv = bias[col];
#pragma unroll
        for (int i = 0; i < 4; i++) {
#pragma unroll
            for (int r = 0; r < 4; r++) {
                const int row = rowbase + (i << 4) + r;
                const float val = (acc[i][j][r] + bv) * scale;
                const size_t dst = (size_t)(PERMC_TB ? (((row & (TT - 1)) << 1) | (row >> 12)) : row) * EE + col;
                if (C_F32) ((float*)Cv)[dst] = val;
                else       ((u16*)Cv)[dst]   = f2bf(val);
            }
        }
    }
}

struct FusedArgs { u16* out[3]; const float* bias[3]; float scale[3]; int vseg; };

// ---------- pipelined 128x128 GEMM (verified best: 0 bank conflicts, 2 blocks/CU) ----------
template<int NSEG, int CF32, int PERMC>
__global__ __launch_bounds__(256, 2) void gemm_pipe_kernel(
    const u16* __restrict__ A, const u16* __restrict__ W, FusedArgs fa)
{
    const int tid = threadIdx.x, lane = tid & 63, w = tid >> 6;
    const int wm = w >> 1, wn = w & 1;
    int bx, by;
    xcd_swizzle(bx, by);
    const int m0 = by << 7, n0 = bx << 7;

    __shared__ __align__(16) u16 As[2][8192];   // [buf][128][64], swizzled
    __shared__ __align__(16) u16 Bs[2][8192];

    const int srow = lane >> 3;                        // 0..7 (== dest row & 7)
    const int scol = ((lane & 7) ^ srow) << 3;         // pre-swizzled source col (elems)
    const u16* gA = A + (size_t)(m0 + (w << 5) + srow) * EE + scol;
    const u16* gB = W + (size_t)(n0 + (w << 5) + srow) * EE + scol;
    u16* lA = &As[0][0] + (w << 11);
    u16* lB = &Bs[0][0] + (w << 11);

    f32x4 acc[4][4];
#pragma unroll
    for (int i = 0; i < 4; i++)
#pragma unroll
        for (int j = 0; j < 4; j++)
            acc[i][j] = (f32x4){0.f, 0.f, 0.f, 0.f};

    const int fr = lane & 15;
    const int qb = (lane >> 4) << 4;                   // frag 16B-chunk byte col
    const int xr = (fr & 7) << 4;                      // read-side swizzle XOR

    auto stageA = [&](int k0, int buf) {
#pragma unroll
        for (int l = 0; l < 4; l++)
            g2l16(gA + (size_t)(l << 3) * EE + k0, lA + buf * 8192 + (l << 9));
    };
    auto stageB = [&](int k0, int buf) {
#pragma unroll
        for (int l = 0; l < 4; l++)
            g2l16(gB + (size_t)(l << 3) * EE + k0, lB + buf * 8192 + (l << 9));
    };

    stageA(0, 0);
    stageB(0, 0);
    __syncthreads();

    constexpr int NT = EE / 64;                        // 16 K-tiles
#pragma unroll 2
    for (int t = 0; t < NT; t++) {
        const int buf = t & 1;
        const bool pf = (t + 1 < NT);
        const int kn = (t + 1) << 6;
        bf16x8 af[4], bfv[4];

        // ---- phase 0 : k-half 0 ----
#pragma unroll
        for (int mi = 0; mi < 4; mi++)
            af[mi] = *(const bf16x8*)((const char*)&As[buf][0] +
                      ((((wm << 6) + (mi << 4) + fr)) << 7) + (qb ^ xr));
#pragma unroll
        for (int nj = 0; nj < 4; nj++)
            bfv[nj] = *(const bf16x8*)((const char*)&Bs[buf][0] +
                      ((((wn << 6) + (nj << 4) + fr)) << 7) + (qb ^ xr));
        if (pf) stageA(kn, buf ^ 1);
        __builtin_amdgcn_s_barrier();
        __builtin_amdgcn_s_setprio(1);
#pragma unroll
        for (int mi = 0; mi < 4; mi++)
#pragma unroll
            for (int nj = 0; nj < 4; nj++)
                acc[mi][nj] = __builtin_amdgcn_mfma_f32_16x16x32_bf16(af[mi], bfv[nj], acc[mi][nj], 0, 0, 0);
        __builtin_amdgcn_s_setprio(0);
        __builtin_amdgcn_s_barrier();

        // ---- phase 1 : k-half 1 ----
#pragma unroll
        for (int mi = 0; mi < 4; mi++)
            af[mi] = *(const bf16x8*)((const char*)&As[buf][0] +
                      ((((wm << 6) + (mi << 4) + fr)) << 7) + ((64 | qb) ^ xr));
#pragma unroll
        for (int nj = 0; nj < 4; nj++)
            bfv[nj] = *(const bf16x8*)((const char*)&Bs[buf][0] +
                      ((((wn << 6) + (nj << 4) + fr)) << 7) + ((64 | qb) ^ xr));
        if (pf) stageB(kn, buf ^ 1);
        __builtin_amdgcn_s_barrier();
        __builtin_amdgcn_s_setprio(1);
#pragma unroll
        for (int mi = 0; mi < 4; mi++)
#pragma unroll
            for (int nj = 0; nj < 4; nj++)
                acc[mi][nj] = __builtin_amdgcn_mfma_f32_16x16x32_bf16(af[mi], bfv[nj], acc[mi][nj], 0, 0, 0);
        __builtin_amdgcn_s_setprio(0);
        __syncthreads();
    }

    const int seg = (NSEG > 1) ? (n0 >> 10) : 0;
    u16* outp = fa.out[seg];
    const float* bp = fa.bias[seg];
    const float scl = fa.scale[seg];
    const bool vtr = (NSEG > 1) && (seg == fa.vseg);

    const int colbase = n0 + (wn << 6);
    const int rowbase = m0 + (wm << 6) + ((lane >> 4) << 2);
#pragma unroll
    for (int j = 0; j < 4; j++) {
        const int col = colbase + (j << 4) + fr;
        const int cl  = col & (EE - 1);
        const float bv = bp[cl];
#pragma unroll
        for (int i = 0; i < 4; i++) {
            if (vtr) {
                const int row0 = rowbase + (i << 4);
                const int bb = row0 >> 12, t = row0 & (TT - 1);
                const int hh = cl >> 6, d = cl & 63;
                ushort4 pk;
                pk.x = f2bf((acc[i][j][0] + bv) * scl);
                pk.y = f2bf((acc[i][j][1] + bv) * scl);
                pk.z = f2bf((acc[i][j][2] + bv) * scl);
                pk.w = f2bf((acc[i][j][3] + bv) * scl);
                *(ushort4*)(outp + (((size_t)(bb * HH + hh) * DD + d) * TT + t)) = pk;
            } else {
#pragma unroll
                for (int r = 0; r < 4; r++) {
                    const int row = rowbase + (i << 4) + r;
                    const float val = (acc[i][j][r] + bv) * scl;
                    const size_t drow = PERMC ? (size_t)(((row & (TT - 1)) << 1) | (row >> 12))
                                              : (size_t)row;
                    if (CF32) ((float*)outp)[drow * EE + cl] = val;
                    else      outp[drow * EE + cl] = f2bf(val);
                }
            }
        }
    }
}

// ---------- band attention: S^T softmax + async staging + defer-max + exp2 ----------
__global__ __launch_bounds__(256) void band_attn_kernel(
    const u16* __restrict__ q, const u16* __restrict__ k, const u16* __restrict__ vt,
    u16* __restrict__ attnb)
{
    const int tid  = threadIdx.x;
    const int lane = tid & 63;
    const int w    = tid >> 6;
    const int col  = lane & 15;
    const int quad = lane >> 4;

    const int qt = blockIdx.x >> 5;
    const int bh = blockIdx.x & 31;
    const int h  = bh & (HH - 1);
    const int b  = bh >> 4;
    const int t0 = qt << 6;

    __shared__ __align__(16) u16 Ks[2][64][72];   // [buf][key][dim]
    __shared__ __align__(16) u16 Vs[2][64][72];   // [buf][dim][key]
    __shared__ __align__(16) u16 Ps[4][16][72];   // [wave][q][k]

    const size_t base   = (size_t)b * TT * EE + (size_t)h * DD;
    const size_t vtbase = (size_t)bh * DD * TT;

    const u16* qp = q + base + (size_t)(t0 + (w << 4) + col) * EE + (quad << 3);
    const bf16x8 qf0 = *(const bf16x8*)qp;
    const bf16x8 qf1 = *(const bf16x8*)(qp + 32);

    float m_i = -1e30f, l_i = 0.f;
    f32x4 acc_o[4];
#pragma unroll
    for (int nt = 0; nt < 4; nt++) acc_o[nt] = (f32x4){0.f, 0.f, 0.f, 0.f};

    const int c_lo = 1 + ((t0 < WQ) ? ((WQ - t0) >> 6) : 0);
    const int c_hi = min(9, 1 + ((TT + WQ - 64 - t0) >> 6));
    const int NTL  = 2 + c_hi - c_lo;              // tiles: 1 global + window tiles

    const int srow  = tid >> 2;
    const int spart = (tid & 3) << 4;

    uint4 kr0, kr1, vr0, vr1;                      // staging regs (in flight)
    auto issue_loads = [&](int i) {
        const int kpos0 = (i == 0) ? 0 : (t0 - WQ + ((c_lo + i - 2) << 6));
        const u16* ks = k + base + (size_t)(kpos0 + srow) * EE + spart;
        const u16* vs = vt + vtbase + (size_t)srow * TT + kpos0 + spart;
        kr0 = *(const uint4*)ks;
        kr1 = *(const uint4*)(ks + 8);
        vr0 = *(const uint4*)vs;
        vr1 = *(const uint4*)(vs + 8);
    };
    auto write_stage = [&](int buf) {
        *(uint4*)&Ks[buf][srow][spart]     = kr0;
        *(uint4*)&Ks[buf][srow][spart + 8] = kr1;
        *(uint4*)&Vs[buf][srow][spart]     = vr0;
        *(uint4*)&Vs[buf][srow][spart + 8] = vr1;
    };

    issue_loads(0);
    write_stage(0);
    int buf = 0;

    const int qrow = (w << 4) + col;               // this lane's query row (rel t0)
    const int alsrc0 = (lane & 48) | ((lane >> 2) & 12);  // lane holding alpha/l for row quad*4+r

#pragma unroll 1
    for (int i = 0; i < NTL; i++) {
        __syncthreads();                           // LDS[buf] ready for all waves
        const int c     = c_lo + i - 1;            // window chunk id (i>=1)
        const int jbase = (i > 0 && (c == 1 || c == 9)) ? ((c - 1) << 6) : -1;
        const bool pf   = (i + 1 < NTL);
        if (pf) issue_loads(i + 1);                // latency hides under compute

        // QK^T transposed: sT[nt] row=key(quad*4+r), col=q
        f32x4 sT[4];
#pragma unroll
        for (int nt = 0; nt < 4; nt++) {
            const bf16x8 kf0 = *(const bf16x8*)&Ks[buf][(nt << 4) + col][quad << 3];
            const bf16x8 kf1 = *(const bf16x8*)&Ks[buf][(nt << 4) + col][32 + (quad << 3)];
            f32x4 s = (f32x4){0.f, 0.f, 0.f, 0.f};
            s = __builtin_amdgcn_mfma_f32_16x16x32_bf16(kf0, qf0, s, 0, 0, 0);
            s = __builtin_amdgcn_mfma_f32_16x16x32_bf16(kf1, qf1, s, 0, 0, 0);
            sT[nt] = s;
        }

        if (jbase >= 0) {
#pragma unroll
            for (int nt = 0; nt < 4; nt++) {
#pragma unroll
                for (int r = 0; r < 4; r++) {
                    const int jp = jbase + (nt << 4) + (quad << 2) + r;
                    const bool ok = (jp >= qrow) && (jp <= qrow + 2 * WQ);
                    if (!ok) sT[nt][r] = -1e30f;
                }
            }
        }

        // per-lane online softmax over this lane's 16 keys + cross-quad reduce
        float mx = sT[0][0];
#pragma unroll
        for (int nt = 0; nt < 4; nt++)
#pragma unroll
            for (int r = 0; r < 4; r++) mx = fmaxf(mx, sT[nt][r]);
        mx = fmaxf(mx, __shfl_xor(mx, 16));
        mx = fmaxf(mx, __shfl_xor(mx, 32));

        // T13 defer-max (log2 units): skip rescale when growth <= 11 (P <= 2^11)
        if (!__all(mx - m_i <= 11.0f)) {
            const float m_new = fmaxf(m_i, mx);
            const float alpha = fast_exp2(m_i - m_new);
            m_i = m_new;
            l_i *= alpha;
            float al[4];
#pragma unroll
            for (int r = 0; r < 4; r++) al[r] = __shfl(alpha, alsrc0 | r);
#pragma unroll
            for (int nt = 0; nt < 4; nt++)
#pragma unroll
                for (int r = 0; r < 4; r++) acc_o[nt][r] *= al[r];
        }

        float ps = 0.f;
#pragma unroll
        for (int nt = 0; nt < 4; nt++)
#pragma unroll
            for (int r = 0; r < 4; r++) {
                const float e = fast_exp2(sT[nt][r] - m_i);
                sT[nt][r] = e;
                ps += e;
            }
        ps += __shfl_xor(ps, 16);
        ps += __shfl_xor(ps, 32);
        l_i += ps;

        // P pack + write: row q=col, k = nt*16 + quad*4 + {0..3}
#pragma unroll
        for (int nt = 0; nt < 4; nt++) {
            uint2 pk2;
            pk2.x = cvt_pk_bf16(sT[nt][0], sT[nt][1]);
            pk2.y = cvt_pk_bf16(sT[nt][2], sT[nt][3]);
            *(uint2*)&Ps[w][col][(nt << 4) + (quad << 2)] = pk2;
        }

        const bf16x8 pf0 = *(const bf16x8*)&Ps[w][col][quad << 3];
        const bf16x8 pf1 = *(const bf16x8*)&Ps[w][col][32 + (quad << 3)];

#pragma unroll
        for (int nt = 0; nt < 4; nt++) {
            const bf16x8 vf0 = *(const bf16x8*)&Vs[buf][(nt << 4) + col][quad << 3];
            const bf16x8 vf1 = *(const bf16x8*)&Vs[buf][(nt << 4) + col][32 + (quad << 3)];
            acc_o[nt] = __builtin_amdgcn_mfma_f32_16x16x32_bf16(pf0, vf0, acc_o[nt], 0, 0, 0);
            acc_o[nt] = __builtin_amdgcn_mfma_f32_16x16x32_bf16(pf1, vf1, acc_o[nt], 0, 0, 0);
        }

        if (pf) write_stage(buf ^ 1);              // regs -> other buffer (no barrier needed)
        buf ^= 1;
    }

    float inv[4];
#pragma unroll
    for (int r = 0; r < 4; r++) inv[r] = 1.f / __shfl(l_i, alsrc0 | r);
#pragma unroll
    for (int nt = 0; nt < 4; nt++) {
#pragma unroll
        for (int r = 0; r < 4; r++) {
            const int t = t0 + (w << 4) + (quad << 2) + r;
            attnb[base + (size_t)t * EE + (nt << 4) + col] = f2bf(acc_o[nt][r] * inv[r]);
        }
    }
}

// ---------- global-token attention: swapped QK^T + transposed V + defer-max + exp2 ----------
__global__ __launch_bounds__(256) void global_attn_flash_kernel(
    const u16* __restrict__ qg, const u16* __restrict__ kg, const u16* __restrict__ vgt,
    float* __restrict__ Op, float* __restrict__ Ml, float* __restrict__ Ll)
{
    const int tid  = threadIdx.x;
    const int lane = tid & 63;
    const int w    = tid >> 6;
    const int col  = lane & 15;
    const int quad = lane >> 4;

    const int s  = blockIdx.x & (NSPLIT - 1);
    const int h  = (blockIdx.x >> 3) & (HH - 1);
    const int b  = blockIdx.x >> 7;
    const int k0pos = s * (TT / NSPLIT);

    __shared__ __align__(16) u16 Ks[2][64][72];   // [buf][key][dim]
    __shared__ __align__(16) u16 Vs[2][64][72];   // [buf][dim][key]
    __shared__ __align__(16) u16 Ps[4][16][72];   // [wave][q][k]

    const size_t base   = (size_t)b * TT * EE + (size_t)h * DD;        // kg row-major
    const size_t vtbase = (size_t)((b << 4) | h) * DD * TT;            // vgt [B,H,D,T]

    const u16* qp = qg + (size_t)(b * GG + (w << 4) + col) * EE + (size_t)h * DD + (quad << 3);
    const bf16x8 qf0 = *(const bf16x8*)qp;
    const bf16x8 qf1 = *(const bf16x8*)(qp + 32);

    float m_i = -1e30f, l_i = 0.f;
    f32x4 acc_o[4];
#pragma unroll
    for (int nt = 0; nt < 4; nt++) acc_o[nt] = (f32x4){0.f, 0.f, 0.f, 0.f};

    constexpr int NTL = TT / NSPLIT / 64;          // 8 key tiles per split
    const int srow  = tid >> 2;
    const int spart = (tid & 3) << 4;

    uint4 kr0, kr1, vr0, vr1;
    auto issue_loads = [&](int i) {
        const int kpos0 = k0pos + (i << 6);
        const u16* ks = kg + base + (size_t)(kpos0 + srow) * EE + spart;
        const u16* vs = vgt + vtbase + (size_t)srow * TT + kpos0 + spart;
        kr0 = *(const uint4*)ks;
        kr1 = *(const uint4*)(ks + 8);
        vr0 = *(const uint4*)vs;
        vr1 = *(const uint4*)(vs + 8);
    };
    auto write_stage = [&](int buf) {
        *(uint4*)&Ks[buf][srow][spart]     = kr0;
        *(uint4*)&Ks[buf][srow][spart + 8] = kr1;
        *(uint4*)&Vs[buf][srow][spart]     = vr0;
        *(uint4*)&Vs[buf][srow][spart + 8] = vr1;
    };

    issue_loads(0);
    write_stage(0);
    int buf = 0;

    const int alsrc0 = (lane & 48) | ((lane >> 2) & 12);

#pragma unroll 1
    for (int i = 0; i < NTL; i++) {
        __syncthreads();
        const bool pf = (i + 1 < NTL);
        if (pf) issue_loads(i + 1);

        f32x4 sT[4];
#pragma unroll
        for (int nt = 0; nt < 4; nt++) {
            const bf16x8 kf0 = *(const bf16x8*)&Ks[buf][(nt << 4) + col][quad << 3];
            const bf16x8 kf1 = *(const bf16x8*)&Ks[buf][(nt << 4) + col][32 + (quad << 3)];
            f32x4 sv = (f32x4){0.f, 0.f, 0.f, 0.f};
            sv = __builtin_amdgcn_mfma_f32_16x16x32_bf16(kf0, qf0, sv, 0, 0, 0);
            sv = __builtin_amdgcn_mfma_f32_16x16x32_bf16(kf1, qf1, sv, 0, 0, 0);
            sT[nt] = sv;
        }

        float mx = sT[0][0];
#pragma unroll
        for (int nt = 0; nt < 4; nt++)
#pragma unroll
            for (int r = 0; r < 4; r++) mx = fmaxf(mx, sT[nt][r]);
        mx = fmaxf(mx, __shfl_xor(mx, 16));
        mx = fmaxf(mx, __shfl_xor(mx, 32));

        if (!__all(mx - m_i <= 11.0f)) {
            const float m_new = fmaxf(m_i, mx);
            const float alpha = fast_exp2(m_i - m_new);
            m_i = m_new;
            l_i *= alpha;
            float al[4];
#pragma unroll
            for (int r = 0; r < 4; r++) al[r] = __shfl(alpha, alsrc0 | r);
#pragma unroll
            for (int nt = 0; nt < 4; nt++)
#pragma unroll
                for (int r = 0; r < 4; r++) acc_o[nt][r] *= al[r];
        }

        float ps = 0.f;
#pragma unroll
        for (int nt = 0; nt < 4; nt++)
#pragma unroll
            for (int r = 0; r < 4; r++) {
                const float e = fast_exp2(sT[nt][r] - m_i);
                sT[nt][r] = e;
                ps += e;
            }
        ps += __shfl_xor(ps, 16);
        ps += __shfl_xor(ps, 32);
        l_i += ps;

#pragma unroll
        for (int nt = 0; nt < 4; nt++) {
            uint2 pk2;
            pk2.x = cvt_pk_bf16(sT[nt][0], sT[nt][1]);
            pk2.y = cvt_pk_bf16(sT[nt][2], sT[nt][3]);
            *(uint2*)&Ps[w][col][(nt << 4) + (quad << 2)] = pk2;
        }

        const bf16x8 pf0 = *(const bf16x8*)&Ps[w][col][quad << 3];
        const bf16x8 pf1 = *(const bf16x8*)&Ps[w][col][32 + (quad << 3)];

#pragma unroll
        for (int nt = 0; nt < 4; nt++) {
            const bf16x8 vf0 = *(const bf16x8*)&Vs[buf][(nt << 4) + col][quad << 3];
            const bf16x8 vf1 = *(const bf16x8*)&Vs[buf][(nt << 4) + col][32 + (quad << 3)];
            acc_o[nt] = __builtin_amdgcn_mfma_f32_16x16x32_bf16(pf0, vf0, acc_o[nt], 0, 0, 0);
            acc_o[nt] = __builtin_amdgcn_mfma_f32_16x16x32_bf16(pf1, vf1, acc_o[nt], 0, 0, 0);
        }

        if (pf) write_stage(buf ^ 1);
        buf ^= 1;
    }

    const size_t obase = (size_t)blockIdx.x * GG * DD;
#pragma unroll
    for (int nt = 0; nt < 4; nt++) {
#pragma unroll
        for (int r = 0; r < 4; r++) {
            const int row = (w << 4) + (quad << 2) + r;
            Op[obase + (size_t)row * DD + (nt << 4) + col] = acc_o[nt][r];
        }
    }
    if (quad == 0) {
        Ml[blockIdx.x * GG + (w << 4) + col] = m_i;
        Ll[blockIdx.x * GG + (w << 4) + col] = l_i;
    }
}

// ---------- combine split-K partials (m/l in log2 units -> exp2) ----------
// R13: grid 32 -> 128 blocks (4x parallelism); per-thread serial chain 32 -> 8 loads.
// Each block handles 16 rows; thread covers (row, 4-dim group). Math/order identical.
__global__ __launch_bounds__(256) void global_combine_kernel(
    const float* __restrict__ Op, const float* __restrict__ Ml, const float* __restrict__ Ll,
    u16* __restrict__ attnb)
{
    const int bh  = blockIdx.x >> 2;               // batch*head
    const int b   = bh >> 4;
    const int h   = bh & (HH - 1);
    const int row = ((blockIdx.x & 3) << 4) + (threadIdx.x >> 4);  // 16 rows/block
    const int d0  = (threadIdx.x & 15) << 2;       // 4-float dim group

    float mv[NSPLIT];
    float m = -1e30f;
#pragma unroll
    for (int s = 0; s < NSPLIT; s++) {
        mv[s] = Ml[(bh * NSPLIT + s) * GG + row];
        m = fmaxf(m, mv[s]);
    }
    float l = 0.f;
    float sc[NSPLIT];
#pragma unroll
    for (int s = 0; s < NSPLIT; s++) {
        sc[s] = fast_exp2(mv[s] - m);
        l += Ll[(bh * NSPLIT + s) * GG + row] * sc[s];
    }
    float o[4];
#pragma unroll
    for (int j = 0; j < 4; j++) o[j] = 0.f;
#pragma unroll
    for (int s = 0; s < NSPLIT; s++) {
        const float4 v4 = *(const float4*)(Op + ((size_t)(bh * NSPLIT + s) * GG + row) * DD + d0);
        const float f = sc[s];
        o[0] = fmaf(v4.x, f, o[0]);
        o[1] = fmaf(v4.y, f, o[1]);
        o[2] = fmaf(v4.z, f, o[2]);
        o[3] = fmaf(v4.w, f, o[3]);
    }
    const float inv = 1.f / l;
    u16* dst = attnb + ((size_t)b * TT + row) * EE + (size_t)h * DD + d0;
    ushort4 pk;
    pk.x = f2bf(o[0] * inv);
    pk.y = f2bf(o[1] * inv);
    pk.z = f2bf(o[2] * inv);
    pk.w = f2bf(o[3] * inv);
    *(ushort4*)dst = pk;
}

extern "C" void kernel_launch(void* const* d_in, const int* in_sizes, int n_in,
                              void* d_out, int out_size, void* d_ws, size_t ws_size,
                              hipStream_t stream)
{
    (void)in_sizes; (void)n_in; (void)out_size; (void)ws_size;
    const float* query = (const float*)d_in[0];
    const float* Wq  = (const float*)d_in[2];  const float* bq  = (const float*)d_in[3];
    const float* Wk  = (const float*)d_in[4];  const float* bk  = (const float*)d_in[5];
    const float* Wv  = (const float*)d_in[6];  const float* bv  = (const float*)d_in[7];
    const float* Wqg = (const float*)d_in[8];  const float* bqg = (const float*)d_in[9];
    const float* Wkg = (const float*)d_in[10]; const float* bkg = (const float*)d_in[11];
    const float* Wvg = (const float*)d_in[12]; const float* bvg = (const float*)d_in[13];
    const float* Wo  = (const float*)d_in[14]; const float* bo  = (const float*)d_in[15];

    const size_t nfull = (size_t)BBATCH * TT * EE;      // 8.39M elems
    const size_t wsz   = (size_t)1 << 20;               // one weight, elems
    u16* xb    = (u16*)d_ws;                            // bf16 x [B,T,E]; later reused as attnb
    u16* wb    = xb + nfull;                            // 7 converted weights
    u16* slotA = wb + 7 * wsz;                          // kg, then q
    u16* slotB = slotA + nfull;                         // vgt, then k
    u16* slotC = slotB + nfull;                         // vt [B,H,D,T]
    u16* qg    = slotC + nfull;                         // [B*G, E]
    float* Op  = (float*)(qg + (size_t)BBATCH * GG * EE);
    float* Ml  = Op + (size_t)BBATCH * HH * NSPLIT * GG * DD;
    float* Ll  = Ml + (size_t)BBATCH * HH * NSPLIT * GG;
    u16* attnb = xb;                                    // alias: xb dead after last GEMM that reads it
    // peak ws ≈ 86 MB

    WPtrs wp;   // order: fuse3 (Wq,Wk,Wv) | fuse2 (Wkg,Wvg) | Wqg | Wo
    wp.p[0] = Wq; wp.p[1] = Wk; wp.p[2] = Wv;
    wp.p[3] = Wkg; wp.p[4] = Wvg; wp.p[5] = Wqg; wp.p[6] = Wo;

    const dim3 blk(256);
    const dim3 gF2(16, 64);     // 128^2 tiles, N=2048
    const dim3 gF3(24, 64);     // 128^2 tiles, N=3072
    const dim3 gFull(8, 64);    // 128^2 tiles, N=1024 (Wo)
    const dim3 gQg(8, 1);
    const float sc = 0.125f * LOG2E;   // D^-0.5, pre-scaled for exp2 softmax

    conv_kernel<<<7680, blk, 0, stream>>>(wp, query, wb, xb);

    // qg projection (reads xb) — tiny M, keep simple kernel; log2e folded in
    gemm_kernel<0, 1, 0><<<gQg, blk, 0, stream>>>(xb, wb + 5 * wsz, bqg, qg, sc);

    // fused kg|vgt projection (vg written transposed per head for the flash)
    FusedArgs fa2;
    fa2.out[0] = slotA; fa2.out[1] = slotB; fa2.out[2] = nullptr;
    fa2.bias[0] = bkg;  fa2.bias[1] = bvg;  fa2.bias[2] = nullptr;
    fa2.scale[0] = 1.f; fa2.scale[1] = 1.f; fa2.scale[2] = 1.f;
    fa2.vseg = 1;
    gemm_pipe_kernel<2, 0, 0><<<gF2, blk, 0, stream>>>(xb, wb + 3 * wsz, fa2);
    global_attn_flash_kernel<<<BBATCH * HH * NSPLIT, blk, 0, stream>>>(qg, slotA, slotB, Op, Ml, Ll);

    // fused q|k|vt projection (q pre-scaled by D^-0.5 * log2e for exp2 softmax)
    FusedArgs fa3;
    fa3.out[0] = slotA; fa3.out[1] = slotB; fa3.out[2] = slotC;
    fa3.bias[0] = bq;   fa3.bias[1] = bk;   fa3.bias[2] = bv;
    fa3.scale[0] = sc;  fa3.scale[1] = 1.f; fa3.scale[2] = 1.f;
    fa3.vseg = 2;
    gemm_pipe_kernel<3, 0, 0><<<gF3, blk, 0, stream>>>(xb, wb, fa3);

    band_attn_kernel<<<BBATCH * HH * (TT / 64), blk, 0, stream>>>(slotA, slotB, slotC, attnb);
    global_combine_kernel<<<BBATCH * HH * 4, blk, 0, stream>>>(Op, Ml, Ll, attnb);

    // output projection (128^2 pipelined, f32 out, [B,T]->[T,B] row perm)
    FusedArgs faO;
    faO.out[0] = (u16*)d_out; faO.out[1] = nullptr; faO.out[2] = nullptr;
    faO.bias[0] = bo;         faO.bias[1] = nullptr; faO.bias[2] = nullptr;
    faO.scale[0] = 1.f;       faO.scale[1] = 1.f;    faO.scale[2] = 1.f;
    faO.vseg = -1;
    gemm_pipe_kernel<1, 1, 1><<<gFull, blk, 0, stream>>>(attnb, wb + 6 * wsz, faO);
}

// Round 14
// 325.995 us; speedup vs baseline: 1.0470x; 1.0121x over previous
//
#include <hip/hip_runtime.h>
#include <hip/hip_bf16.h>

typedef unsigned short u16;
typedef __bf16 bf16x8 __attribute__((ext_vector_type(8)));
typedef float  f32x4  __attribute__((ext_vector_type(4)));

constexpr int TT = 4096;   // seq
constexpr int BBATCH = 2;  // batch
constexpr int EE = 1024;   // embed
constexpr int HH = 16;     // heads
constexpr int DD = 64;     // head dim
constexpr int WQ = 256;    // one-sided window
constexpr int GG = 64;     // global tokens
constexpr int NSPLIT = 8;  // key splits for global attention
constexpr float LOG2E = 1.4426950408889634f;

// ---------- bf16 / math helpers ----------
__device__ __forceinline__ float fast_exp2(float x) {
    return __builtin_amdgcn_exp2f(x);   // native v_exp_f32 (2^x)
}
__device__ __forceinline__ u16 f2bf(float f) {
    union { float f; unsigned int i; } c; c.f = f;
    unsigned int x = c.i;
    return (u16)((x + 0x7fffu + ((x >> 16) & 1u)) >> 16);  // RNE
}
__device__ __forceinline__ unsigned cvt_pk_bf16(float a, float b) {
    unsigned r;
    asm("v_cvt_pk_bf16_f32 %0, %1, %2" : "=v"(r) : "v"(a), "v"(b));
    return r;  // low16 = bf16(a), high16 = bf16(b), RNE
}
__device__ __forceinline__ uint4 pack8(float4 a, float4 b) {
    uint4 r;
    r.x = (unsigned)f2bf(a.x) | ((unsigned)f2bf(a.y) << 16);
    r.y = (unsigned)f2bf(a.z) | ((unsigned)f2bf(a.w) << 16);
    r.z = (unsigned)f2bf(b.x) | ((unsigned)f2bf(b.y) << 16);
    r.w = (unsigned)f2bf(b.z) | ((unsigned)f2bf(b.w) << 16);
    return r;
}

// async global->LDS, 16B per lane; LDS dest = wave-uniform base + lane*16
__device__ __forceinline__ void g2l16(const u16* g, u16* l) {
    __builtin_amdgcn_global_load_lds(
        (const __attribute__((address_space(1))) void*)g,
        (__attribute__((address_space(3))) void*)l, 16, 0, 0);
}

// XCD swizzle: blocks sharing an M-tile (y) get linear ids == c (mod 8) -> one XCD's L2
__device__ __forceinline__ void xcd_swizzle(int& bx, int& by) {
    bx = blockIdx.x; by = blockIdx.y;
    if ((gridDim.y & 7) == 0) {
        const int g   = blockIdx.x + blockIdx.y * gridDim.x;
        const int idx = g >> 3;
        bx = idx % gridDim.x;
        by = (g & 7) + ((idx / gridDim.x) << 3);
    }
}

// ---------- fp32 -> bf16 conversion ----------
struct WPtrs { const float* p[7]; };
__global__ __launch_bounds__(256) void conv_kernel(
    WPtrs wp, const float* __restrict__ query, u16* __restrict__ wb, u16* __restrict__ xb)
{
    const size_t i8 = ((size_t)blockIdx.x * 256 + threadIdx.x) << 3;
    const size_t WTOT = (size_t)7 << 20;   // 7 x 1024*1024
    const float* src;
    u16* dst;
    if (i8 < WTOT) {
        const int which = (int)(i8 >> 20);
        src = wp.p[which] + (i8 & (((size_t)1 << 20) - 1));
        dst = wb + i8;
    } else {
        const size_t j = i8 - WTOT;            // dst index in [B,T,E]
        const size_t e = j & (EE - 1);
        const size_t t = (j >> 10) & (TT - 1);
        const size_t b = j >> 22;
        src = query + (t * BBATCH + b) * EE + e;
        dst = xb + j;
    }
    const float4 f0 = *(const float4*)src;
    const float4 f1 = *(const float4*)(src + 4);
    *(uint4*)dst = pack8(f0, f1);
}

// ---------- single-output GEMM (qg only: tiny M) ----------
template<int C_F32, int PERMA_QG, int PERMC_TB>
__global__ __launch_bounds__(256) void gemm_kernel(
    const u16* __restrict__ A, const u16* __restrict__ W, const float* __restrict__ bias,
    void* __restrict__ Cv, float scale)
{
    const int tid = threadIdx.x, lane = tid & 63, w = tid >> 6;
    const int wm = w >> 1, wn = w & 1;
    int bx, by;
    xcd_swizzle(bx, by);
    const int m0 = by << 7, n0 = bx << 7;

    __shared__ __align__(16) u16 As[2 * 128 * 32];   // two 32-col panels
    __shared__ __align__(16) u16 Bs[2 * 128 * 32];

    const int lrow = lane >> 2;
    const int lcol = (lane & 3) << 3;
    auto arow = [](int m) -> size_t {
        return PERMA_QG ? (size_t)(((m >> 6) << 12) | (m & 63)) : (size_t)m;
    };
    const u16* gA0 = A + arow(m0 + (w << 4) + lrow) * EE + lcol;
    const u16* gA1 = A + arow(m0 + 64 + (w << 4) + lrow) * EE + lcol;
    const u16* gB0 = W + (size_t)(n0 + (w << 4) + lrow) * EE + lcol;
    const u16* gB1 = gB0 + (size_t)64 * EE;
    u16* lA0 = As + (w << 9);
    u16* lA1 = As + 2048 + (w << 9);
    u16* lB0 = Bs + (w << 9);
    u16* lB1 = Bs + 2048 + (w << 9);

    f32x4 acc[4][4];
#pragma unroll
    for (int i = 0; i < 4; i++)
#pragma unroll
        for (int j = 0; j < 4; j++)
            acc[i][j] = (f32x4){0.f, 0.f, 0.f, 0.f};

    const int fr = lane & 15;
    const int fq = (lane >> 4) << 3;

    for (int k0 = 0; k0 < EE; k0 += 64) {
        g2l16(gA0 + k0, lA0);  g2l16(gA0 + k0 + 32, lA0 + 4096);
        g2l16(gA1 + k0, lA1);  g2l16(gA1 + k0 + 32, lA1 + 4096);
        g2l16(gB0 + k0, lB0);  g2l16(gB0 + k0 + 32, lB0 + 4096);
        g2l16(gB1 + k0, lB1);  g2l16(gB1 + k0 + 32, lB1 + 4096);
        __syncthreads();
#pragma unroll
        for (int p = 0; p < 2; p++) {
            bf16x8 af[4], bfv[4];
#pragma unroll
            for (int i = 0; i < 4; i++)
                af[i] = *(const bf16x8*)&As[p * 4096 + ((wm << 6) + (i << 4) + fr) * 32 + fq];
#pragma unroll
            for (int j = 0; j < 4; j++)
                bfv[j] = *(const bf16x8*)&Bs[p * 4096 + ((wn << 6) + (j << 4) + fr) * 32 + fq];
#pragma unroll
            for (int i = 0; i < 4; i++)
#pragma unroll
                for (int j = 0; j < 4; j++)
                    acc[i][j] = __builtin_amdgcn_mfma_f32_16x16x32_bf16(af[i], bfv[j], acc[i][j], 0, 0, 0);
        }
        __syncthreads();
    }

    const int colbase = n0 + (wn << 6);
    const int rowbase = m0 + (wm << 6) + ((lane >> 4) << 2);
#pragma unroll
    for (int j = 0; j < 4; j++) {
        const int col = colbase + (j << 4) + fr;
        const float bv = bias[col];
#pragma unroll
        for (int i = 0; i < 4; i++) {
#pragma unroll
            for (int r = 0; r < 4; r++) {
                const int row = rowbase + (i << 4) + r;
                const float val = (acc[i][j][r] + bv) * scale;
                const size_t dst = (size_t)(PERMC_TB ? (((row & (TT - 1)) << 1) | (row >> 12)) : row) * EE + col;
                if (C_F32) ((float*)Cv)[dst] = val;
                else       ((u16*)Cv)[dst]   = f2bf(val);
            }
        }
    }
}

struct FusedArgs { u16* out[3]; const float* bias[3]; float scale[3]; int vseg; };

// ---------- pipelined 128x128 GEMM (verified best: 0 bank conflicts, 2 blocks/CU) ----------
template<int NSEG, int CF32, int PERMC>
__global__ __launch_bounds__(256, 2) void gemm_pipe_kernel(
    const u16* __restrict__ A, const u16* __restrict__ W, FusedArgs fa)
{
    const int tid = threadIdx.x, lane = tid & 63, w = tid >> 6;
    const int wm = w >> 1, wn = w & 1;
    int bx, by;
    xcd_swizzle(bx, by);
    const int m0 = by << 7, n0 = bx << 7;

    __shared__ __align__(16) u16 As[2][8192];   // [buf][128][64], swizzled
    __shared__ __align__(16) u16 Bs[2][8192];

    const int srow = lane >> 3;                        // 0..7 (== dest row & 7)
    const int scol = ((lane & 7) ^ srow) << 3;         // pre-swizzled source col (elems)
    const u16* gA = A + (size_t)(m0 + (w << 5) + srow) * EE + scol;
    const u16* gB = W + (size_t)(n0 + (w << 5) + srow) * EE + scol;
    u16* lA = &As[0][0] + (w << 11);
    u16* lB = &Bs[0][0] + (w << 11);

    f32x4 acc[4][4];
#pragma unroll
    for (int i = 0; i < 4; i++)
#pragma unroll
        for (int j = 0; j < 4; j++)
            acc[i][j] = (f32x4){0.f, 0.f, 0.f, 0.f};

    const int fr = lane & 15;
    const int qb = (lane >> 4) << 4;                   // frag 16B-chunk byte col
    const int xr = (fr & 7) << 4;                      // read-side swizzle XOR

    auto stageA = [&](int k0, int buf) {
#pragma unroll
        for (int l = 0; l < 4; l++)
            g2l16(gA + (size_t)(l << 3) * EE + k0, lA + buf * 8192 + (l << 9));
    };
    auto stageB = [&](int k0, int buf) {
#pragma unroll
        for (int l = 0; l < 4; l++)
            g2l16(gB + (size_t)(l << 3) * EE + k0, lB + buf * 8192 + (l << 9));
    };

    stageA(0, 0);
    stageB(0, 0);
    __syncthreads();

    constexpr int NT = EE / 64;                        // 16 K-tiles
#pragma unroll 2
    for (int t = 0; t < NT; t++) {
        const int buf = t & 1;
        const bool pf = (t + 1 < NT);
        const int kn = (t + 1) << 6;
        bf16x8 af[4], bfv[4];

        // ---- phase 0 : k-half 0 ----
#pragma unroll
        for (int mi = 0; mi < 4; mi++)
            af[mi] = *(const bf16x8*)((const char*)&As[buf][0] +
                      ((((wm << 6) + (mi << 4) + fr)) << 7) + (qb ^ xr));
#pragma unroll
        for (int nj = 0; nj < 4; nj++)
            bfv[nj] = *(const bf16x8*)((const char*)&Bs[buf][0] +
                      ((((wn << 6) + (nj << 4) + fr)) << 7) + (qb ^ xr));
        if (pf) stageA(kn, buf ^ 1);
        __builtin_amdgcn_s_barrier();
        __builtin_amdgcn_s_setprio(1);
#pragma unroll
        for (int mi = 0; mi < 4; mi++)
#pragma unroll
            for (int nj = 0; nj < 4; nj++)
                acc[mi][nj] = __builtin_amdgcn_mfma_f32_16x16x32_bf16(af[mi], bfv[nj], acc[mi][nj], 0, 0, 0);
        __builtin_amdgcn_s_setprio(0);
        __builtin_amdgcn_s_barrier();

        // ---- phase 1 : k-half 1 ----
#pragma unroll
        for (int mi = 0; mi < 4; mi++)
            af[mi] = *(const bf16x8*)((const char*)&As[buf][0] +
                      ((((wm << 6) + (mi << 4) + fr)) << 7) + ((64 | qb) ^ xr));
#pragma unroll
        for (int nj = 0; nj < 4; nj++)
            bfv[nj] = *(const bf16x8*)((const char*)&Bs[buf][0] +
                      ((((wn << 6) + (nj << 4) + fr)) << 7) + ((64 | qb) ^ xr));
        if (pf) stageB(kn, buf ^ 1);
        __builtin_amdgcn_s_barrier();
        __builtin_amdgcn_s_setprio(1);
#pragma unroll
        for (int mi = 0; mi < 4; mi++)
#pragma unroll
            for (int nj = 0; nj < 4; nj++)
                acc[mi][nj] = __builtin_amdgcn_mfma_f32_16x16x32_bf16(af[mi], bfv[nj], acc[mi][nj], 0, 0, 0);
        __builtin_amdgcn_s_setprio(0);
        __syncthreads();
    }

    const int seg = (NSEG > 1) ? (n0 >> 10) : 0;
    u16* outp = fa.out[seg];
    const float* bp = fa.bias[seg];
    const float scl = fa.scale[seg];
    const bool vtr = (NSEG > 1) && (seg == fa.vseg);

    const int colbase = n0 + (wn << 6);
    const int rowbase = m0 + (wm << 6) + ((lane >> 4) << 2);
#pragma unroll
    for (int j = 0; j < 4; j++) {
        const int col = colbase + (j << 4) + fr;
        const int cl  = col & (EE - 1);
        const float bv = bp[cl];
#pragma unroll
        for (int i = 0; i < 4; i++) {
            if (vtr) {
                const int row0 = rowbase + (i << 4);
                const int bb = row0 >> 12, t = row0 & (TT - 1);
                const int hh = cl >> 6, d = cl & 63;
                ushort4 pk;
                pk.x = f2bf((acc[i][j][0] + bv) * scl);
                pk.y = f2bf((acc[i][j][1] + bv) * scl);
                pk.z = f2bf((acc[i][j][2] + bv) * scl);
                pk.w = f2bf((acc[i][j][3] + bv) * scl);
                *(ushort4*)(outp + (((size_t)(bb * HH + hh) * DD + d) * TT + t)) = pk;
            } else {
#pragma unroll
                for (int r = 0; r < 4; r++) {
                    const int row = rowbase + (i << 4) + r;
                    const float val = (acc[i][j][r] + bv) * scl;
                    const size_t drow = PERMC ? (size_t)(((row & (TT - 1)) << 1) | (row >> 12))
                                              : (size_t)row;
                    if (CF32) ((float*)outp)[drow * EE + cl] = val;
                    else      outp[drow * EE + cl] = f2bf(val);
                }
            }
        }
    }
}

// ---------- band attention + fused split-K combine ----------
// Blocks [0, 2048): band flash. qt==0 blocks (rows 0..63) early-exit: the reference
// REPLACES attn[:, :G] with the global-attention output, so their work is dead.
// Blocks [2048, 2176): the (widened) combine - writes exactly rows 0..63 per (b,h).
// Disjoint attnb row sets -> no inter-block ordering needed. Combine inputs (Op/Ml/Ll)
// complete before this launch.
__global__ __launch_bounds__(256) void band_attn_kernel(
    const u16* __restrict__ q, const u16* __restrict__ k, const u16* __restrict__ vt,
    u16* __restrict__ attnb,
    const float* __restrict__ Op, const float* __restrict__ Ml, const float* __restrict__ Ll)
{
    const int tid  = threadIdx.x;

    if (blockIdx.x >= BBATCH * HH * (TT / 64)) {
        // ---- combine path (m/l in log2 units -> exp2) ----
        const int cb  = blockIdx.x - BBATCH * HH * (TT / 64);
        const int bh  = cb >> 2;                     // batch*head
        const int b   = bh >> 4;
        const int h   = bh & (HH - 1);
        const int row = ((cb & 3) << 4) + (tid >> 4);  // 16 rows/block
        const int d0  = (tid & 15) << 2;             // 4-float dim group

        float mv[NSPLIT];
        float m = -1e30f;
#pragma unroll
        for (int s = 0; s < NSPLIT; s++) {
            mv[s] = Ml[(bh * NSPLIT + s) * GG + row];
            m = fmaxf(m, mv[s]);
        }
        float l = 0.f;
        float sc[NSPLIT];
#pragma unroll
        for (int s = 0; s < NSPLIT; s++) {
            sc[s] = fast_exp2(mv[s] - m);
            l += Ll[(bh * NSPLIT + s) * GG + row] * sc[s];
        }
        float o[4];
#pragma unroll
        for (int j = 0; j < 4; j++) o[j] = 0.f;
#pragma unroll
        for (int s = 0; s < NSPLIT; s++) {
            const float4 v4 = *(const float4*)(Op + ((size_t)(bh * NSPLIT + s) * GG + row) * DD + d0);
            const float f = sc[s];
            o[0] = fmaf(v4.x, f, o[0]);
            o[1] = fmaf(v4.y, f, o[1]);
            o[2] = fmaf(v4.z, f, o[2]);
            o[3] = fmaf(v4.w, f, o[3]);
        }
        const float inv = 1.f / l;
        u16* dst = attnb + ((size_t)b * TT + row) * EE + (size_t)h * DD + d0;
        ushort4 pk;
        pk.x = f2bf(o[0] * inv);
        pk.y = f2bf(o[1] * inv);
        pk.z = f2bf(o[2] * inv);
        pk.w = f2bf(o[3] * inv);
        *(ushort4*)dst = pk;
        return;
    }

    const int qt = blockIdx.x >> 5;
    if (qt == 0) return;                           // rows 0..63 are overwritten by combine

    const int lane = tid & 63;
    const int w    = tid >> 6;
    const int col  = lane & 15;
    const int quad = lane >> 4;

    const int bh = blockIdx.x & 31;
    const int h  = bh & (HH - 1);
    const int b  = bh >> 4;
    const int t0 = qt << 6;

    __shared__ __align__(16) u16 Ks[2][64][72];   // [buf][key][dim]
    __shared__ __align__(16) u16 Vs[2][64][72];   // [buf][dim][key]
    __shared__ __align__(16) u16 Ps[4][16][72];   // [wave][q][k]

    const size_t base   = (size_t)b * TT * EE + (size_t)h * DD;
    const size_t vtbase = (size_t)bh * DD * TT;

    const u16* qp = q + base + (size_t)(t0 + (w << 4) + col) * EE + (quad << 3);
    const bf16x8 qf0 = *(const bf16x8*)qp;
    const bf16x8 qf1 = *(const bf16x8*)(qp + 32);

    float m_i = -1e30f, l_i = 0.f;
    f32x4 acc_o[4];
#pragma unroll
    for (int nt = 0; nt < 4; nt++) acc_o[nt] = (f32x4){0.f, 0.f, 0.f, 0.f};

    const int c_lo = 1 + ((t0 < WQ) ? ((WQ - t0) >> 6) : 0);
    const int c_hi = min(9, 1 + ((TT + WQ - 64 - t0) >> 6));
    const int NTL  = 2 + c_hi - c_lo;              // tiles: 1 global + window tiles

    const int srow  = tid >> 2;
    const int spart = (tid & 3) << 4;

    uint4 kr0, kr1, vr0, vr1;                      // staging regs (in flight)
    auto issue_loads = [&](int i) {
        const int kpos0 = (i == 0) ? 0 : (t0 - WQ + ((c_lo + i - 2) << 6));
        const u16* ks = k + base + (size_t)(kpos0 + srow) * EE + spart;
        const u16* vs = vt + vtbase + (size_t)srow * TT + kpos0 + spart;
        kr0 = *(const uint4*)ks;
        kr1 = *(const uint4*)(ks + 8);
        vr0 = *(const uint4*)vs;
        vr1 = *(const uint4*)(vs + 8);
    };
    auto write_stage = [&](int buf) {
        *(uint4*)&Ks[buf][srow][spart]     = kr0;
        *(uint4*)&Ks[buf][srow][spart + 8] = kr1;
        *(uint4*)&Vs[buf][srow][spart]     = vr0;
        *(uint4*)&Vs[buf][srow][spart + 8] = vr1;
    };

    issue_loads(0);
    write_stage(0);
    int buf = 0;

    const int qrow = (w << 4) + col;               // this lane's query row (rel t0)
    const int alsrc0 = (lane & 48) | ((lane >> 2) & 12);  // lane holding alpha/l for row quad*4+r

#pragma unroll 1
    for (int i = 0; i < NTL; i++) {
        __syncthreads();                           // LDS[buf] ready for all waves
        const int c     = c_lo + i - 1;            // window chunk id (i>=1)
        const int jbase = (i > 0 && (c == 1 || c == 9)) ? ((c - 1) << 6) : -1;
        const bool pf   = (i + 1 < NTL);
        if (pf) issue_loads(i + 1);                // latency hides under compute

        // QK^T transposed: sT[nt] row=key(quad*4+r), col=q
        f32x4 sT[4];
#pragma unroll
        for (int nt = 0; nt < 4; nt++) {
            const bf16x8 kf0 = *(const bf16x8*)&Ks[buf][(nt << 4) + col][quad << 3];
            const bf16x8 kf1 = *(const bf16x8*)&Ks[buf][(nt << 4) + col][32 + (quad << 3)];
            f32x4 s = (f32x4){0.f, 0.f, 0.f, 0.f};
            s = __builtin_amdgcn_mfma_f32_16x16x32_bf16(kf0, qf0, s, 0, 0, 0);
            s = __builtin_amdgcn_mfma_f32_16x16x32_bf16(kf1, qf1, s, 0, 0, 0);
            sT[nt] = s;
        }

        if (jbase >= 0) {
#pragma unroll
            for (int nt = 0; nt < 4; nt++) {
#pragma unroll
                for (int r = 0; r < 4; r++) {
                    const int jp = jbase + (nt << 4) + (quad << 2) + r;
                    const bool ok = (jp >= qrow) && (jp <= qrow + 2 * WQ);
                    if (!ok) sT[nt][r] = -1e30f;
                }
            }
        }

        // per-lane online softmax over this lane's 16 keys + cross-quad reduce
        float mx = sT[0][0];
#pragma unroll
        for (int nt = 0; nt < 4; nt++)
#pragma unroll
            for (int r = 0; r < 4; r++) mx = fmaxf(mx, sT[nt][r]);
        mx = fmaxf(mx, __shfl_xor(mx, 16));
        mx = fmaxf(mx, __shfl_xor(mx, 32));

        // T13 defer-max (log2 units): skip rescale when growth <= 11 (P <= 2^11)
        if (!__all(mx - m_i <= 11.0f)) {
            const float m_new = fmaxf(m_i, mx);
            const float alpha = fast_exp2(m_i - m_new);
            m_i = m_new;
            l_i *= alpha;
            float al[4];
#pragma unroll
            for (int r = 0; r < 4; r++) al[r] = __shfl(alpha, alsrc0 | r);
#pragma unroll
            for (int nt = 0; nt < 4; nt++)
#pragma unroll
                for (int r = 0; r < 4; r++) acc_o[nt][r] *= al[r];
        }

        float ps = 0.f;
#pragma unroll
        for (int nt = 0; nt < 4; nt++)
#pragma unroll
            for (int r = 0; r < 4; r++) {
                const float e = fast_exp2(sT[nt][r] - m_i);
                sT[nt][r] = e;
                ps += e;
            }
        ps += __shfl_xor(ps, 16);
        ps += __shfl_xor(ps, 32);
        l_i += ps;

        // P pack + write: row q=col, k = nt*16 + quad*4 + {0..3}
#pragma unroll
        for (int nt = 0; nt < 4; nt++) {
            uint2 pk2;
            pk2.x = cvt_pk_bf16(sT[nt][0], sT[nt][1]);
            pk2.y = cvt_pk_bf16(sT[nt][2], sT[nt][3]);
            *(uint2*)&Ps[w][col][(nt << 4) + (quad << 2)] = pk2;
        }

        const bf16x8 pf0 = *(const bf16x8*)&Ps[w][col][quad << 3];
        const bf16x8 pf1 = *(const bf16x8*)&Ps[w][col][32 + (quad << 3)];

#pragma unroll
        for (int nt = 0; nt < 4; nt++) {
            const bf16x8 vf0 = *(const bf16x8*)&Vs[buf][(nt << 4) + col][quad << 3];
            const bf16x8 vf1 = *(const bf16x8*)&Vs[buf][(nt << 4) + col][32 + (quad << 3)];
            acc_o[nt] = __builtin_amdgcn_mfma_f32_16x16x32_bf16(pf0, vf0, acc_o[nt], 0, 0, 0);
            acc_o[nt] = __builtin_amdgcn_mfma_f32_16x16x32_bf16(pf1, vf1, acc_o[nt], 0, 0, 0);
        }

        if (pf) write_stage(buf ^ 1);              // regs -> other buffer (no barrier needed)
        buf ^= 1;
    }

    float inv[4];
#pragma unroll
    for (int r = 0; r < 4; r++) inv[r] = 1.f / __shfl(l_i, alsrc0 | r);
#pragma unroll
    for (int nt = 0; nt < 4; nt++) {
#pragma unroll
        for (int r = 0; r < 4; r++) {
            const int t = t0 + (w << 4) + (quad << 2) + r;
            attnb[base + (size_t)t * EE + (nt << 4) + col] = f2bf(acc_o[nt][r] * inv[r]);
        }
    }
}

// ---------- global-token attention: swapped QK^T + transposed V + defer-max + exp2 ----------
__global__ __launch_bounds__(256) void global_attn_flash_kernel(
    const u16* __restrict__ qg, const u16* __restrict__ kg, const u16* __restrict__ vgt,
    float* __restrict__ Op, float* __restrict__ Ml, float* __restrict__ Ll)
{
    const int tid  = threadIdx.x;
    const int lane = tid & 63;
    const int w    = tid >> 6;
    const int col  = lane & 15;
    const int quad = lane >> 4;

    const int s  = blockIdx.x & (NSPLIT - 1);
    const int h  = (blockIdx.x >> 3) & (HH - 1);
    const int b  = blockIdx.x >> 7;
    const int k0pos = s * (TT / NSPLIT);

    __shared__ __align__(16) u16 Ks[2][64][72];   // [buf][key][dim]
    __shared__ __align__(16) u16 Vs[2][64][72];   // [buf][dim][key]
    __shared__ __align__(16) u16 Ps[4][16][72];   // [wave][q][k]

    const size_t base   = (size_t)b * TT * EE + (size_t)h * DD;        // kg row-major
    const size_t vtbase = (size_t)((b << 4) | h) * DD * TT;            // vgt [B,H,D,T]

    const u16* qp = qg + (size_t)(b * GG + (w << 4) + col) * EE + (size_t)h * DD + (quad << 3);
    const bf16x8 qf0 = *(const bf16x8*)qp;
    const bf16x8 qf1 = *(const bf16x8*)(qp + 32);

    float m_i = -1e30f, l_i = 0.f;
    f32x4 acc_o[4];
#pragma unroll
    for (int nt = 0; nt < 4; nt++) acc_o[nt] = (f32x4){0.f, 0.f, 0.f, 0.f};

    constexpr int NTL = TT / NSPLIT / 64;          // 8 key tiles per split
    const int srow  = tid >> 2;
    const int spart = (tid & 3) << 4;

    uint4 kr0, kr1, vr0, vr1;
    auto issue_loads = [&](int i) {
        const int kpos0 = k0pos + (i << 6);
        const u16* ks = kg + base + (size_t)(kpos0 + srow) * EE + spart;
        const u16* vs = vgt + vtbase + (size_t)srow * TT + kpos0 + spart;
        kr0 = *(const uint4*)ks;
        kr1 = *(const uint4*)(ks + 8);
        vr0 = *(const uint4*)vs;
        vr1 = *(const uint4*)(vs + 8);
    };
    auto write_stage = [&](int buf) {
        *(uint4*)&Ks[buf][srow][spart]     = kr0;
        *(uint4*)&Ks[buf][srow][spart + 8] = kr1;
        *(uint4*)&Vs[buf][srow][spart]     = vr0;
        *(uint4*)&Vs[buf][srow][spart + 8] = vr1;
    };

    issue_loads(0);
    write_stage(0);
    int buf = 0;

    const int alsrc0 = (lane & 48) | ((lane >> 2) & 12);

#pragma unroll 1
    for (int i = 0; i < NTL; i++) {
        __syncthreads();
        const bool pf = (i + 1 < NTL);
        if (pf) issue_loads(i + 1);

        f32x4 sT[4];
#pragma unroll
        for (int nt = 0; nt < 4; nt++) {
            const bf16x8 kf0 = *(const bf16x8*)&Ks[buf][(nt << 4) + col][quad << 3];
            const bf16x8 kf1 = *(const bf16x8*)&Ks[buf][(nt << 4) + col][32 + (quad << 3)];
            f32x4 sv = (f32x4){0.f, 0.f, 0.f, 0.f};
            sv = __builtin_amdgcn_mfma_f32_16x16x32_bf16(kf0, qf0, sv, 0, 0, 0);
            sv = __builtin_amdgcn_mfma_f32_16x16x32_bf16(kf1, qf1, sv, 0, 0, 0);
            sT[nt] = sv;
        }

        float mx = sT[0][0];
#pragma unroll
        for (int nt = 0; nt < 4; nt++)
#pragma unroll
            for (int r = 0; r < 4; r++) mx = fmaxf(mx, sT[nt][r]);
        mx = fmaxf(mx, __shfl_xor(mx, 16));
        mx = fmaxf(mx, __shfl_xor(mx, 32));

        if (!__all(mx - m_i <= 11.0f)) {
            const float m_new = fmaxf(m_i, mx);
            const float alpha = fast_exp2(m_i - m_new);
            m_i = m_new;
            l_i *= alpha;
            float al[4];
#pragma unroll
            for (int r = 0; r < 4; r++) al[r] = __shfl(alpha, alsrc0 | r);
#pragma unroll
            for (int nt = 0; nt < 4; nt++)
#pragma unroll
                for (int r = 0; r < 4; r++) acc_o[nt][r] *= al[r];
        }

        float ps = 0.f;
#pragma unroll
        for (int nt = 0; nt < 4; nt++)
#pragma unroll
            for (int r = 0; r < 4; r++) {
                const float e = fast_exp2(sT[nt][r] - m_i);
                sT[nt][r] = e;
                ps += e;
            }
        ps += __shfl_xor(ps, 16);
        ps += __shfl_xor(ps, 32);
        l_i += ps;

#pragma unroll
        for (int nt = 0; nt < 4; nt++) {
            uint2 pk2;
            pk2.x = cvt_pk_bf16(sT[nt][0], sT[nt][1]);
            pk2.y = cvt_pk_bf16(sT[nt][2], sT[nt][3]);
            *(uint2*)&Ps[w][col][(nt << 4) + (quad << 2)] = pk2;
        }

        const bf16x8 pf0 = *(const bf16x8*)&Ps[w][col][quad << 3];
        const bf16x8 pf1 = *(const bf16x8*)&Ps[w][col][32 + (quad << 3)];

#pragma unroll
        for (int nt = 0; nt < 4; nt++) {
            const bf16x8 vf0 = *(const bf16x8*)&Vs[buf][(nt << 4) + col][quad << 3];
            const bf16x8 vf1 = *(const bf16x8*)&Vs[buf][(nt << 4) + col][32 + (quad << 3)];
            acc_o[nt] = __builtin_amdgcn_mfma_f32_16x16x32_bf16(pf0, vf0, acc_o[nt], 0, 0, 0);
            acc_o[nt] = __builtin_amdgcn_mfma_f32_16x16x32_bf16(pf1, vf1, acc_o[nt], 0, 0, 0);
        }

        if (pf) write_stage(buf ^ 1);
        buf ^= 1;
    }

    const size_t obase = (size_t)blockIdx.x * GG * DD;
#pragma unroll
    for (int nt = 0; nt < 4; nt++) {
#pragma unroll
        for (int r = 0; r < 4; r++) {
            const int row = (w << 4) + (quad << 2) + r;
            Op[obase + (size_t)row * DD + (nt << 4) + col] = acc_o[nt][r];
        }
    }
    if (quad == 0) {
        Ml[blockIdx.x * GG + (w << 4) + col] = m_i;
        Ll[blockIdx.x * GG + (w << 4) + col] = l_i;
    }
}

extern "C" void kernel_launch(void* const* d_in, const int* in_sizes, int n_in,
                              void* d_out, int out_size, void* d_ws, size_t ws_size,
                              hipStream_t stream)
{
    (void)in_sizes; (void)n_in; (void)out_size; (void)ws_size;
    const float* query = (const float*)d_in[0];
    const float* Wq  = (const float*)d_in[2];  const float* bq  = (const float*)d_in[3];
    const float* Wk  = (const float*)d_in[4];  const float* bk  = (const float*)d_in[5];
    const float* Wv  = (const float*)d_in[6];  const float* bv  = (const float*)d_in[7];
    const float* Wqg = (const float*)d_in[8];  const float* bqg = (const float*)d_in[9];
    const float* Wkg = (const float*)d_in[10]; const float* bkg = (const float*)d_in[11];
    const float* Wvg = (const float*)d_in[12]; const float* bvg = (const float*)d_in[13];
    const float* Wo  = (const float*)d_in[14]; const float* bo  = (const float*)d_in[15];

    const size_t nfull = (size_t)BBATCH * TT * EE;      // 8.39M elems
    const size_t wsz   = (size_t)1 << 20;               // one weight, elems
    u16* xb    = (u16*)d_ws;                            // bf16 x [B,T,E]; later reused as attnb
    u16* wb    = xb + nfull;                            // 7 converted weights
    u16* slotA = wb + 7 * wsz;                          // kg, then q
    u16* slotB = slotA + nfull;                         // vgt, then k
    u16* slotC = slotB + nfull;                         // vt [B,H,D,T]
    u16* qg    = slotC + nfull;                         // [B*G, E]
    float* Op  = (float*)(qg + (size_t)BBATCH * GG * EE);
    float* Ml  = Op + (size_t)BBATCH * HH * NSPLIT * GG * DD;
    float* Ll  = Ml + (size_t)BBATCH * HH * NSPLIT * GG;
    u16* attnb = xb;                                    // alias: xb dead after last GEMM that reads it
    // peak ws ≈ 86 MB

    WPtrs wp;   // order: fuse3 (Wq,Wk,Wv) | fuse2 (Wkg,Wvg) | Wqg | Wo
    wp.p[0] = Wq; wp.p[1] = Wk; wp.p[2] = Wv;
    wp.p[3] = Wkg; wp.p[4] = Wvg; wp.p[5] = Wqg; wp.p[6] = Wo;

    const dim3 blk(256);
    const dim3 gF2(16, 64);     // 128^2 tiles, N=2048
    const dim3 gF3(24, 64);     // 128^2 tiles, N=3072
    const dim3 gFull(8, 64);    // 128^2 tiles, N=1024 (Wo)
    const dim3 gQg(8, 1);
    const float sc = 0.125f * LOG2E;   // D^-0.5, pre-scaled for exp2 softmax

    conv_kernel<<<7680, blk, 0, stream>>>(wp, query, wb, xb);

    // qg projection (reads xb) — tiny M, keep simple kernel; log2e folded in
    gemm_kernel<0, 1, 0><<<gQg, blk, 0, stream>>>(xb, wb + 5 * wsz, bqg, qg, sc);

    // fused kg|vgt projection (vg written transposed per head for the flash)
    FusedArgs fa2;
    fa2.out[0] = slotA; fa2.out[1] = slotB; fa2.out[2] = nullptr;
    fa2.bias[0] = bkg;  fa2.bias[1] = bvg;  fa2.bias[2] = nullptr;
    fa2.scale[0] = 1.f; fa2.scale[1] = 1.f; fa2.scale[2] = 1.f;
    fa2.vseg = 1;
    gemm_pipe_kernel<2, 0, 0><<<gF2, blk, 0, stream>>>(xb, wb + 3 * wsz, fa2);
    global_attn_flash_kernel<<<BBATCH * HH * NSPLIT, blk, 0, stream>>>(qg, slotA, slotB, Op, Ml, Ll);

    // fused q|k|vt projection (q pre-scaled by D^-0.5 * log2e for exp2 softmax)
    FusedArgs fa3;
    fa3.out[0] = slotA; fa3.out[1] = slotB; fa3.out[2] = slotC;
    fa3.bias[0] = bq;   fa3.bias[1] = bk;   fa3.bias[2] = bv;
    fa3.scale[0] = sc;  fa3.scale[1] = 1.f; fa3.scale[2] = 1.f;
    fa3.vseg = 2;
    gemm_pipe_kernel<3, 0, 0><<<gF3, blk, 0, stream>>>(xb, wb, fa3);

    // band attention + fused combine (band qt==0 blocks early-exit; combine = last 128 blocks)
    band_attn_kernel<<<BBATCH * HH * (TT / 64) + BBATCH * HH * 4, blk, 0, stream>>>(
        slotA, slotB, slotC, attnb, Op, Ml, Ll);

    // output projection (128^2 pipelined, f32 out, [B,T]->[T,B] row perm)
    FusedArgs faO;
    faO.out[0] = (u16*)d_out; faO.out[1] = nullptr; faO.out[2] = nullptr;
    faO.bias[0] = bo;         faO.bias[1] = nullptr; faO.bias[2] = nullptr;
    faO.scale[0] = 1.f;       faO.scale[1] = 1.f;    faO.scale[2] = 1.f;
    faO.vseg = -1;
    gemm_pipe_kernel<1, 1, 1><<<gFull, blk, 0, stream>>>(attnb, wb + 6 * wsz, faO);
}

// Round 15
// 325.683 us; speedup vs baseline: 1.0480x; 1.0010x over previous
//
#include <hip/hip_runtime.h>
#include <hip/hip_bf16.h>

typedef unsigned short u16;
typedef __bf16 bf16x8 __attribute__((ext_vector_type(8)));
typedef float  f32x4  __attribute__((ext_vector_type(4)));

constexpr int TT = 4096;   // seq
constexpr int BBATCH = 2;  // batch
constexpr int EE = 1024;   // embed
constexpr int HH = 16;     // heads
constexpr int DD = 64;     // head dim
constexpr int WQ = 256;    // one-sided window
constexpr int GG = 64;     // global tokens
constexpr int NSPLIT = 8;  // key splits for global attention
constexpr float LOG2E = 1.4426950408889634f;

constexpr int NBAND = BBATCH * HH * (TT / 64 - 1);   // band blocks (qt>=1 only): 1984
constexpr int NCOMB = BBATCH * HH * 4;               // fused combine blocks: 128

// ---------- bf16 / math helpers ----------
__device__ __forceinline__ float fast_exp2(float x) {
    return __builtin_amdgcn_exp2f(x);   // native v_exp_f32 (2^x)
}
__device__ __forceinline__ u16 f2bf(float f) {
    union { float f; unsigned int i; } c; c.f = f;
    unsigned int x = c.i;
    return (u16)((x + 0x7fffu + ((x >> 16) & 1u)) >> 16);  // RNE
}
__device__ __forceinline__ unsigned cvt_pk_bf16(float a, float b) {
    unsigned r;
    asm("v_cvt_pk_bf16_f32 %0, %1, %2" : "=v"(r) : "v"(a), "v"(b));
    return r;  // low16 = bf16(a), high16 = bf16(b), RNE
}
__device__ __forceinline__ uint4 pack8(float4 a, float4 b) {
    uint4 r;
    r.x = (unsigned)f2bf(a.x) | ((unsigned)f2bf(a.y) << 16);
    r.y = (unsigned)f2bf(a.z) | ((unsigned)f2bf(a.w) << 16);
    r.z = (unsigned)f2bf(b.x) | ((unsigned)f2bf(b.y) << 16);
    r.w = (unsigned)f2bf(b.z) | ((unsigned)f2bf(b.w) << 16);
    return r;
}

// async global->LDS, 16B per lane; LDS dest = wave-uniform base + lane*16
__device__ __forceinline__ void g2l16(const u16* g, u16* l) {
    __builtin_amdgcn_global_load_lds(
        (const __attribute__((address_space(1))) void*)g,
        (__attribute__((address_space(3))) void*)l, 16, 0, 0);
}

// XCD swizzle: blocks sharing an M-tile (y) get linear ids == c (mod 8) -> one XCD's L2
__device__ __forceinline__ void xcd_swizzle(int& bx, int& by) {
    bx = blockIdx.x; by = blockIdx.y;
    if ((gridDim.y & 7) == 0) {
        const int g   = blockIdx.x + blockIdx.y * gridDim.x;
        const int idx = g >> 3;
        bx = idx % gridDim.x;
        by = (g & 7) + ((idx / gridDim.x) << 3);
    }
}

// ---------- fp32 -> bf16 conversion ----------
struct WPtrs { const float* p[7]; };
__global__ __launch_bounds__(256) void conv_kernel(
    WPtrs wp, const float* __restrict__ query, u16* __restrict__ wb, u16* __restrict__ xb)
{
    const size_t i8 = ((size_t)blockIdx.x * 256 + threadIdx.x) << 3;
    const size_t WTOT = (size_t)7 << 20;   // 7 x 1024*1024
    const float* src;
    u16* dst;
    if (i8 < WTOT) {
        const int which = (int)(i8 >> 20);
        src = wp.p[which] + (i8 & (((size_t)1 << 20) - 1));
        dst = wb + i8;
    } else {
        const size_t j = i8 - WTOT;            // dst index in [B,T,E]
        const size_t e = j & (EE - 1);
        const size_t t = (j >> 10) & (TT - 1);
        const size_t b = j >> 22;
        src = query + (t * BBATCH + b) * EE + e;
        dst = xb + j;
    }
    const float4 f0 = *(const float4*)src;
    const float4 f1 = *(const float4*)(src + 4);
    *(uint4*)dst = pack8(f0, f1);
}

// ---------- single-output GEMM (qg only: tiny M) ----------
template<int C_F32, int PERMA_QG, int PERMC_TB>
__global__ __launch_bounds__(256) void gemm_kernel(
    const u16* __restrict__ A, const u16* __restrict__ W, const float* __restrict__ bias,
    void* __restrict__ Cv, float scale)
{
    const int tid = threadIdx.x, lane = tid & 63, w = tid >> 6;
    const int wm = w >> 1, wn = w & 1;
    int bx, by;
    xcd_swizzle(bx, by);
    const int m0 = by << 7, n0 = bx << 7;

    __shared__ __align__(16) u16 As[2 * 128 * 32];   // two 32-col panels
    __shared__ __align__(16) u16 Bs[2 * 128 * 32];

    const int lrow = lane >> 2;
    const int lcol = (lane & 3) << 3;
    auto arow = [](int m) -> size_t {
        return PERMA_QG ? (size_t)(((m >> 6) << 12) | (m & 63)) : (size_t)m;
    };
    const u16* gA0 = A + arow(m0 + (w << 4) + lrow) * EE + lcol;
    const u16* gA1 = A + arow(m0 + 64 + (w << 4) + lrow) * EE + lcol;
    const u16* gB0 = W + (size_t)(n0 + (w << 4) + lrow) * EE + lcol;
    const u16* gB1 = gB0 + (size_t)64 * EE;
    u16* lA0 = As + (w << 9);
    u16* lA1 = As + 2048 + (w << 9);
    u16* lB0 = Bs + (w << 9);
    u16* lB1 = Bs + 2048 + (w << 9);

    f32x4 acc[4][4];
#pragma unroll
    for (int i = 0; i < 4; i++)
#pragma unroll
        for (int j = 0; j < 4; j++)
            acc[i][j] = (f32x4){0.f, 0.f, 0.f, 0.f};

    const int fr = lane & 15;
    const int fq = (lane >> 4) << 3;

    for (int k0 = 0; k0 < EE; k0 += 64) {
        g2l16(gA0 + k0, lA0);  g2l16(gA0 + k0 + 32, lA0 + 4096);
        g2l16(gA1 + k0, lA1);  g2l16(gA1 + k0 + 32, lA1 + 4096);
        g2l16(gB0 + k0, lB0);  g2l16(gB0 + k0 + 32, lB0 + 4096);
        g2l16(gB1 + k0, lB1);  g2l16(gB1 + k0 + 32, lB1 + 4096);
        __syncthreads();
#pragma unroll
        for (int p = 0; p < 2; p++) {
            bf16x8 af[4], bfv[4];
#pragma unroll
            for (int i = 0; i < 4; i++)
                af[i] = *(const bf16x8*)&As[p * 4096 + ((wm << 6) + (i << 4) + fr) * 32 + fq];
#pragma unroll
            for (int j = 0; j < 4; j++)
                bfv[j] = *(const bf16x8*)&Bs[p * 4096 + ((wn << 6) + (j << 4) + fr) * 32 + fq];
#pragma unroll
            for (int i = 0; i < 4; i++)
#pragma unroll
                for (int j = 0; j < 4; j++)
                    acc[i][j] = __builtin_amdgcn_mfma_f32_16x16x32_bf16(af[i], bfv[j], acc[i][j], 0, 0, 0);
        }
        __syncthreads();
    }

    const int colbase = n0 + (wn << 6);
    const int rowbase = m0 + (wm << 6) + ((lane >> 4) << 2);
#pragma unroll
    for (int j = 0; j < 4; j++) {
        const int col = colbase + (j << 4) + fr;
        const float bv = bias[col];
#pragma unroll
        for (int i = 0; i < 4; i++) {
#pragma unroll
            for (int r = 0; r < 4; r++) {
                const int row = rowbase + (i << 4) + r;
                const float val = (acc[i][j][r] + bv) * scale;
                const size_t dst = (size_t)(PERMC_TB ? (((row & (TT - 1)) << 1) | (row >> 12)) : row) * EE + col;
                if (C_F32) ((float*)Cv)[dst] = val;
                else       ((u16*)Cv)[dst]   = f2bf(val);
            }
        }
    }
}

struct FusedArgs { u16* out[3]; const float* bias[3]; float scale[3]; int vseg; };

// ---------- pipelined 128x128 GEMM (verified best: 0 bank conflicts, 2 blocks/CU) ----------
template<int NSEG, int CF32, int PERMC>
__global__ __launch_bounds__(256, 2) void gemm_pipe_kernel(
    const u16* __restrict__ A, const u16* __restrict__ W, FusedArgs fa)
{
    const int tid = threadIdx.x, lane = tid & 63, w = tid >> 6;
    const int wm = w >> 1, wn = w & 1;
    int bx, by;
    xcd_swizzle(bx, by);
    const int m0 = by << 7, n0 = bx << 7;

    __shared__ __align__(16) u16 As[2][8192];   // [buf][128][64], swizzled
    __shared__ __align__(16) u16 Bs[2][8192];

    const int srow = lane >> 3;                        // 0..7 (== dest row & 7)
    const int scol = ((lane & 7) ^ srow) << 3;         // pre-swizzled source col (elems)
    const u16* gA = A + (size_t)(m0 + (w << 5) + srow) * EE + scol;
    const u16* gB = W + (size_t)(n0 + (w << 5) + srow) * EE + scol;
    u16* lA = &As[0][0] + (w << 11);
    u16* lB = &Bs[0][0] + (w << 11);

    f32x4 acc[4][4];
#pragma unroll
    for (int i = 0; i < 4; i++)
#pragma unroll
        for (int j = 0; j < 4; j++)
            acc[i][j] = (f32x4){0.f, 0.f, 0.f, 0.f};

    const int fr = lane & 15;
    const int qb = (lane >> 4) << 4;                   // frag 16B-chunk byte col
    const int xr = (fr & 7) << 4;                      // read-side swizzle XOR

    auto stageA = [&](int k0, int buf) {
#pragma unroll
        for (int l = 0; l < 4; l++)
            g2l16(gA + (size_t)(l << 3) * EE + k0, lA + buf * 8192 + (l << 9));
    };
    auto stageB = [&](int k0, int buf) {
#pragma unroll
        for (int l = 0; l < 4; l++)
            g2l16(gB + (size_t)(l << 3) * EE + k0, lB + buf * 8192 + (l << 9));
    };

    stageA(0, 0);
    stageB(0, 0);
    __syncthreads();

    constexpr int NT = EE / 64;                        // 16 K-tiles
#pragma unroll 2
    for (int t = 0; t < NT; t++) {
        const int buf = t & 1;
        const bool pf = (t + 1 < NT);
        const int kn = (t + 1) << 6;
        bf16x8 af[4], bfv[4];

        // ---- phase 0 : k-half 0 ----
#pragma unroll
        for (int mi = 0; mi < 4; mi++)
            af[mi] = *(const bf16x8*)((const char*)&As[buf][0] +
                      ((((wm << 6) + (mi << 4) + fr)) << 7) + (qb ^ xr));
#pragma unroll
        for (int nj = 0; nj < 4; nj++)
            bfv[nj] = *(const bf16x8*)((const char*)&Bs[buf][0] +
                      ((((wn << 6) + (nj << 4) + fr)) << 7) + (qb ^ xr));
        if (pf) stageA(kn, buf ^ 1);
        __builtin_amdgcn_s_barrier();
        __builtin_amdgcn_s_setprio(1);
#pragma unroll
        for (int mi = 0; mi < 4; mi++)
#pragma unroll
            for (int nj = 0; nj < 4; nj++)
                acc[mi][nj] = __builtin_amdgcn_mfma_f32_16x16x32_bf16(af[mi], bfv[nj], acc[mi][nj], 0, 0, 0);
        __builtin_amdgcn_s_setprio(0);
        __builtin_amdgcn_s_barrier();

        // ---- phase 1 : k-half 1 ----
#pragma unroll
        for (int mi = 0; mi < 4; mi++)
            af[mi] = *(const bf16x8*)((const char*)&As[buf][0] +
                      ((((wm << 6) + (mi << 4) + fr)) << 7) + ((64 | qb) ^ xr));
#pragma unroll
        for (int nj = 0; nj < 4; nj++)
            bfv[nj] = *(const bf16x8*)((const char*)&Bs[buf][0] +
                      ((((wn << 6) + (nj << 4) + fr)) << 7) + ((64 | qb) ^ xr));
        if (pf) stageB(kn, buf ^ 1);
        __builtin_amdgcn_s_barrier();
        __builtin_amdgcn_s_setprio(1);
#pragma unroll
        for (int mi = 0; mi < 4; mi++)
#pragma unroll
            for (int nj = 0; nj < 4; nj++)
                acc[mi][nj] = __builtin_amdgcn_mfma_f32_16x16x32_bf16(af[mi], bfv[nj], acc[mi][nj], 0, 0, 0);
        __builtin_amdgcn_s_setprio(0);
        __syncthreads();
    }

    const int seg = (NSEG > 1) ? (n0 >> 10) : 0;
    u16* outp = fa.out[seg];
    const float* bp = fa.bias[seg];
    const float scl = fa.scale[seg];
    const bool vtr = (NSEG > 1) && (seg == fa.vseg);

    const int colbase = n0 + (wn << 6);
    const int rowbase = m0 + (wm << 6) + ((lane >> 4) << 2);
#pragma unroll
    for (int j = 0; j < 4; j++) {
        const int col = colbase + (j << 4) + fr;
        const int cl  = col & (EE - 1);
        const float bv = bp[cl];
#pragma unroll
        for (int i = 0; i < 4; i++) {
            if (vtr) {
                const int row0 = rowbase + (i << 4);
                const int bb = row0 >> 12, t = row0 & (TT - 1);
                const int hh = cl >> 6, d = cl & 63;
                ushort4 pk;
                pk.x = f2bf((acc[i][j][0] + bv) * scl);
                pk.y = f2bf((acc[i][j][1] + bv) * scl);
                pk.z = f2bf((acc[i][j][2] + bv) * scl);
                pk.w = f2bf((acc[i][j][3] + bv) * scl);
                *(ushort4*)(outp + (((size_t)(bb * HH + hh) * DD + d) * TT + t)) = pk;
            } else {
#pragma unroll
                for (int r = 0; r < 4; r++) {
                    const int row = rowbase + (i << 4) + r;
                    const float val = (acc[i][j][r] + bv) * scl;
                    const size_t drow = PERMC ? (size_t)(((row & (TT - 1)) << 1) | (row >> 12))
                                              : (size_t)row;
                    if (CF32) ((float*)outp)[drow * EE + cl] = val;
                    else      outp[drow * EE + cl] = f2bf(val);
                }
            }
        }
    }
}

// ---------- band attention + fused split-K combine ----------
// Blocks [0, NBAND): band flash for qt = bid/32 + 1 (rows 64..4095; rows 0..63 are
// REPLACED by the global-attention output in the reference, so qt==0 is never computed).
// Blocks [NBAND, NBAND+NCOMB): widened split-K combine - writes exactly rows 0..63 per
// (b,h). Disjoint attnb row sets -> no inter-block ordering needed. Combine inputs
// (Op/Ml/Ll) are complete before this launch.
__global__ __launch_bounds__(256) void band_attn_kernel(
    const u16* __restrict__ q, const u16* __restrict__ k, const u16* __restrict__ vt,
    u16* __restrict__ attnb,
    const float* __restrict__ Op, const float* __restrict__ Ml, const float* __restrict__ Ll)
{
    const int tid  = threadIdx.x;

    if (blockIdx.x >= NBAND) {
        // ---- combine path (m/l in log2 units -> exp2) ----
        const int cb  = blockIdx.x - NBAND;
        const int bh  = cb >> 2;                     // batch*head
        const int b   = bh >> 4;
        const int h   = bh & (HH - 1);
        const int row = ((cb & 3) << 4) + (tid >> 4);  // 16 rows/block
        const int d0  = (tid & 15) << 2;             // 4-float dim group

        float mv[NSPLIT];
        float m = -1e30f;
#pragma unroll
        for (int s = 0; s < NSPLIT; s++) {
            mv[s] = Ml[(bh * NSPLIT + s) * GG + row];
            m = fmaxf(m, mv[s]);
        }
        float l = 0.f;
        float sc[NSPLIT];
#pragma unroll
        for (int s = 0; s < NSPLIT; s++) {
            sc[s] = fast_exp2(mv[s] - m);
            l += Ll[(bh * NSPLIT + s) * GG + row] * sc[s];
        }
        float o[4];
#pragma unroll
        for (int j = 0; j < 4; j++) o[j] = 0.f;
#pragma unroll
        for (int s = 0; s < NSPLIT; s++) {
            const float4 v4 = *(const float4*)(Op + ((size_t)(bh * NSPLIT + s) * GG + row) * DD + d0);
            const float f = sc[s];
            o[0] = fmaf(v4.x, f, o[0]);
            o[1] = fmaf(v4.y, f, o[1]);
            o[2] = fmaf(v4.z, f, o[2]);
            o[3] = fmaf(v4.w, f, o[3]);
        }
        const float inv = 1.f / l;
        u16* dst = attnb + ((size_t)b * TT + row) * EE + (size_t)h * DD + d0;
        ushort4 pk;
        pk.x = f2bf(o[0] * inv);
        pk.y = f2bf(o[1] * inv);
        pk.z = f2bf(o[2] * inv);
        pk.w = f2bf(o[3] * inv);
        *(ushort4*)dst = pk;
        return;
    }

    const int qt = (blockIdx.x >> 5) + 1;          // qt in [1, 64): rows 64..4095
    const int lane = tid & 63;
    const int w    = tid >> 6;
    const int col  = lane & 15;
    const int quad = lane >> 4;

    const int bh = blockIdx.x & 31;
    const int h  = bh & (HH - 1);
    const int b  = bh >> 4;
    const int t0 = qt << 6;

    __shared__ __align__(16) u16 Ks[2][64][72];   // [buf][key][dim]
    __shared__ __align__(16) u16 Vs[2][64][72];   // [buf][dim][key]
    __shared__ __align__(16) u16 Ps[4][16][72];   // [wave][q][k]

    const size_t base   = (size_t)b * TT * EE + (size_t)h * DD;
    const size_t vtbase = (size_t)bh * DD * TT;

    const u16* qp = q + base + (size_t)(t0 + (w << 4) + col) * EE + (quad << 3);
    const bf16x8 qf0 = *(const bf16x8*)qp;
    const bf16x8 qf1 = *(const bf16x8*)(qp + 32);

    float m_i = -1e30f, l_i = 0.f;
    f32x4 acc_o[4];
#pragma unroll
    for (int nt = 0; nt < 4; nt++) acc_o[nt] = (f32x4){0.f, 0.f, 0.f, 0.f};

    const int c_lo = 1 + ((t0 < WQ) ? ((WQ - t0) >> 6) : 0);
    const int c_hi = min(9, 1 + ((TT + WQ - 64 - t0) >> 6));
    const int NTL  = 2 + c_hi - c_lo;              // tiles: 1 global + window tiles

    const int srow  = tid >> 2;
    const int spart = (tid & 3) << 4;

    uint4 kr0, kr1, vr0, vr1;                      // staging regs (in flight)
    auto issue_loads = [&](int i) {
        const int kpos0 = (i == 0) ? 0 : (t0 - WQ + ((c_lo + i - 2) << 6));
        const u16* ks = k + base + (size_t)(kpos0 + srow) * EE + spart;
        const u16* vs = vt + vtbase + (size_t)srow * TT + kpos0 + spart;
        kr0 = *(const uint4*)ks;
        kr1 = *(const uint4*)(ks + 8);
        vr0 = *(const uint4*)vs;
        vr1 = *(const uint4*)(vs + 8);
    };
    auto write_stage = [&](int buf) {
        *(uint4*)&Ks[buf][srow][spart]     = kr0;
        *(uint4*)&Ks[buf][srow][spart + 8] = kr1;
        *(uint4*)&Vs[buf][srow][spart]     = vr0;
        *(uint4*)&Vs[buf][srow][spart + 8] = vr1;
    };

    issue_loads(0);
    write_stage(0);
    int buf = 0;

    const int qrow = (w << 4) + col;               // this lane's query row (rel t0)
    const int alsrc0 = (lane & 48) | ((lane >> 2) & 12);  // lane holding alpha/l for row quad*4+r

#pragma unroll 1
    for (int i = 0; i < NTL; i++) {
        __syncthreads();                           // LDS[buf] ready for all waves
        const int c     = c_lo + i - 1;            // window chunk id (i>=1)
        const int jbase = (i > 0 && (c == 1 || c == 9)) ? ((c - 1) << 6) : -1;
        const bool pf   = (i + 1 < NTL);
        if (pf) issue_loads(i + 1);                // latency hides under compute

        // QK^T transposed: sT[nt] row=key(quad*4+r), col=q
        f32x4 sT[4];
#pragma unroll
        for (int nt = 0; nt < 4; nt++) {
            const bf16x8 kf0 = *(const bf16x8*)&Ks[buf][(nt << 4) + col][quad << 3];
            const bf16x8 kf1 = *(const bf16x8*)&Ks[buf][(nt << 4) + col][32 + (quad << 3)];
            f32x4 s = (f32x4){0.f, 0.f, 0.f, 0.f};
            s = __builtin_amdgcn_mfma_f32_16x16x32_bf16(kf0, qf0, s, 0, 0, 0);
            s = __builtin_amdgcn_mfma_f32_16x16x32_bf16(kf1, qf1, s, 0, 0, 0);
            sT[nt] = s;
        }

        if (jbase >= 0) {
#pragma unroll
            for (int nt = 0; nt < 4; nt++) {
#pragma unroll
                for (int r = 0; r < 4; r++) {
                    const int jp = jbase + (nt << 4) + (quad << 2) + r;
                    const bool ok = (jp >= qrow) && (jp <= qrow + 2 * WQ);
                    if (!ok) sT[nt][r] = -1e30f;
                }
            }
        }

        // per-lane online softmax over this lane's 16 keys + cross-quad reduce
        float mx = sT[0][0];
#pragma unroll
        for (int nt = 0; nt < 4; nt++)
#pragma unroll
            for (int r = 0; r < 4; r++) mx = fmaxf(mx, sT[nt][r]);
        mx = fmaxf(mx, __shfl_xor(mx, 16));
        mx = fmaxf(mx, __shfl_xor(mx, 32));

        // T13 defer-max (log2 units): skip rescale when growth <= 11 (P <= 2^11)
        if (!__all(mx - m_i <= 11.0f)) {
            const float m_new = fmaxf(m_i, mx);
            const float alpha = fast_exp2(m_i - m_new);
            m_i = m_new;
            l_i *= alpha;
            float al[4];
#pragma unroll
            for (int r = 0; r < 4; r++) al[r] = __shfl(alpha, alsrc0 | r);
#pragma unroll
            for (int nt = 0; nt < 4; nt++)
#pragma unroll
                for (int r = 0; r < 4; r++) acc_o[nt][r] *= al[r];
        }

        float ps = 0.f;
#pragma unroll
        for (int nt = 0; nt < 4; nt++)
#pragma unroll
            for (int r = 0; r < 4; r++) {
                const float e = fast_exp2(sT[nt][r] - m_i);
                sT[nt][r] = e;
                ps += e;
            }
        ps += __shfl_xor(ps, 16);
        ps += __shfl_xor(ps, 32);
        l_i += ps;

        // P pack + write: row q=col, k = nt*16 + quad*4 + {0..3}
#pragma unroll
        for (int nt = 0; nt < 4; nt++) {
            uint2 pk2;
            pk2.x = cvt_pk_bf16(sT[nt][0], sT[nt][1]);
            pk2.y = cvt_pk_bf16(sT[nt][2], sT[nt][3]);
            *(uint2*)&Ps[w][col][(nt << 4) + (quad << 2)] = pk2;
        }

        const bf16x8 pf0 = *(const bf16x8*)&Ps[w][col][quad << 3];
        const bf16x8 pf1 = *(const bf16x8*)&Ps[w][col][32 + (quad << 3)];

#pragma unroll
        for (int nt = 0; nt < 4; nt++) {
            const bf16x8 vf0 = *(const bf16x8*)&Vs[buf][(nt << 4) + col][quad << 3];
            const bf16x8 vf1 = *(const bf16x8*)&Vs[buf][(nt << 4) + col][32 + (quad << 3)];
            acc_o[nt] = __builtin_amdgcn_mfma_f32_16x16x32_bf16(pf0, vf0, acc_o[nt], 0, 0, 0);
            acc_o[nt] = __builtin_amdgcn_mfma_f32_16x16x32_bf16(pf1, vf1, acc_o[nt], 0, 0, 0);
        }

        if (pf) write_stage(buf ^ 1);              // regs -> other buffer (no barrier needed)
        buf ^= 1;
    }

    float inv[4];
#pragma unroll
    for (int r = 0; r < 4; r++) inv[r] = 1.f / __shfl(l_i, alsrc0 | r);
#pragma unroll
    for (int nt = 0; nt < 4; nt++) {
#pragma unroll
        for (int r = 0; r < 4; r++) {
            const int t = t0 + (w << 4) + (quad << 2) + r;
            attnb[base + (size_t)t * EE + (nt << 4) + col] = f2bf(acc_o[nt][r] * inv[r]);
        }
    }
}

// ---------- global-token attention: swapped QK^T + transposed V + defer-max + exp2 ----------
__global__ __launch_bounds__(256) void global_attn_flash_kernel(
    const u16* __restrict__ qg, const u16* __restrict__ kg, const u16* __restrict__ vgt,
    float* __restrict__ Op, float* __restrict__ Ml, float* __restrict__ Ll)
{
    const int tid  = threadIdx.x;
    const int lane = tid & 63;
    const int w    = tid >> 6;
    const int col  = lane & 15;
    const int quad = lane >> 4;

    const int s  = blockIdx.x & (NSPLIT - 1);
    const int h  = (blockIdx.x >> 3) & (HH - 1);
    const int b  = blockIdx.x >> 7;
    const int k0pos = s * (TT / NSPLIT);

    __shared__ __align__(16) u16 Ks[2][64][72];   // [buf][key][dim]
    __shared__ __align__(16) u16 Vs[2][64][72];   // [buf][dim][key]
    __shared__ __align__(16) u16 Ps[4][16][72];   // [wave][q][k]

    const size_t base   = (size_t)b * TT * EE + (size_t)h * DD;        // kg row-major
    const size_t vtbase = (size_t)((b << 4) | h) * DD * TT;            // vgt [B,H,D,T]

    const u16* qp = qg + (size_t)(b * GG + (w << 4) + col) * EE + (size_t)h * DD + (quad << 3);
    const bf16x8 qf0 = *(const bf16x8*)qp;
    const bf16x8 qf1 = *(const bf16x8*)(qp + 32);

    float m_i = -1e30f, l_i = 0.f;
    f32x4 acc_o[4];
#pragma unroll
    for (int nt = 0; nt < 4; nt++) acc_o[nt] = (f32x4){0.f, 0.f, 0.f, 0.f};

    constexpr int NTL = TT / NSPLIT / 64;          // 8 key tiles per split
    const int srow  = tid >> 2;
    const int spart = (tid & 3) << 4;

    uint4 kr0, kr1, vr0, vr1;
    auto issue_loads = [&](int i) {
        const int kpos0 = k0pos + (i << 6);
        const u16* ks = kg + base + (size_t)(kpos0 + srow) * EE + spart;
        const u16* vs = vgt + vtbase + (size_t)srow * TT + kpos0 + spart;
        kr0 = *(const uint4*)ks;
        kr1 = *(const uint4*)(ks + 8);
        vr0 = *(const uint4*)vs;
        vr1 = *(const uint4*)(vs + 8);
    };
    auto write_stage = [&](int buf) {
        *(uint4*)&Ks[buf][srow][spart]     = kr0;
        *(uint4*)&Ks[buf][srow][spart + 8] = kr1;
        *(uint4*)&Vs[buf][srow][spart]     = vr0;
        *(uint4*)&Vs[buf][srow][spart + 8] = vr1;
    };

    issue_loads(0);
    write_stage(0);
    int buf = 0;

    const int alsrc0 = (lane & 48) | ((lane >> 2) & 12);

#pragma unroll 1
    for (int i = 0; i < NTL; i++) {
        __syncthreads();
        const bool pf = (i + 1 < NTL);
        if (pf) issue_loads(i + 1);

        f32x4 sT[4];
#pragma unroll
        for (int nt = 0; nt < 4; nt++) {
            const bf16x8 kf0 = *(const bf16x8*)&Ks[buf][(nt << 4) + col][quad << 3];
            const bf16x8 kf1 = *(const bf16x8*)&Ks[buf][(nt << 4) + col][32 + (quad << 3)];
            f32x4 sv = (f32x4){0.f, 0.f, 0.f, 0.f};
            sv = __builtin_amdgcn_mfma_f32_16x16x32_bf16(kf0, qf0, sv, 0, 0, 0);
            sv = __builtin_amdgcn_mfma_f32_16x16x32_bf16(kf1, qf1, sv, 0, 0, 0);
            sT[nt] = sv;
        }

        float mx = sT[0][0];
#pragma unroll
        for (int nt = 0; nt < 4; nt++)
#pragma unroll
            for (int r = 0; r < 4; r++) mx = fmaxf(mx, sT[nt][r]);
        mx = fmaxf(mx, __shfl_xor(mx, 16));
        mx = fmaxf(mx, __shfl_xor(mx, 32));

        if (!__all(mx - m_i <= 11.0f)) {
            const float m_new = fmaxf(m_i, mx);
            const float alpha = fast_exp2(m_i - m_new);
            m_i = m_new;
            l_i *= alpha;
            float al[4];
#pragma unroll
            for (int r = 0; r < 4; r++) al[r] = __shfl(alpha, alsrc0 | r);
#pragma unroll
            for (int nt = 0; nt < 4; nt++)
#pragma unroll
                for (int r = 0; r < 4; r++) acc_o[nt][r] *= al[r];
        }

        float ps = 0.f;
#pragma unroll
        for (int nt = 0; nt < 4; nt++)
#pragma unroll
            for (int r = 0; r < 4; r++) {
                const float e = fast_exp2(sT[nt][r] - m_i);
                sT[nt][r] = e;
                ps += e;
            }
        ps += __shfl_xor(ps, 16);
        ps += __shfl_xor(ps, 32);
        l_i += ps;

#pragma unroll
        for (int nt = 0; nt < 4; nt++) {
            uint2 pk2;
            pk2.x = cvt_pk_bf16(sT[nt][0], sT[nt][1]);
            pk2.y = cvt_pk_bf16(sT[nt][2], sT[nt][3]);
            *(uint2*)&Ps[w][col][(nt << 4) + (quad << 2)] = pk2;
        }

        const bf16x8 pf0 = *(const bf16x8*)&Ps[w][col][quad << 3];
        const bf16x8 pf1 = *(const bf16x8*)&Ps[w][col][32 + (quad << 3)];

#pragma unroll
        for (int nt = 0; nt < 4; nt++) {
            const bf16x8 vf0 = *(const bf16x8*)&Vs[buf][(nt << 4) + col][quad << 3];
            const bf16x8 vf1 = *(const bf16x8*)&Vs[buf][(nt << 4) + col][32 + (quad << 3)];
            acc_o[nt] = __builtin_amdgcn_mfma_f32_16x16x32_bf16(pf0, vf0, acc_o[nt], 0, 0, 0);
            acc_o[nt] = __builtin_amdgcn_mfma_f32_16x16x32_bf16(pf1, vf1, acc_o[nt], 0, 0, 0);
        }

        if (pf) write_stage(buf ^ 1);
        buf ^= 1;
    }

    const size_t obase = (size_t)blockIdx.x * GG * DD;
#pragma unroll
    for (int nt = 0; nt < 4; nt++) {
#pragma unroll
        for (int r = 0; r < 4; r++) {
            const int row = (w << 4) + (quad << 2) + r;
            Op[obase + (size_t)row * DD + (nt << 4) + col] = acc_o[nt][r];
        }
    }
    if (quad == 0) {
        Ml[blockIdx.x * GG + (w << 4) + col] = m_i;
        Ll[blockIdx.x * GG + (w << 4) + col] = l_i;
    }
}

extern "C" void kernel_launch(void* const* d_in, const int* in_sizes, int n_in,
                              void* d_out, int out_size, void* d_ws, size_t ws_size,
                              hipStream_t stream)
{
    (void)in_sizes; (void)n_in; (void)out_size; (void)ws_size;
    const float* query = (const float*)d_in[0];
    const float* Wq  = (const float*)d_in[2];  const float* bq  = (const float*)d_in[3];
    const float* Wk  = (const float*)d_in[4];  const float* bk  = (const float*)d_in[5];
    const float* Wv  = (const float*)d_in[6];  const float* bv  = (const float*)d_in[7];
    const float* Wqg = (const float*)d_in[8];  const float* bqg = (const float*)d_in[9];
    const float* Wkg = (const float*)d_in[10]; const float* bkg = (const float*)d_in[11];
    const float* Wvg = (const float*)d_in[12]; const float* bvg = (const float*)d_in[13];
    const float* Wo  = (const float*)d_in[14]; const float* bo  = (const float*)d_in[15];

    const size_t nfull = (size_t)BBATCH * TT * EE;      // 8.39M elems
    const size_t wsz   = (size_t)1 << 20;               // one weight, elems
    u16* xb    = (u16*)d_ws;                            // bf16 x [B,T,E]; later reused as attnb
    u16* wb    = xb + nfull;                            // 7 converted weights
    u16* slotA = wb + 7 * wsz;                          // kg, then q
    u16* slotB = slotA + nfull;                         // vgt, then k
    u16* slotC = slotB + nfull;                         // vt [B,H,D,T]
    u16* qg    = slotC + nfull;                         // [B*G, E]
    float* Op  = (float*)(qg + (size_t)BBATCH * GG * EE);
    float* Ml  = Op + (size_t)BBATCH * HH * NSPLIT * GG * DD;
    float* Ll  = Ml + (size_t)BBATCH * HH * NSPLIT * GG;
    u16* attnb = xb;                                    // alias: xb dead after last GEMM that reads it
    // peak ws ≈ 86 MB

    WPtrs wp;   // order: fuse3 (Wq,Wk,Wv) | fuse2 (Wkg,Wvg) | Wqg | Wo
    wp.p[0] = Wq; wp.p[1] = Wk; wp.p[2] = Wv;
    wp.p[3] = Wkg; wp.p[4] = Wvg; wp.p[5] = Wqg; wp.p[6] = Wo;

    const dim3 blk(256);
    const dim3 gF2(16, 64);     // 128^2 tiles, N=2048
    const dim3 gF3(24, 64);     // 128^2 tiles, N=3072
    const dim3 gFull(8, 64);    // 128^2 tiles, N=1024 (Wo)
    const dim3 gQg(8, 1);
    const float sc = 0.125f * LOG2E;   // D^-0.5, pre-scaled for exp2 softmax

    conv_kernel<<<7680, blk, 0, stream>>>(wp, query, wb, xb);

    // qg projection (reads xb) — tiny M, keep simple kernel; log2e folded in
    gemm_kernel<0, 1, 0><<<gQg, blk, 0, stream>>>(xb, wb + 5 * wsz, bqg, qg, sc);

    // fused kg|vgt projection (vg written transposed per head for the flash)
    FusedArgs fa2;
    fa2.out[0] = slotA; fa2.out[1] = slotB; fa2.out[2] = nullptr;
    fa2.bias[0] = bkg;  fa2.bias[1] = bvg;  fa2.bias[2] = nullptr;
    fa2.scale[0] = 1.f; fa2.scale[1] = 1.f; fa2.scale[2] = 1.f;
    fa2.vseg = 1;
    gemm_pipe_kernel<2, 0, 0><<<gF2, blk, 0, stream>>>(xb, wb + 3 * wsz, fa2);
    global_attn_flash_kernel<<<BBATCH * HH * NSPLIT, blk, 0, stream>>>(qg, slotA, slotB, Op, Ml, Ll);

    // fused q|k|vt projection (q pre-scaled by D^-0.5 * log2e for exp2 softmax)
    FusedArgs fa3;
    fa3.out[0] = slotA; fa3.out[1] = slotB; fa3.out[2] = slotC;
    fa3.bias[0] = bq;   fa3.bias[1] = bk;   fa3.bias[2] = bv;
    fa3.scale[0] = sc;  fa3.scale[1] = 1.f; fa3.scale[2] = 1.f;
    fa3.vseg = 2;
    gemm_pipe_kernel<3, 0, 0><<<gF3, blk, 0, stream>>>(xb, wb, fa3);

    // band attention (qt>=1 only) + fused combine (last NCOMB blocks)
    band_attn_kernel<<<NBAND + NCOMB, blk, 0, stream>>>(
        slotA, slotB, slotC, attnb, Op, Ml, Ll);

    // output projection (128^2 pipelined, f32 out, [B,T]->[T,B] row perm)
    FusedArgs faO;
    faO.out[0] = (u16*)d_out; faO.out[1] = nullptr; faO.out[2] = nullptr;
    faO.bias[0] = bo;         faO.bias[1] = nullptr; faO.bias[2] = nullptr;
    faO.scale[0] = 1.f;       faO.scale[1] = 1.f;    faO.scale[2] = 1.f;
    faO.vseg = -1;
    gemm_pipe_kernel<1, 1, 1><<<gFull, blk, 0, stream>>>(attnb, wb + 6 * wsz, faO);
}